// Round 2
// baseline (563.090 us; speedup 1.0000x reference)
//
#include <hip/hip_runtime.h>

// LM-LIIF fused pipeline, fp32.
// R1 changes (query_kernel only):
//  - thread=query, but block = 256 threads over a 16x16 query tile (24x24 grid)
//    -> gather footprint per block = 5x5 latent px (L1-resident), fixes the
//       320 MB FETCH_SIZE seen in R0.
//  - layer-1 fully in registers: h[64] -> h2[64], 64x64 FMA fully unrolled,
//    W1 read at wave-uniform literal offsets (s_load + v_fmac v,s,v).
//    No LDS, no __syncthreads in query kernel at all.
//  - ensemble loop rolled (runtime e) to keep the body ~1x in I$;
//    per-tap rm/r0/r1/wgt selected from named scalars via cndmask chains.

#define HW 96
#define NPIX (96*96)
#define CFEAT 64

__global__ __launch_bounds__(256) void hyper_kernel(
    const float* __restrict__ feat,
    const float* __restrict__ cell,
    const float* __restrict__ Wh1,   // (578,256)
    const float* __restrict__ bh1,   // (256)
    const float* __restrict__ Wh2,   // (256,256)
    const float* __restrict__ bh2,   // (256)
    const float* __restrict__ W0,    // (68,64)
    const float* __restrict__ b0,    // (64)
    float* __restrict__ mod_ws,      // (9216,256)
    float* __restrict__ f0_ws)       // (9216,64)
{
    __shared__ float patch[CFEAT*54];   // [c][dy(3)][xx(18)]  13.8 KB
    __shared__ float h1s[256*17];       // [n][m pad 17]       17.4 KB

    const int tid = threadIdx.x;
    const int blk = blockIdx.x;
    const int y   = blk / 6;
    const int x0  = (blk % 6) * 16;

    for (int idx = tid; idx < CFEAT*54; idx += 256) {
        int c  = idx / 54;
        int r  = idx % 54;
        int dy = r / 18;
        int xx = r % 18;
        int gy = y + dy - 1;
        int gx = x0 + xx - 1;
        float v = 0.0f;
        if (gy >= 0 && gy < HW && gx >= 0 && gx < HW)
            v = feat[c*NPIX + gy*HW + gx];
        patch[idx] = v;
    }
    __syncthreads();

    const int lane  = tid & 63;
    const int mg    = tid >> 6;
    const int m0    = mg * 4;
    const int qbase = y*HW + x0;

    // ---- F0[p][n] = sum_c feat[c,p]*W0[c,n] + b0[n] ----
    {
        float acc[4] = {0.f, 0.f, 0.f, 0.f};
        for (int c = 0; c < CFEAT; ++c) {
            float w = W0[c*64 + lane];
            const float* p = &patch[c*54 + 18 + 1 + m0];
            acc[0] = fmaf(p[0], w, acc[0]);
            acc[1] = fmaf(p[1], w, acc[1]);
            acc[2] = fmaf(p[2], w, acc[2]);
            acc[3] = fmaf(p[3], w, acc[3]);
        }
        float bb = b0[lane];
        #pragma unroll
        for (int mi = 0; mi < 4; ++mi)
            f0_ws[(qbase + m0 + mi)*64 + lane] = acc[mi] + bb;
    }

    // ---- hyper layer 1: 576-unfold -> 256 ----
    float acc[4][4];
    #pragma unroll
    for (int i = 0; i < 4; ++i) {
        acc[i][0] = 0.f; acc[i][1] = 0.f; acc[i][2] = 0.f; acc[i][3] = 0.f;
    }

    const float4* Wh1v = (const float4*)Wh1;
    for (int c = 0; c < CFEAT; ++c) {
        #pragma unroll
        for (int dy = 0; dy < 3; ++dy) {
            #pragma unroll
            for (int dx = 0; dx < 3; ++dx) {
                const int k = c*9 + dy*3 + dx;
                const float4 w = Wh1v[k*64 + lane];
                const float* p = &patch[c*54 + dy*18 + dx + m0];
                #pragma unroll
                for (int mi = 0; mi < 4; ++mi) {
                    float xv = p[mi];
                    acc[mi][0] = fmaf(xv, w.x, acc[mi][0]);
                    acc[mi][1] = fmaf(xv, w.y, acc[mi][1]);
                    acc[mi][2] = fmaf(xv, w.z, acc[mi][2]);
                    acc[mi][3] = fmaf(xv, w.w, acc[mi][3]);
                }
            }
        }
    }

    {
        const float4 bb   = ((const float4*)bh1)[lane];
        const float4 w576 = Wh1v[576*64 + lane];
        const float4 w577 = Wh1v[577*64 + lane];
        #pragma unroll
        for (int mi = 0; mi < 4; ++mi) {
            const int q = qbase + m0 + mi;
            const float rc0 = cell[q*2+0] * 96.0f;
            const float rc1 = cell[q*2+1] * 96.0f;
            float v0 = acc[mi][0] + bb.x + rc0*w576.x + rc1*w577.x;
            float v1 = acc[mi][1] + bb.y + rc0*w576.y + rc1*w577.y;
            float v2 = acc[mi][2] + bb.z + rc0*w576.z + rc1*w577.z;
            float v3 = acc[mi][3] + bb.w + rc0*w576.w + rc1*w577.w;
            h1s[(4*lane+0)*17 + m0 + mi] = fmaxf(v0, 0.f);
            h1s[(4*lane+1)*17 + m0 + mi] = fmaxf(v1, 0.f);
            h1s[(4*lane+2)*17 + m0 + mi] = fmaxf(v2, 0.f);
            h1s[(4*lane+3)*17 + m0 + mi] = fmaxf(v3, 0.f);
        }
    }
    __syncthreads();

    // ---- hyper layer 2: 256 -> 256 ----
    float acc2[4][4];
    #pragma unroll
    for (int i = 0; i < 4; ++i) {
        acc2[i][0] = 0.f; acc2[i][1] = 0.f; acc2[i][2] = 0.f; acc2[i][3] = 0.f;
    }
    const float4* Wh2v = (const float4*)Wh2;
    for (int k = 0; k < 256; ++k) {
        const float4 w = Wh2v[k*64 + lane];
        const float* p = &h1s[k*17 + m0];
        #pragma unroll
        for (int mi = 0; mi < 4; ++mi) {
            float xv = p[mi];
            acc2[mi][0] = fmaf(xv, w.x, acc2[mi][0]);
            acc2[mi][1] = fmaf(xv, w.y, acc2[mi][1]);
            acc2[mi][2] = fmaf(xv, w.z, acc2[mi][2]);
            acc2[mi][3] = fmaf(xv, w.w, acc2[mi][3]);
        }
    }
    {
        const float4 bb = ((const float4*)bh2)[lane];
        #pragma unroll
        for (int mi = 0; mi < 4; ++mi) {
            const int q = qbase + m0 + mi;
            float4 o;
            o.x = acc2[mi][0] + bb.x;
            o.y = acc2[mi][1] + bb.y;
            o.z = acc2[mi][2] + bb.z;
            o.w = acc2[mi][3] + bb.w;
            ((float4*)mod_ws)[q*64 + lane] = o;
        }
    }
}

__global__ __launch_bounds__(256) void query_kernel(
    const float* __restrict__ coord,
    const float* __restrict__ cell,
    const float* __restrict__ W0,      // rows 64..67 used here
    const float* __restrict__ W1,      // (64,64)
    const float* __restrict__ b1,      // (64)
    const float* __restrict__ W2,      // (64,3)
    const float* __restrict__ b2,      // (3)
    const float* __restrict__ mod_ws,  // (9216,256)
    const float* __restrict__ f0_ws,   // (9216,64)
    float* __restrict__ out)           // (Q,3)
{
    const int tid = threadIdx.x;
    const int tx  = tid & 15;
    const int ty  = tid >> 4;
    const int bX  = blockIdx.x % 24;
    const int bY  = blockIdx.x / 24;
    const int X   = bX * 16 + tx;
    const int Y   = bY * 16 + ty;
    const int q   = Y * 384 + X;

    const float cy  = coord[q*2 + 0];
    const float cx  = coord[q*2 + 1];
    const float rc0 = cell[q*2 + 0] * 96.0f;
    const float rc1 = cell[q*2 + 1] * 96.0f;

    // per-ensemble tap math -> named scalars (no runtime-indexed arrays)
    int   rm0, rm1, rm2, rm3;
    float r00, r01, r02, r03;
    float r10, r11, r12, r13;
    float a0, a1, a2, a3;
    {
        #define TAPCALC(VX, VY, RM, R0, R1, AR)                                \
        {                                                                      \
            float ey = cy + (VX)*(1.0f/96.0f) + 1e-6f;                         \
            float ex = cx + (VY)*(1.0f/96.0f) + 1e-6f;                         \
            ey = fminf(fmaxf(ey, -1.0f + 1e-6f), 1.0f - 1e-6f);                \
            ex = fminf(fmaxf(ex, -1.0f + 1e-6f), 1.0f - 1e-6f);                \
            int iy = (int)rintf((ey + 1.0f) * 48.0f - 0.5f);                   \
            int ix = (int)rintf((ex + 1.0f) * 48.0f - 0.5f);                   \
            iy = min(max(iy, 0), 95);                                          \
            ix = min(max(ix, 0), 95);                                          \
            const float qy = ((iy + 0.5f) / 96.0f) * 2.0f - 1.0f;              \
            const float qx = ((ix + 0.5f) / 96.0f) * 2.0f - 1.0f;              \
            R0 = (cy - qy) * 96.0f;                                            \
            R1 = (cx - qx) * 96.0f;                                            \
            RM = iy*96 + ix;                                                   \
            AR = fabsf(R0 * R1) + 1e-9f;                                       \
        }
        TAPCALC(-1.0f, -1.0f, rm0, r00, r10, a0)
        TAPCALC(-1.0f,  1.0f, rm1, r01, r11, a1)
        TAPCALC( 1.0f, -1.0f, rm2, r02, r12, a2)
        TAPCALC( 1.0f,  1.0f, rm3, r03, r13, a3)
        #undef TAPCALC
    }

    float oa0 = 0.f, oa1 = 0.f, oa2 = 0.f;

    for (int e = 0; e < 4; ++e) {
        const int   rm  = (e == 0) ? rm0 : (e == 1) ? rm1 : (e == 2) ? rm2 : rm3;
        const float r0  = (e == 0) ? r00 : (e == 1) ? r01 : (e == 2) ? r02 : r03;
        const float r1  = (e == 0) ? r10 : (e == 1) ? r11 : (e == 2) ? r12 : r13;
        const float wgt = (e == 0) ? a3  : (e == 1) ? a2  : (e == 2) ? a1  : a0;

        const float4* F0v  = (const float4*)(f0_ws + (size_t)rm*64);
        const float4* modv = (const float4*)(mod_ws + (size_t)rm*256);
        const float4* w64v = (const float4*)(W0 + 64*64);
        const float4* w65v = (const float4*)(W0 + 65*64);
        const float4* w66v = (const float4*)(W0 + 66*64);
        const float4* w67v = (const float4*)(W0 + 67*64);

        // layer 0 (collapsed) + mod1 + relu -> h[64] in registers
        float h[64];
        #pragma unroll
        for (int n4 = 0; n4 < 16; ++n4) {
            const float4 f  = F0v[n4];
            const float4 a  = w64v[n4];
            const float4 b  = w65v[n4];
            const float4 c  = w66v[n4];
            const float4 d  = w67v[n4];
            const float4 sc = modv[n4];
            const float4 sh = modv[32 + n4];
            float hx = f.x + r0*a.x + r1*b.x + rc0*c.x + rc1*d.x;
            float hy = f.y + r0*a.y + r1*b.y + rc0*c.y + rc1*d.y;
            float hz = f.z + r0*a.z + r1*b.z + rc0*c.z + rc1*d.z;
            float hw = f.w + r0*a.w + r1*b.w + rc0*c.w + rc1*d.w;
            h[n4*4+0] = fmaxf(fmaf(hx, sc.x, sh.x), 0.f);
            h[n4*4+1] = fmaxf(fmaf(hy, sc.y, sh.y), 0.f);
            h[n4*4+2] = fmaxf(fmaf(hz, sc.z, sh.z), 0.f);
            h[n4*4+3] = fmaxf(fmaf(hw, sc.w, sh.w), 0.f);
        }

        // layer 1: fully-unrolled 64x64 register matvec.
        // W1[k*64+n] has wave-uniform literal offsets -> s_load + v_fmac(v,s,v)
        float h2[64];
        #pragma unroll
        for (int n = 0; n < 64; ++n) h2[n] = b1[n];
        #pragma unroll
        for (int k = 0; k < 64; ++k) {
            const float xk = h[k];
            #pragma unroll
            for (int n = 0; n < 64; ++n)
                h2[n] = fmaf(xk, W1[k*64 + n], h2[n]);
        }

        // mod2 + relu + layer 2
        float o0 = b2[0], o1 = b2[1], o2 = b2[2];
        #pragma unroll
        for (int n4 = 0; n4 < 16; ++n4) {
            const float4 sc = modv[16 + n4];
            const float4 sh = modv[48 + n4];
            float v0 = fmaxf(fmaf(h2[n4*4+0], sc.x, sh.x), 0.f);
            float v1 = fmaxf(fmaf(h2[n4*4+1], sc.y, sh.y), 0.f);
            float v2 = fmaxf(fmaf(h2[n4*4+2], sc.z, sh.z), 0.f);
            float v3 = fmaxf(fmaf(h2[n4*4+3], sc.w, sh.w), 0.f);
            const int n0 = n4*4;
            o0 = fmaf(v0, W2[(n0+0)*3+0], o0);
            o1 = fmaf(v0, W2[(n0+0)*3+1], o1);
            o2 = fmaf(v0, W2[(n0+0)*3+2], o2);
            o0 = fmaf(v1, W2[(n0+1)*3+0], o0);
            o1 = fmaf(v1, W2[(n0+1)*3+1], o1);
            o2 = fmaf(v1, W2[(n0+1)*3+2], o2);
            o0 = fmaf(v2, W2[(n0+2)*3+0], o0);
            o1 = fmaf(v2, W2[(n0+2)*3+1], o1);
            o2 = fmaf(v2, W2[(n0+2)*3+2], o2);
            o0 = fmaf(v3, W2[(n0+3)*3+0], o0);
            o1 = fmaf(v3, W2[(n0+3)*3+1], o1);
            o2 = fmaf(v3, W2[(n0+3)*3+2], o2);
        }

        oa0 = fmaf(o0, wgt, oa0);
        oa1 = fmaf(o1, wgt, oa1);
        oa2 = fmaf(o2, wgt, oa2);
    }

    const float inv = 1.0f / (a0 + a1 + a2 + a3);
    out[q*3 + 0] = oa0 * inv;
    out[q*3 + 1] = oa1 * inv;
    out[q*3 + 2] = oa2 * inv;
}

extern "C" void kernel_launch(void* const* d_in, const int* in_sizes, int n_in,
                              void* d_out, int out_size, void* d_ws, size_t ws_size,
                              hipStream_t stream) {
    const float* feat  = (const float*)d_in[0];
    const float* coord = (const float*)d_in[1];
    const float* cell  = (const float*)d_in[2];
    const float* Wh1   = (const float*)d_in[3];
    const float* bh1   = (const float*)d_in[4];
    const float* Wh2   = (const float*)d_in[5];
    const float* bh2   = (const float*)d_in[6];
    const float* W0    = (const float*)d_in[7];
    const float* b0    = (const float*)d_in[8];
    const float* W1    = (const float*)d_in[9];
    const float* b1    = (const float*)d_in[10];
    const float* W2    = (const float*)d_in[11];
    const float* b2    = (const float*)d_in[12];
    float* out = (float*)d_out;

    float* mod_ws = (float*)d_ws;                    // 9216*256 f32 = 9.44 MB
    float* f0_ws  = (float*)d_ws + 9216*256;         // 9216*64  f32 = 2.36 MB

    hyper_kernel<<<dim3(576), dim3(256), 0, stream>>>(
        feat, cell, Wh1, bh1, Wh2, bh2, W0, b0, mod_ws, f0_ws);
    query_kernel<<<dim3(576), dim3(256), 0, stream>>>(
        coord, cell, W0, W1, b1, W2, b2, mod_ws, f0_ws, out);
}

// Round 3
// 183.198 us; speedup vs baseline: 3.0737x; 3.0737x over previous
//
#include <hip/hip_runtime.h>

// LM-LIIF fused pipeline. R2: query layer-1 moved to MFMA (bf16 hi/lo split,
// 3-term product => ~2^-16 relative error, fp32 accumulate).
//
// query_kernel_mfma structure:
//   block = 256 thr = 4 waves; wave = 4x4 query tile; M-tile = 16 rows
//   (4 queries x 4 taps). A-frag (row=lane&15, k=(lane>>4)*8+j) built
//   in-register from collapsed layer0 (F0 gather + rank-1 + mod1 + relu).
//   B-frag = W1 split, loaded once per wave. C (col=lane&15,
//   row=(lane>>4)*4+i) => lane holds 4 taps of one query => mod2 + layer2
//   partials per lane, 16-lane butterfly reduce, area-blend, store.

#define HW 96
#define NPIX (96*96)
#define CFEAT 64

typedef __attribute__((ext_vector_type(8))) short short8;
typedef __attribute__((ext_vector_type(4))) float f32x4;

__device__ __forceinline__ unsigned pack_bf2(float a, float b) {
    unsigned ua = __builtin_bit_cast(unsigned, a);
    unsigned ub = __builtin_bit_cast(unsigned, b);
    return (ua >> 16) | (ub & 0xffff0000u);
}
__device__ __forceinline__ float bf_hi(float a) {
    return __builtin_bit_cast(float, __builtin_bit_cast(unsigned, a) & 0xffff0000u);
}
__device__ __forceinline__ void split8(const float (&v)[8], short8& hi, short8& lo) {
    union { short8 s; unsigned u[4]; } H, L;
    #pragma unroll
    for (int p = 0; p < 4; ++p) {
        float a = v[2*p], b = v[2*p+1];
        H.u[p] = pack_bf2(a, b);
        L.u[p] = pack_bf2(a - bf_hi(a), b - bf_hi(b));
    }
    hi = H.s; lo = L.s;
}

// tap math: given query center (cy,cx) and tap id, produce latent index rm,
// rel coords r0,r1 (x96) and area.
#define TAPCALC(VX, VY, RM, R0, R1, AR)                                \
{                                                                      \
    float ey = cy + (VX)*(1.0f/96.0f) + 1e-6f;                         \
    float ex = cx + (VY)*(1.0f/96.0f) + 1e-6f;                         \
    ey = fminf(fmaxf(ey, -1.0f + 1e-6f), 1.0f - 1e-6f);                \
    ex = fminf(fmaxf(ex, -1.0f + 1e-6f), 1.0f - 1e-6f);                \
    int iy = (int)rintf((ey + 1.0f) * 48.0f - 0.5f);                   \
    int ix = (int)rintf((ex + 1.0f) * 48.0f - 0.5f);                   \
    iy = min(max(iy, 0), 95);                                          \
    ix = min(max(ix, 0), 95);                                          \
    const float qy = ((iy + 0.5f) / 96.0f) * 2.0f - 1.0f;              \
    const float qx = ((ix + 0.5f) / 96.0f) * 2.0f - 1.0f;              \
    R0 = (cy - qy) * 96.0f;                                            \
    R1 = (cx - qx) * 96.0f;                                            \
    RM = iy*96 + ix;                                                   \
    AR = fabsf(R0 * R1) + 1e-9f;                                       \
}

__global__ __launch_bounds__(256) void hyper_kernel(
    const float* __restrict__ feat,
    const float* __restrict__ cell,
    const float* __restrict__ Wh1,   // (578,256)
    const float* __restrict__ bh1,
    const float* __restrict__ Wh2,   // (256,256)
    const float* __restrict__ bh2,
    const float* __restrict__ W0,    // (68,64)
    const float* __restrict__ b0,
    float* __restrict__ mod_ws,      // (9216,256)
    float* __restrict__ f0_ws)       // (9216,64)
{
    __shared__ float patch[CFEAT*54];
    __shared__ float h1s[256*17];

    const int tid = threadIdx.x;
    const int blk = blockIdx.x;
    const int y   = blk / 6;
    const int x0  = (blk % 6) * 16;

    for (int idx = tid; idx < CFEAT*54; idx += 256) {
        int cc = idx / 54;
        int r  = idx % 54;
        int dy = r / 18;
        int xx = r % 18;
        int gy = y + dy - 1;
        int gx = x0 + xx - 1;
        float v = 0.0f;
        if (gy >= 0 && gy < HW && gx >= 0 && gx < HW)
            v = feat[cc*NPIX + gy*HW + gx];
        patch[idx] = v;
    }
    __syncthreads();

    const int lane  = tid & 63;
    const int mg    = tid >> 6;
    const int m0    = mg * 4;
    const int qbase = y*HW + x0;

    {
        float acc[4] = {0.f, 0.f, 0.f, 0.f};
        for (int cc = 0; cc < CFEAT; ++cc) {
            float w = W0[cc*64 + lane];
            const float* p = &patch[cc*54 + 18 + 1 + m0];
            acc[0] = fmaf(p[0], w, acc[0]);
            acc[1] = fmaf(p[1], w, acc[1]);
            acc[2] = fmaf(p[2], w, acc[2]);
            acc[3] = fmaf(p[3], w, acc[3]);
        }
        float bb = b0[lane];
        #pragma unroll
        for (int mi = 0; mi < 4; ++mi)
            f0_ws[(qbase + m0 + mi)*64 + lane] = acc[mi] + bb;
    }

    float acc[4][4];
    #pragma unroll
    for (int i = 0; i < 4; ++i) {
        acc[i][0] = 0.f; acc[i][1] = 0.f; acc[i][2] = 0.f; acc[i][3] = 0.f;
    }
    const float4* Wh1v = (const float4*)Wh1;
    for (int cc = 0; cc < CFEAT; ++cc) {
        #pragma unroll
        for (int dy = 0; dy < 3; ++dy) {
            #pragma unroll
            for (int dx = 0; dx < 3; ++dx) {
                const int k = cc*9 + dy*3 + dx;
                const float4 w = Wh1v[k*64 + lane];
                const float* p = &patch[cc*54 + dy*18 + dx + m0];
                #pragma unroll
                for (int mi = 0; mi < 4; ++mi) {
                    float xv = p[mi];
                    acc[mi][0] = fmaf(xv, w.x, acc[mi][0]);
                    acc[mi][1] = fmaf(xv, w.y, acc[mi][1]);
                    acc[mi][2] = fmaf(xv, w.z, acc[mi][2]);
                    acc[mi][3] = fmaf(xv, w.w, acc[mi][3]);
                }
            }
        }
    }
    {
        const float4 bb   = ((const float4*)bh1)[lane];
        const float4 w576 = Wh1v[576*64 + lane];
        const float4 w577 = Wh1v[577*64 + lane];
        #pragma unroll
        for (int mi = 0; mi < 4; ++mi) {
            const int q = qbase + m0 + mi;
            const float rc0 = cell[q*2+0] * 96.0f;
            const float rc1 = cell[q*2+1] * 96.0f;
            float v0 = acc[mi][0] + bb.x + rc0*w576.x + rc1*w577.x;
            float v1 = acc[mi][1] + bb.y + rc0*w576.y + rc1*w577.y;
            float v2 = acc[mi][2] + bb.z + rc0*w576.z + rc1*w577.z;
            float v3 = acc[mi][3] + bb.w + rc0*w576.w + rc1*w577.w;
            h1s[(4*lane+0)*17 + m0 + mi] = fmaxf(v0, 0.f);
            h1s[(4*lane+1)*17 + m0 + mi] = fmaxf(v1, 0.f);
            h1s[(4*lane+2)*17 + m0 + mi] = fmaxf(v2, 0.f);
            h1s[(4*lane+3)*17 + m0 + mi] = fmaxf(v3, 0.f);
        }
    }
    __syncthreads();

    float acc2[4][4];
    #pragma unroll
    for (int i = 0; i < 4; ++i) {
        acc2[i][0] = 0.f; acc2[i][1] = 0.f; acc2[i][2] = 0.f; acc2[i][3] = 0.f;
    }
    const float4* Wh2v = (const float4*)Wh2;
    for (int k = 0; k < 256; ++k) {
        const float4 w = Wh2v[k*64 + lane];
        const float* p = &h1s[k*17 + m0];
        #pragma unroll
        for (int mi = 0; mi < 4; ++mi) {
            float xv = p[mi];
            acc2[mi][0] = fmaf(xv, w.x, acc2[mi][0]);
            acc2[mi][1] = fmaf(xv, w.y, acc2[mi][1]);
            acc2[mi][2] = fmaf(xv, w.z, acc2[mi][2]);
            acc2[mi][3] = fmaf(xv, w.w, acc2[mi][3]);
        }
    }
    {
        const float4 bb = ((const float4*)bh2)[lane];
        #pragma unroll
        for (int mi = 0; mi < 4; ++mi) {
            const int q = qbase + m0 + mi;
            float4 o;
            o.x = acc2[mi][0] + bb.x;
            o.y = acc2[mi][1] + bb.y;
            o.z = acc2[mi][2] + bb.z;
            o.w = acc2[mi][3] + bb.w;
            ((float4*)mod_ws)[q*64 + lane] = o;
        }
    }
}

__global__ __launch_bounds__(256) void query_kernel_mfma(
    const float* __restrict__ coord,
    const float* __restrict__ cell,
    const float* __restrict__ W0,      // (68,64); rows 64..67 used
    const float* __restrict__ W1,      // (64,64)
    const float* __restrict__ b1,      // (64)
    const float* __restrict__ W2,      // (64,3)
    const float* __restrict__ b2,      // (3)
    const float* __restrict__ mod_ws,  // (9216,256)
    const float* __restrict__ f0_ws,   // (9216,64)
    float* __restrict__ out)           // (Q,3)
{
    const int tid  = threadIdx.x;
    const int lane = tid & 63;
    const int wid  = tid >> 6;
    const int bX   = blockIdx.x % 48;
    const int bY   = blockIdx.x / 48;
    const int X0   = bX*8 + (wid & 1)*4;
    const int Y0   = bY*8 + (wid >> 1)*4;

    const int c  = lane & 15;   // A-row / C-col within tile
    const int kg = lane >> 4;   // k-group (8 contiguous k)

    // ---- one-time per-wave preloads ----
    // W1 fragments, split hi/lo: B[k][n], frag(nt,kt): k=kt*32+kg*8+j, n=nt*16+c
    short8 Bhi[4][2], Blo[4][2];
    #pragma unroll
    for (int nt = 0; nt < 4; ++nt) {
        #pragma unroll
        for (int kt = 0; kt < 2; ++kt) {
            float wv[8];
            #pragma unroll
            for (int j = 0; j < 8; ++j)
                wv[j] = W1[(kt*32 + kg*8 + j)*64 + nt*16 + c];
            split8(wv, Bhi[nt][kt], Blo[nt][kt]);
        }
    }
    // W0 rows 64..67, k-slice per lane
    float wr64[2][8], wr65[2][8], wr66[2][8], wr67[2][8];
    #pragma unroll
    for (int kt = 0; kt < 2; ++kt) {
        const int kb = kt*32 + kg*8;
        #pragma unroll
        for (int j = 0; j < 8; ++j) {
            wr64[kt][j] = W0[64*64 + kb + j];
            wr65[kt][j] = W0[65*64 + kb + j];
            wr66[kt][j] = W0[66*64 + kb + j];
            wr67[kt][j] = W0[67*64 + kb + j];
        }
    }
    // b1 per C-col, W2 rows for this lane's 4 cols, b2
    float b1c[4];
    float w2r[4][3];
    #pragma unroll
    for (int nt = 0; nt < 4; ++nt) {
        b1c[nt] = b1[nt*16 + c];
        w2r[nt][0] = W2[(nt*16 + c)*3 + 0];
        w2r[nt][1] = W2[(nt*16 + c)*3 + 1];
        w2r[nt][2] = W2[(nt*16 + c)*3 + 2];
    }
    const float b2v0 = b2[0], b2v1 = b2[1], b2v2 = b2[2];

    // A-phase row identity (fixed per lane): row = c -> (qxA, tapA)
    const int qxA  = (c >> 2);
    const int tapA = (c & 3);
    const float vxA = (tapA < 2) ? -1.0f : 1.0f;
    const float vyA = (tapA & 1) ? 1.0f : -1.0f;

    for (int m = 0; m < 4; ++m) {
        // ================= A-build =================
        short8 Ahi[2], Alo[2];
        {
            const int qA = (Y0 + m)*384 + (X0 + qxA);
            const float cy  = coord[qA*2 + 0];
            const float cx  = coord[qA*2 + 1];
            const float rc0 = cell[qA*2 + 0] * 96.0f;
            const float rc1 = cell[qA*2 + 1] * 96.0f;
            int rmA; float r0A, r1A, arA;
            TAPCALC(vxA, vyA, rmA, r0A, r1A, arA)
            (void)arA;
            #pragma unroll
            for (int kt = 0; kt < 2; ++kt) {
                const int kb = kt*32 + kg*8;
                const float4 f0a = *(const float4*)(f0_ws + (size_t)rmA*64 + kb);
                const float4 f0b = *(const float4*)(f0_ws + (size_t)rmA*64 + kb + 4);
                const float4 s1a = *(const float4*)(mod_ws + (size_t)rmA*256 + kb);
                const float4 s1b = *(const float4*)(mod_ws + (size_t)rmA*256 + kb + 4);
                const float4 t1a = *(const float4*)(mod_ws + (size_t)rmA*256 + 128 + kb);
                const float4 t1b = *(const float4*)(mod_ws + (size_t)rmA*256 + 128 + kb + 4);
                float f0[8]  = {f0a.x,f0a.y,f0a.z,f0a.w,f0b.x,f0b.y,f0b.z,f0b.w};
                float sc1[8] = {s1a.x,s1a.y,s1a.z,s1a.w,s1b.x,s1b.y,s1b.z,s1b.w};
                float sh1[8] = {t1a.x,t1a.y,t1a.z,t1a.w,t1b.x,t1b.y,t1b.z,t1b.w};
                float hv[8];
                #pragma unroll
                for (int j = 0; j < 8; ++j) {
                    float pre = f0[j];
                    pre = fmaf(r0A, wr64[kt][j], pre);
                    pre = fmaf(r1A, wr65[kt][j], pre);
                    pre = fmaf(rc0, wr66[kt][j], pre);
                    pre = fmaf(rc1, wr67[kt][j], pre);
                    hv[j] = fmaxf(fmaf(pre, sc1[j], sh1[j]), 0.f);
                }
                split8(hv, Ahi[kt], Alo[kt]);
            }
        }

        // ================= MFMA: h(16x64) @ W1(64x64) =================
        f32x4 acc[4];
        #pragma unroll
        for (int nt = 0; nt < 4; ++nt) {
            f32x4 a0 = {b1c[nt], b1c[nt], b1c[nt], b1c[nt]};
            acc[nt] = a0;
        }
        #pragma unroll
        for (int nt = 0; nt < 4; ++nt) {
            #pragma unroll
            for (int kt = 0; kt < 2; ++kt) {
                acc[nt] = __builtin_amdgcn_mfma_f32_16x16x32_bf16(Ahi[kt], Bhi[nt][kt], acc[nt], 0, 0, 0);
                acc[nt] = __builtin_amdgcn_mfma_f32_16x16x32_bf16(Ahi[kt], Blo[nt][kt], acc[nt], 0, 0, 0);
                acc[nt] = __builtin_amdgcn_mfma_f32_16x16x32_bf16(Alo[kt], Bhi[nt][kt], acc[nt], 0, 0, 0);
            }
        }

        // ================= epilogue =================
        // lane's C elements: row = kg*4 + i  -> query (Y0+m, X0+kg), tap i
        const int qE = (Y0 + m)*384 + (X0 + kg);
        const float cy  = coord[qE*2 + 0];
        const float cx  = coord[qE*2 + 1];
        int rm0, rm1, rm2, rm3;
        float r00, r01, r02, r03, r10, r11, r12, r13, a0, a1, a2, a3;
        TAPCALC(-1.0f, -1.0f, rm0, r00, r10, a0)
        TAPCALC(-1.0f,  1.0f, rm1, r01, r11, a1)
        TAPCALC( 1.0f, -1.0f, rm2, r02, r12, a2)
        TAPCALC( 1.0f,  1.0f, rm3, r03, r13, a3)

        float p0[3] = {0.f,0.f,0.f}, p1[3] = {0.f,0.f,0.f};
        float p2[3] = {0.f,0.f,0.f}, p3[3] = {0.f,0.f,0.f};
        #pragma unroll
        for (int nt = 0; nt < 4; ++nt) {
            const int colOff = 64 + nt*16 + c;   // scale2 offset
            #pragma unroll
            for (int i = 0; i < 4; ++i) {
                const int rmi = (i == 0) ? rm0 : (i == 1) ? rm1 : (i == 2) ? rm2 : rm3;
                const float sc2 = mod_ws[(size_t)rmi*256 + colOff];
                const float sh2 = mod_ws[(size_t)rmi*256 + colOff + 128];
                const float v = fmaxf(fmaf(acc[nt][i], sc2, sh2), 0.f);
                float* pp = (i == 0) ? p0 : (i == 1) ? p1 : (i == 2) ? p2 : p3;
                pp[0] = fmaf(v, w2r[nt][0], pp[0]);
                pp[1] = fmaf(v, w2r[nt][1], pp[1]);
                pp[2] = fmaf(v, w2r[nt][2], pp[2]);
            }
        }
        // butterfly reduce over the 16 lanes sharing this query (lanes kg*16..kg*16+15)
        #pragma unroll
        for (int d = 1; d < 16; d <<= 1) {
            #pragma unroll
            for (int j = 0; j < 3; ++j) {
                p0[j] += __shfl_xor(p0[j], d);
                p1[j] += __shfl_xor(p1[j], d);
                p2[j] += __shfl_xor(p2[j], d);
                p3[j] += __shfl_xor(p3[j], d);
            }
        }
        // area blend (diagonal swap): pred_i weighted by area[3-i]
        const float invt = 1.0f / (a0 + a1 + a2 + a3);
        const float o0 = fmaf(p0[0], a3, fmaf(p1[0], a2, fmaf(p2[0], a1, p3[0]*a0))) * invt + b2v0;
        const float o1 = fmaf(p0[1], a3, fmaf(p1[1], a2, fmaf(p2[1], a1, p3[1]*a0))) * invt + b2v1;
        const float o2 = fmaf(p0[2], a3, fmaf(p1[2], a2, fmaf(p2[2], a1, p3[2]*a0))) * invt + b2v2;
        if (c < 3)
            out[(size_t)qE*3 + c] = (c == 0) ? o0 : (c == 1) ? o1 : o2;
    }
}

extern "C" void kernel_launch(void* const* d_in, const int* in_sizes, int n_in,
                              void* d_out, int out_size, void* d_ws, size_t ws_size,
                              hipStream_t stream) {
    const float* feat  = (const float*)d_in[0];
    const float* coord = (const float*)d_in[1];
    const float* cell  = (const float*)d_in[2];
    const float* Wh1   = (const float*)d_in[3];
    const float* bh1   = (const float*)d_in[4];
    const float* Wh2   = (const float*)d_in[5];
    const float* bh2   = (const float*)d_in[6];
    const float* W0    = (const float*)d_in[7];
    const float* b0    = (const float*)d_in[8];
    const float* W1    = (const float*)d_in[9];
    const float* b1    = (const float*)d_in[10];
    const float* W2    = (const float*)d_in[11];
    const float* b2    = (const float*)d_in[12];
    float* out = (float*)d_out;

    float* mod_ws = (float*)d_ws;                    // 9216*256 f32
    float* f0_ws  = (float*)d_ws + 9216*256;         // 9216*64  f32

    hyper_kernel<<<dim3(576), dim3(256), 0, stream>>>(
        feat, cell, Wh1, bh1, Wh2, bh2, W0, b0, mod_ws, f0_ws);
    query_kernel_mfma<<<dim3(2304), dim3(256), 0, stream>>>(
        coord, cell, W0, W1, b1, W2, b2, mod_ws, f0_ws, out);
}

// Round 4
// 156.876 us; speedup vs baseline: 3.5894x; 1.1678x over previous
//
#include <hip/hip_runtime.h>

// LM-LIIF fused pipeline. R3: query kernel v3 —
//  - block = 16x16 query tile (576 blocks); 6x6 latent patch [f0|mod] staged
//    in LDS (rows padded to 324 floats -> <=2-way bank conflicts), all
//    A-build + epilogue gathers now LDS with cheap addresses.
//  - area weights folded before butterfly reduce (3 values, not 12).
//  - layer1 MFMA: exact A hi/lo split x RNE-bf16 W1 (2 MFMAs per nt,kt).

#define HW 96
#define NPIX (96*96)
#define CFEAT 64

typedef __attribute__((ext_vector_type(8))) short short8;
typedef __attribute__((ext_vector_type(4))) float f32x4;

__device__ __forceinline__ unsigned pack_bf2(float a, float b) {
    unsigned ua = __builtin_bit_cast(unsigned, a);
    unsigned ub = __builtin_bit_cast(unsigned, b);
    return (ua >> 16) | (ub & 0xffff0000u);
}
__device__ __forceinline__ float bf_hi(float a) {
    return __builtin_bit_cast(float, __builtin_bit_cast(unsigned, a) & 0xffff0000u);
}
__device__ __forceinline__ void split8(const float (&v)[8], short8& hi, short8& lo) {
    union { short8 s; unsigned u[4]; } H, L;
    #pragma unroll
    for (int p = 0; p < 4; ++p) {
        float a = v[2*p], b = v[2*p+1];
        H.u[p] = pack_bf2(a, b);
        L.u[p] = pack_bf2(a - bf_hi(a), b - bf_hi(b));
    }
    hi = H.s; lo = L.s;
}
__device__ __forceinline__ unsigned rne16(float x) {
    unsigned u = __builtin_bit_cast(unsigned, x);
    return (u + 0x7fffu + ((u >> 16) & 1u)) >> 16;
}
__device__ __forceinline__ unsigned pack_bf2_rne(float a, float b) {
    return rne16(a) | (rne16(b) << 16);
}

// tap math incl. integer latent coords for LDS-local indexing
#define TAPCALC2(VX, VY, IY, IX, R0, R1, AR)                           \
{                                                                      \
    float ey = cy + (VX)*(1.0f/96.0f) + 1e-6f;                         \
    float ex = cx + (VY)*(1.0f/96.0f) + 1e-6f;                         \
    ey = fminf(fmaxf(ey, -1.0f + 1e-6f), 1.0f - 1e-6f);                \
    ex = fminf(fmaxf(ex, -1.0f + 1e-6f), 1.0f - 1e-6f);                \
    IY = (int)rintf((ey + 1.0f) * 48.0f - 0.5f);                       \
    IX = (int)rintf((ex + 1.0f) * 48.0f - 0.5f);                       \
    IY = min(max(IY, 0), 95);                                          \
    IX = min(max(IX, 0), 95);                                          \
    const float qy_ = ((IY + 0.5f) / 96.0f) * 2.0f - 1.0f;             \
    const float qx_ = ((IX + 0.5f) / 96.0f) * 2.0f - 1.0f;             \
    R0 = (cy - qy_) * 96.0f;                                           \
    R1 = (cx - qx_) * 96.0f;                                           \
    AR = fabsf(R0 * R1) + 1e-9f;                                       \
}

__global__ __launch_bounds__(256) void hyper_kernel(
    const float* __restrict__ feat,
    const float* __restrict__ cell,
    const float* __restrict__ Wh1,   // (578,256)
    const float* __restrict__ bh1,
    const float* __restrict__ Wh2,   // (256,256)
    const float* __restrict__ bh2,
    const float* __restrict__ W0,    // (68,64)
    const float* __restrict__ b0,
    float* __restrict__ mod_ws,      // (9216,256)
    float* __restrict__ f0_ws)       // (9216,64)
{
    __shared__ float patch[CFEAT*54];
    __shared__ float h1s[256*17];

    const int tid = threadIdx.x;
    const int blk = blockIdx.x;
    const int y   = blk / 6;
    const int x0  = (blk % 6) * 16;

    for (int idx = tid; idx < CFEAT*54; idx += 256) {
        int cc = idx / 54;
        int r  = idx % 54;
        int dy = r / 18;
        int xx = r % 18;
        int gy = y + dy - 1;
        int gx = x0 + xx - 1;
        float v = 0.0f;
        if (gy >= 0 && gy < HW && gx >= 0 && gx < HW)
            v = feat[cc*NPIX + gy*HW + gx];
        patch[idx] = v;
    }
    __syncthreads();

    const int lane  = tid & 63;
    const int mg    = tid >> 6;
    const int m0    = mg * 4;
    const int qbase = y*HW + x0;

    {
        float acc[4] = {0.f, 0.f, 0.f, 0.f};
        for (int cc = 0; cc < CFEAT; ++cc) {
            float w = W0[cc*64 + lane];
            const float* p = &patch[cc*54 + 18 + 1 + m0];
            acc[0] = fmaf(p[0], w, acc[0]);
            acc[1] = fmaf(p[1], w, acc[1]);
            acc[2] = fmaf(p[2], w, acc[2]);
            acc[3] = fmaf(p[3], w, acc[3]);
        }
        float bb = b0[lane];
        #pragma unroll
        for (int mi = 0; mi < 4; ++mi)
            f0_ws[(qbase + m0 + mi)*64 + lane] = acc[mi] + bb;
    }

    float acc[4][4];
    #pragma unroll
    for (int i = 0; i < 4; ++i) {
        acc[i][0] = 0.f; acc[i][1] = 0.f; acc[i][2] = 0.f; acc[i][3] = 0.f;
    }
    const float4* Wh1v = (const float4*)Wh1;
    for (int cc = 0; cc < CFEAT; ++cc) {
        #pragma unroll
        for (int dy = 0; dy < 3; ++dy) {
            #pragma unroll
            for (int dx = 0; dx < 3; ++dx) {
                const int k = cc*9 + dy*3 + dx;
                const float4 w = Wh1v[k*64 + lane];
                const float* p = &patch[cc*54 + dy*18 + dx + m0];
                #pragma unroll
                for (int mi = 0; mi < 4; ++mi) {
                    float xv = p[mi];
                    acc[mi][0] = fmaf(xv, w.x, acc[mi][0]);
                    acc[mi][1] = fmaf(xv, w.y, acc[mi][1]);
                    acc[mi][2] = fmaf(xv, w.z, acc[mi][2]);
                    acc[mi][3] = fmaf(xv, w.w, acc[mi][3]);
                }
            }
        }
    }
    {
        const float4 bb   = ((const float4*)bh1)[lane];
        const float4 w576 = Wh1v[576*64 + lane];
        const float4 w577 = Wh1v[577*64 + lane];
        #pragma unroll
        for (int mi = 0; mi < 4; ++mi) {
            const int q = qbase + m0 + mi;
            const float rc0 = cell[q*2+0] * 96.0f;
            const float rc1 = cell[q*2+1] * 96.0f;
            float v0 = acc[mi][0] + bb.x + rc0*w576.x + rc1*w577.x;
            float v1 = acc[mi][1] + bb.y + rc0*w576.y + rc1*w577.y;
            float v2 = acc[mi][2] + bb.z + rc0*w576.z + rc1*w577.z;
            float v3 = acc[mi][3] + bb.w + rc0*w576.w + rc1*w577.w;
            h1s[(4*lane+0)*17 + m0 + mi] = fmaxf(v0, 0.f);
            h1s[(4*lane+1)*17 + m0 + mi] = fmaxf(v1, 0.f);
            h1s[(4*lane+2)*17 + m0 + mi] = fmaxf(v2, 0.f);
            h1s[(4*lane+3)*17 + m0 + mi] = fmaxf(v3, 0.f);
        }
    }
    __syncthreads();

    float acc2[4][4];
    #pragma unroll
    for (int i = 0; i < 4; ++i) {
        acc2[i][0] = 0.f; acc2[i][1] = 0.f; acc2[i][2] = 0.f; acc2[i][3] = 0.f;
    }
    const float4* Wh2v = (const float4*)Wh2;
    for (int k = 0; k < 256; ++k) {
        const float4 w = Wh2v[k*64 + lane];
        const float* p = &h1s[k*17 + m0];
        #pragma unroll
        for (int mi = 0; mi < 4; ++mi) {
            float xv = p[mi];
            acc2[mi][0] = fmaf(xv, w.x, acc2[mi][0]);
            acc2[mi][1] = fmaf(xv, w.y, acc2[mi][1]);
            acc2[mi][2] = fmaf(xv, w.z, acc2[mi][2]);
            acc2[mi][3] = fmaf(xv, w.w, acc2[mi][3]);
        }
    }
    {
        const float4 bb = ((const float4*)bh2)[lane];
        #pragma unroll
        for (int mi = 0; mi < 4; ++mi) {
            const int q = qbase + m0 + mi;
            float4 o;
            o.x = acc2[mi][0] + bb.x;
            o.y = acc2[mi][1] + bb.y;
            o.z = acc2[mi][2] + bb.z;
            o.w = acc2[mi][3] + bb.w;
            ((float4*)mod_ws)[q*64 + lane] = o;
        }
    }
}

// LDS row layout per latent pixel: [f0(64) | mod(256)] padded to 324 floats.
//  sc1 = mod[0:64]   -> off  64..127
//  sc2 = mod[64:128] -> off 128..191
//  sh1 = mod[128:192]-> off 192..255
//  sh2 = mod[192:256]-> off 256..319
#define ROWP 324

__global__ __launch_bounds__(256) void query_kernel_v3(
    const float* __restrict__ coord,
    const float* __restrict__ cell,
    const float* __restrict__ W0,      // rows 64..67 used
    const float* __restrict__ W1,      // (64,64)
    const float* __restrict__ b1,
    const float* __restrict__ W2,      // (64,3)
    const float* __restrict__ b2,
    const float* __restrict__ mod_ws,  // (9216,256)
    const float* __restrict__ f0_ws,   // (9216,64)
    float* __restrict__ out)
{
    __shared__ float smem[36*ROWP];    // 46.6 KB

    const int tid = threadIdx.x;
    const int bX  = blockIdx.x % 24;
    const int bY  = blockIdx.x / 24;
    const int X0  = bX * 16;
    const int Y0  = bY * 16;
    const int lx0 = bX*4 - 1;
    const int ly0 = bY*4 - 1;

    // ---- stage 6x6 latent patch: 36 rows x 80 float4 ----
    for (int idx = tid; idx < 2880; idx += 256) {
        const int r  = idx / 80;
        const int o  = idx - r*80;
        const int ry = r / 6;
        const int rx = r - ry*6;
        const int gy = min(max(ly0 + ry, 0), 95);
        const int gx = min(max(lx0 + rx, 0), 95);
        const int src = gy*96 + gx;
        float4 v;
        int dst;
        if (o < 16) {
            v = ((const float4*)(f0_ws + (size_t)src*64))[o];
            dst = r*ROWP + o*4;
        } else {
            v = ((const float4*)(mod_ws + (size_t)src*256))[o - 16];
            dst = r*ROWP + 64 + (o - 16)*4;
        }
        *(float4*)(smem + dst) = v;
    }

    const int lane = tid & 63;
    const int wid  = tid >> 6;
    const int c    = lane & 15;
    const int kg   = lane >> 4;

    // ---- per-wave constant preloads ----
    short8 Bh[4][2];                    // W1 RNE-bf16
    #pragma unroll
    for (int nt = 0; nt < 4; ++nt) {
        #pragma unroll
        for (int kt = 0; kt < 2; ++kt) {
            union { short8 s; unsigned u[4]; } H;
            #pragma unroll
            for (int p = 0; p < 4; ++p) {
                float a = W1[(kt*32 + kg*8 + 2*p    )*64 + nt*16 + c];
                float b = W1[(kt*32 + kg*8 + 2*p + 1)*64 + nt*16 + c];
                H.u[p] = pack_bf2_rne(a, b);
            }
            Bh[nt][kt] = H.s;
        }
    }
    float wr64[2][8], wr65[2][8], wr66[2][8], wr67[2][8];
    #pragma unroll
    for (int kt = 0; kt < 2; ++kt) {
        const int kb = kt*32 + kg*8;
        #pragma unroll
        for (int j = 0; j < 8; ++j) {
            wr64[kt][j] = W0[64*64 + kb + j];
            wr65[kt][j] = W0[65*64 + kb + j];
            wr66[kt][j] = W0[66*64 + kb + j];
            wr67[kt][j] = W0[67*64 + kb + j];
        }
    }
    float b1c[4];
    float w2r[4][3];
    #pragma unroll
    for (int nt = 0; nt < 4; ++nt) {
        b1c[nt] = b1[nt*16 + c];
        w2r[nt][0] = W2[(nt*16 + c)*3 + 0];
        w2r[nt][1] = W2[(nt*16 + c)*3 + 1];
        w2r[nt][2] = W2[(nt*16 + c)*3 + 2];
    }
    const float b2v0 = b2[0], b2v1 = b2[1], b2v2 = b2[2];

    __syncthreads();

    const int Xw   = X0 + wid*4;
    const int qxA  = c >> 2;
    const int tapA = c & 3;
    const float vxA = (tapA < 2) ? -1.0f : 1.0f;
    const float vyA = (tapA & 1) ? 1.0f : -1.0f;
    const float2* coordv = (const float2*)coord;
    const float2* cellv  = (const float2*)cell;

    for (int m = 0; m < 16; ++m) {
        const int qy = Y0 + m;

        // ================= A-build (from LDS) =================
        short8 Ahi[2], Alo[2];
        {
            const int qA = qy*384 + Xw + qxA;
            const float2 cv = coordv[qA];
            const float2 ce = cellv[qA];
            const float cy = cv.x, cx = cv.y;
            const float rc0 = ce.x * 96.0f;
            const float rc1 = ce.y * 96.0f;
            int iyA, ixA; float r0A, r1A, arA;
            TAPCALC2(vxA, vyA, iyA, ixA, r0A, r1A, arA)
            (void)arA;
            const float* rowp = smem + ((iyA - ly0)*6 + (ixA - lx0)) * ROWP;
            #pragma unroll
            for (int kt = 0; kt < 2; ++kt) {
                const int kb = kt*32 + kg*8;
                const float4 f0a = *(const float4*)(rowp + kb);
                const float4 f0b = *(const float4*)(rowp + kb + 4);
                const float4 s1a = *(const float4*)(rowp + 64 + kb);
                const float4 s1b = *(const float4*)(rowp + 64 + kb + 4);
                const float4 t1a = *(const float4*)(rowp + 192 + kb);
                const float4 t1b = *(const float4*)(rowp + 192 + kb + 4);
                float f0[8]  = {f0a.x,f0a.y,f0a.z,f0a.w,f0b.x,f0b.y,f0b.z,f0b.w};
                float sc1[8] = {s1a.x,s1a.y,s1a.z,s1a.w,s1b.x,s1b.y,s1b.z,s1b.w};
                float sh1[8] = {t1a.x,t1a.y,t1a.z,t1a.w,t1b.x,t1b.y,t1b.z,t1b.w};
                float hv[8];
                #pragma unroll
                for (int j = 0; j < 8; ++j) {
                    float pre = f0[j];
                    pre = fmaf(r0A, wr64[kt][j], pre);
                    pre = fmaf(r1A, wr65[kt][j], pre);
                    pre = fmaf(rc0, wr66[kt][j], pre);
                    pre = fmaf(rc1, wr67[kt][j], pre);
                    hv[j] = fmaxf(fmaf(pre, sc1[j], sh1[j]), 0.f);
                }
                split8(hv, Ahi[kt], Alo[kt]);
            }
        }

        // ================= MFMA =================
        f32x4 acc[4];
        #pragma unroll
        for (int nt = 0; nt < 4; ++nt) {
            f32x4 a0 = {b1c[nt], b1c[nt], b1c[nt], b1c[nt]};
            acc[nt] = a0;
        }
        #pragma unroll
        for (int nt = 0; nt < 4; ++nt) {
            #pragma unroll
            for (int kt = 0; kt < 2; ++kt) {
                acc[nt] = __builtin_amdgcn_mfma_f32_16x16x32_bf16(Ahi[kt], Bh[nt][kt], acc[nt], 0, 0, 0);
                acc[nt] = __builtin_amdgcn_mfma_f32_16x16x32_bf16(Alo[kt], Bh[nt][kt], acc[nt], 0, 0, 0);
            }
        }

        // ================= epilogue =================
        const int qE = qy*384 + Xw + kg;
        const float2 cv = coordv[qE];
        const float cy = cv.x, cx = cv.y;
        int iy0,ix0,iy1,ix1,iy2,ix2,iy3,ix3;
        float r00,r10,r01,r11,r02,r12,r03,r13, a0,a1,a2,a3;
        TAPCALC2(-1.0f, -1.0f, iy0, ix0, r00, r10, a0)
        TAPCALC2(-1.0f,  1.0f, iy1, ix1, r01, r11, a1)
        TAPCALC2( 1.0f, -1.0f, iy2, ix2, r02, r12, a2)
        TAPCALC2( 1.0f,  1.0f, iy3, ix3, r03, r13, a3)
        const int lr0 = (iy0 - ly0)*6 + (ix0 - lx0);
        const int lr1 = (iy1 - ly0)*6 + (ix1 - lx0);
        const int lr2 = (iy2 - ly0)*6 + (ix2 - lx0);
        const int lr3 = (iy3 - ly0)*6 + (ix3 - lx0);
        const float invt = 1.0f / (a0 + a1 + a2 + a3);
        const float w0_ = a3 * invt, w1_ = a2 * invt, w2_ = a1 * invt, w3_ = a0 * invt;

        float p0 = 0.f, p1 = 0.f, p2 = 0.f;
        #pragma unroll
        for (int i = 0; i < 4; ++i) {
            const int   lri = (i == 0) ? lr0 : (i == 1) ? lr1 : (i == 2) ? lr2 : lr3;
            const float wi  = (i == 0) ? w0_ : (i == 1) ? w1_ : (i == 2) ? w2_ : w3_;
            const float* rp = smem + lri*ROWP;
            float s0 = 0.f, s1 = 0.f, s2 = 0.f;
            #pragma unroll
            for (int nt = 0; nt < 4; ++nt) {
                const float sc2 = rp[128 + nt*16 + c];
                const float sh2 = rp[256 + nt*16 + c];
                const float v = fmaxf(fmaf(acc[nt][i], sc2, sh2), 0.f);
                s0 = fmaf(v, w2r[nt][0], s0);
                s1 = fmaf(v, w2r[nt][1], s1);
                s2 = fmaf(v, w2r[nt][2], s2);
            }
            p0 = fmaf(s0, wi, p0);
            p1 = fmaf(s1, wi, p1);
            p2 = fmaf(s2, wi, p2);
        }
        #pragma unroll
        for (int d = 1; d < 16; d <<= 1) {
            p0 += __shfl_xor(p0, d);
            p1 += __shfl_xor(p1, d);
            p2 += __shfl_xor(p2, d);
        }
        if (c < 3) {
            const float ov = (c == 0) ? p0 + b2v0 : (c == 1) ? p1 + b2v1 : p2 + b2v2;
            out[(size_t)qE*3 + c] = ov;
        }
    }
}

extern "C" void kernel_launch(void* const* d_in, const int* in_sizes, int n_in,
                              void* d_out, int out_size, void* d_ws, size_t ws_size,
                              hipStream_t stream) {
    const float* feat  = (const float*)d_in[0];
    const float* coord = (const float*)d_in[1];
    const float* cell  = (const float*)d_in[2];
    const float* Wh1   = (const float*)d_in[3];
    const float* bh1   = (const float*)d_in[4];
    const float* Wh2   = (const float*)d_in[5];
    const float* bh2   = (const float*)d_in[6];
    const float* W0    = (const float*)d_in[7];
    const float* b0    = (const float*)d_in[8];
    const float* W1    = (const float*)d_in[9];
    const float* b1    = (const float*)d_in[10];
    const float* W2    = (const float*)d_in[11];
    const float* b2    = (const float*)d_in[12];
    float* out = (float*)d_out;

    float* mod_ws = (float*)d_ws;                    // 9216*256 f32
    float* f0_ws  = (float*)d_ws + 9216*256;         // 9216*64  f32

    hyper_kernel<<<dim3(576), dim3(256), 0, stream>>>(
        feat, cell, Wh1, bh1, Wh2, bh2, W0, b0, mod_ws, f0_ws);
    query_kernel_v3<<<dim3(576), dim3(256), 0, stream>>>(
        coord, cell, W0, W1, b1, W2, b2, mod_ws, f0_ws, out);
}

// Round 5
// 141.891 us; speedup vs baseline: 3.9685x; 1.1056x over previous
//
#include <hip/hip_runtime.h>

// LM-LIIF fused pipeline. R4: hyper net moved to MFMA.
//  - swizzle_kernel: pre-packs Wh1/Wh2/W0(rows0-63) into fragment-ordered
//    split-bf16 (hi+lo) so GEMM B-loads are coalesced 16B dwordx4.
//  - hyper_mfma: block = 16-px strip, 4 waves (wave = N-slice of 64).
//    im2col tile [576][16] in LDS (pair-interleaved: elem (k,px) at
//    (k>>1)*34 + px*2 + (k&1)) -> A-frags are 4x ds_read_b64, <=2-way banks.
//    F0 (K=64), layer1 (K=576) + rel_cell rank-1 epilogue, h1 -> pair-LDS,
//    layer2 (K=256). All GEMMs 3-MFMA hi/lo split (validated in query).
//  - query_kernel_v3 unchanged.

#define HW 96
#define NPIX (96*96)
#define CFEAT 64

typedef __attribute__((ext_vector_type(8))) short short8;
typedef __attribute__((ext_vector_type(4))) float f32x4;

__device__ __forceinline__ unsigned pack_bf2(float a, float b) {
    unsigned ua = __builtin_bit_cast(unsigned, a);
    unsigned ub = __builtin_bit_cast(unsigned, b);
    return (ua >> 16) | (ub & 0xffff0000u);
}
__device__ __forceinline__ float bf_hi(float a) {
    return __builtin_bit_cast(float, __builtin_bit_cast(unsigned, a) & 0xffff0000u);
}
__device__ __forceinline__ void split8(const float (&v)[8], short8& hi, short8& lo) {
    union { short8 s; unsigned u[4]; } H, L;
    #pragma unroll
    for (int p = 0; p < 4; ++p) {
        float a = v[2*p], b = v[2*p+1];
        H.u[p] = pack_bf2(a, b);
        L.u[p] = pack_bf2(a - bf_hi(a), b - bf_hi(b));
    }
    hi = H.s; lo = L.s;
}
__device__ __forceinline__ unsigned rne16(float x) {
    unsigned u = __builtin_bit_cast(unsigned, x);
    return (u + 0x7fffu + ((u >> 16) & 1u)) >> 16;
}
__device__ __forceinline__ unsigned pack_bf2_rne(float a, float b) {
    return rne16(a) | (rne16(b) << 16);
}

#define TAPCALC2(VX, VY, IY, IX, R0, R1, AR)                           \
{                                                                      \
    float ey = cy + (VX)*(1.0f/96.0f) + 1e-6f;                         \
    float ex = cx + (VY)*(1.0f/96.0f) + 1e-6f;                         \
    ey = fminf(fmaxf(ey, -1.0f + 1e-6f), 1.0f - 1e-6f);                \
    ex = fminf(fmaxf(ex, -1.0f + 1e-6f), 1.0f - 1e-6f);                \
    IY = (int)rintf((ey + 1.0f) * 48.0f - 0.5f);                       \
    IX = (int)rintf((ex + 1.0f) * 48.0f - 0.5f);                       \
    IY = min(max(IY, 0), 95);                                          \
    IX = min(max(IX, 0), 95);                                          \
    const float qy_ = ((IY + 0.5f) / 96.0f) * 2.0f - 1.0f;             \
    const float qx_ = ((IX + 0.5f) / 96.0f) * 2.0f - 1.0f;             \
    R0 = (cy - qy_) * 96.0f;                                           \
    R1 = (cx - qx_) * 96.0f;                                           \
    AR = fabsf(R0 * R1) + 1e-9f;                                       \
}

// ---------------- weight pre-swizzle ----------------
// frag layout per frag (1024 shorts): hi[lane*8..] at +0, lo at +512.
// wh1f: 288 frags (kt 0..17, nt 0..15), wh2f: 128 (kt 0..7), w0f: 8 (kt 0..1, nt 0..3)
__global__ __launch_bounds__(256) void swizzle_kernel(
    const float* __restrict__ Wh1, const float* __restrict__ Wh2,
    const float* __restrict__ W0, short* __restrict__ wsw)
{
    const int gid = blockIdx.x*256 + threadIdx.x;
    if (gid >= 424*64) return;
    const int f    = gid >> 6;
    const int lane = gid & 63;
    const int c    = lane & 15;
    const int kg   = lane >> 4;
    const float* W; int kt, nt, N;
    if (f < 288)      { W = Wh1; kt = f >> 4;        nt = f & 15;        N = 256; }
    else if (f < 416) { W = Wh2; kt = (f-288) >> 4;  nt = (f-288) & 15;  N = 256; }
    else              { W = W0;  kt = (f-416) >> 2;  nt = (f-416) & 3;   N = 64;  }
    float v[8];
    #pragma unroll
    for (int j = 0; j < 8; ++j)
        v[j] = W[(kt*32 + kg*8 + j)*N + nt*16 + c];
    short8 hi, lo;
    split8(v, hi, lo);
    *(short8*)(wsw + (size_t)f*1024 + lane*8)       = hi;
    *(short8*)(wsw + (size_t)f*1024 + 512 + lane*8) = lo;
}

// ---------------- hyper net (MFMA) ----------------
__global__ __launch_bounds__(256) void hyper_mfma(
    const float* __restrict__ feat,
    const float* __restrict__ cell,
    const float* __restrict__ Wh1,    // rows 576,577 (rel_cell) read raw
    const float* __restrict__ bh1,
    const float* __restrict__ bh2,
    const float* __restrict__ b0,
    const short* __restrict__ wsw,    // swizzled weights
    float* __restrict__ mod_ws,       // (9216,256)
    float* __restrict__ f0_ws)        // (9216,64)
{
    __shared__ float a_lds[288*34];   // im2col pairs: (k>>1)*34 + px*2 + (k&1)
    __shared__ float h_lds[128*36];   // h1 pairs:     (n>>1)*36 + px*2 + (n&1)

    const int tid = threadIdx.x;
    const int blk = blockIdx.x;
    const int y   = blk / 6;
    const int x0  = (blk % 6) * 16;
    const int qbase = y*HW + x0;

    // ---- im2col stage: hyp_in[k][px], k = c*9 + dy*3 + dx ----
    for (int idx = tid; idx < 9216; idx += 256) {
        const int px = idx & 15;
        const int k  = idx >> 4;
        const int ch = k / 9;
        const int j  = k - 9*ch;
        const int dy = j / 3;
        const int dx = j - 3*dy;
        const int gy = y + dy - 1;
        const int gx = x0 + px + dx - 1;
        float v = 0.0f;
        if (gy >= 0 && gy < HW && gx >= 0 && gx < HW)
            v = feat[ch*NPIX + gy*HW + gx];
        a_lds[(k>>1)*34 + px*2 + (k&1)] = v;
    }
    __syncthreads();

    const int lane = tid & 63;
    const int wid  = tid >> 6;
    const int c    = lane & 15;   // A-row px / C-col
    const int kg   = lane >> 4;

    const short* wh1f = wsw;
    const short* wh2f = wsw + (size_t)288*1024;
    const short* w0f  = wsw + (size_t)416*1024;

    // ================= F0 = feat @ W0[0:64] + b0 =================
    {
        f32x4 acc0;
        const float bb = b0[wid*16 + c];
        acc0[0] = bb; acc0[1] = bb; acc0[2] = bb; acc0[3] = bb;
        #pragma unroll
        for (int kt = 0; kt < 2; ++kt) {
            float v[8];
            #pragma unroll
            for (int j = 0; j < 8; ++j) {
                const int kc = (kt*32 + kg*8 + j)*9 + 4;   // center tap row
                v[j] = a_lds[(kc>>1)*34 + c*2 + (kc&1)];
            }
            short8 Ahi, Alo;
            split8(v, Ahi, Alo);
            const short* bp = w0f + (size_t)(kt*4 + wid)*1024 + lane*8;
            const short8 Bhi = *(const short8*)bp;
            const short8 Blo = *(const short8*)(bp + 512);
            acc0 = __builtin_amdgcn_mfma_f32_16x16x32_bf16(Ahi, Bhi, acc0, 0, 0, 0);
            acc0 = __builtin_amdgcn_mfma_f32_16x16x32_bf16(Alo, Bhi, acc0, 0, 0, 0);
            acc0 = __builtin_amdgcn_mfma_f32_16x16x32_bf16(Ahi, Blo, acc0, 0, 0, 0);
        }
        #pragma unroll
        for (int i = 0; i < 4; ++i)
            f0_ws[(size_t)(qbase + kg*4 + i)*64 + wid*16 + c] = acc0[i];
    }

    // ================= layer1: hyp_in(16x576) @ Wh1 + rc + bias =================
    f32x4 acc[4];
    #pragma unroll
    for (int nt = 0; nt < 4; ++nt) {
        const float bb = bh1[wid*64 + nt*16 + c];
        acc[nt][0] = bb; acc[nt][1] = bb; acc[nt][2] = bb; acc[nt][3] = bb;
    }
    #pragma unroll
    for (int kt = 0; kt < 18; ++kt) {
        float v[8];
        #pragma unroll
        for (int j2 = 0; j2 < 4; ++j2) {
            const float2 p = *(const float2*)&a_lds[(kt*16 + kg*4 + j2)*34 + c*2];
            v[2*j2]   = p.x;
            v[2*j2+1] = p.y;
        }
        short8 Ahi, Alo;
        split8(v, Ahi, Alo);
        #pragma unroll
        for (int nt = 0; nt < 4; ++nt) {
            const short* bp = wh1f + (size_t)(kt*16 + wid*4 + nt)*1024 + lane*8;
            const short8 Bhi = *(const short8*)bp;
            const short8 Blo = *(const short8*)(bp + 512);
            acc[nt] = __builtin_amdgcn_mfma_f32_16x16x32_bf16(Ahi, Bhi, acc[nt], 0, 0, 0);
            acc[nt] = __builtin_amdgcn_mfma_f32_16x16x32_bf16(Alo, Bhi, acc[nt], 0, 0, 0);
            acc[nt] = __builtin_amdgcn_mfma_f32_16x16x32_bf16(Ahi, Blo, acc[nt], 0, 0, 0);
        }
    }
    // epilogue: + rc0*Wh1[576] + rc1*Wh1[577], relu, -> h_lds (pair layout)
    {
        float rc0v[4], rc1v[4];
        #pragma unroll
        for (int i = 0; i < 4; ++i) {
            const int q = qbase + kg*4 + i;
            const float2 ce = ((const float2*)cell)[q];
            rc0v[i] = ce.x * 96.0f;
            rc1v[i] = ce.y * 96.0f;
        }
        #pragma unroll
        for (int nt = 0; nt < 4; ++nt) {
            const int n = wid*64 + nt*16 + c;
            const float w5 = Wh1[576*256 + n];
            const float w6 = Wh1[577*256 + n];
            #pragma unroll
            for (int i = 0; i < 4; ++i) {
                float hv = acc[nt][i] + rc0v[i]*w5 + rc1v[i]*w6;
                hv = fmaxf(hv, 0.0f);
                h_lds[(n>>1)*36 + (kg*4 + i)*2 + (n&1)] = hv;
            }
        }
    }
    __syncthreads();

    // ================= layer2: h1(16x256) @ Wh2 + bh2 =================
    f32x4 acc2[4];
    #pragma unroll
    for (int nt = 0; nt < 4; ++nt) {
        const float bb = bh2[wid*64 + nt*16 + c];
        acc2[nt][0] = bb; acc2[nt][1] = bb; acc2[nt][2] = bb; acc2[nt][3] = bb;
    }
    #pragma unroll
    for (int kt = 0; kt < 8; ++kt) {
        float v[8];
        #pragma unroll
        for (int j2 = 0; j2 < 4; ++j2) {
            const float2 p = *(const float2*)&h_lds[(kt*16 + kg*4 + j2)*36 + c*2];
            v[2*j2]   = p.x;
            v[2*j2+1] = p.y;
        }
        short8 Ahi, Alo;
        split8(v, Ahi, Alo);
        #pragma unroll
        for (int nt = 0; nt < 4; ++nt) {
            const short* bp = wh2f + (size_t)(kt*16 + wid*4 + nt)*1024 + lane*8;
            const short8 Bhi = *(const short8*)bp;
            const short8 Blo = *(const short8*)(bp + 512);
            acc2[nt] = __builtin_amdgcn_mfma_f32_16x16x32_bf16(Ahi, Bhi, acc2[nt], 0, 0, 0);
            acc2[nt] = __builtin_amdgcn_mfma_f32_16x16x32_bf16(Alo, Bhi, acc2[nt], 0, 0, 0);
            acc2[nt] = __builtin_amdgcn_mfma_f32_16x16x32_bf16(Ahi, Blo, acc2[nt], 0, 0, 0);
        }
    }
    #pragma unroll
    for (int nt = 0; nt < 4; ++nt) {
        #pragma unroll
        for (int i = 0; i < 4; ++i)
            mod_ws[(size_t)(qbase + kg*4 + i)*256 + wid*64 + nt*16 + c] = acc2[nt][i];
    }
}

// ---------------- query kernel (unchanged from R3) ----------------
#define ROWP 324

__global__ __launch_bounds__(256) void query_kernel_v3(
    const float* __restrict__ coord,
    const float* __restrict__ cell,
    const float* __restrict__ W0,      // rows 64..67 used
    const float* __restrict__ W1,      // (64,64)
    const float* __restrict__ b1,
    const float* __restrict__ W2,      // (64,3)
    const float* __restrict__ b2,
    const float* __restrict__ mod_ws,
    const float* __restrict__ f0_ws,
    float* __restrict__ out)
{
    __shared__ float smem[36*ROWP];

    const int tid = threadIdx.x;
    const int bX  = blockIdx.x % 24;
    const int bY  = blockIdx.x / 24;
    const int X0  = bX * 16;
    const int Y0  = bY * 16;
    const int lx0 = bX*4 - 1;
    const int ly0 = bY*4 - 1;

    for (int idx = tid; idx < 2880; idx += 256) {
        const int r  = idx / 80;
        const int o  = idx - r*80;
        const int ry = r / 6;
        const int rx = r - ry*6;
        const int gy = min(max(ly0 + ry, 0), 95);
        const int gx = min(max(lx0 + rx, 0), 95);
        const int src = gy*96 + gx;
        float4 v;
        int dst;
        if (o < 16) {
            v = ((const float4*)(f0_ws + (size_t)src*64))[o];
            dst = r*ROWP + o*4;
        } else {
            v = ((const float4*)(mod_ws + (size_t)src*256))[o - 16];
            dst = r*ROWP + 64 + (o - 16)*4;
        }
        *(float4*)(smem + dst) = v;
    }

    const int lane = tid & 63;
    const int wid  = tid >> 6;
    const int c    = lane & 15;
    const int kg   = lane >> 4;

    short8 Bh[4][2];
    #pragma unroll
    for (int nt = 0; nt < 4; ++nt) {
        #pragma unroll
        for (int kt = 0; kt < 2; ++kt) {
            union { short8 s; unsigned u[4]; } H;
            #pragma unroll
            for (int p = 0; p < 4; ++p) {
                float a = W1[(kt*32 + kg*8 + 2*p    )*64 + nt*16 + c];
                float b = W1[(kt*32 + kg*8 + 2*p + 1)*64 + nt*16 + c];
                H.u[p] = pack_bf2_rne(a, b);
            }
            Bh[nt][kt] = H.s;
        }
    }
    float wr64[2][8], wr65[2][8], wr66[2][8], wr67[2][8];
    #pragma unroll
    for (int kt = 0; kt < 2; ++kt) {
        const int kb = kt*32 + kg*8;
        #pragma unroll
        for (int j = 0; j < 8; ++j) {
            wr64[kt][j] = W0[64*64 + kb + j];
            wr65[kt][j] = W0[65*64 + kb + j];
            wr66[kt][j] = W0[66*64 + kb + j];
            wr67[kt][j] = W0[67*64 + kb + j];
        }
    }
    float b1c[4];
    float w2r[4][3];
    #pragma unroll
    for (int nt = 0; nt < 4; ++nt) {
        b1c[nt] = b1[nt*16 + c];
        w2r[nt][0] = W2[(nt*16 + c)*3 + 0];
        w2r[nt][1] = W2[(nt*16 + c)*3 + 1];
        w2r[nt][2] = W2[(nt*16 + c)*3 + 2];
    }
    const float b2v0 = b2[0], b2v1 = b2[1], b2v2 = b2[2];

    __syncthreads();

    const int Xw   = X0 + wid*4;
    const int qxA  = c >> 2;
    const int tapA = c & 3;
    const float vxA = (tapA < 2) ? -1.0f : 1.0f;
    const float vyA = (tapA & 1) ? 1.0f : -1.0f;
    const float2* coordv = (const float2*)coord;
    const float2* cellv  = (const float2*)cell;

    for (int m = 0; m < 16; ++m) {
        const int qy = Y0 + m;

        short8 Ahi[2], Alo[2];
        {
            const int qA = qy*384 + Xw + qxA;
            const float2 cv = coordv[qA];
            const float2 ce = cellv[qA];
            const float cy = cv.x, cx = cv.y;
            const float rc0 = ce.x * 96.0f;
            const float rc1 = ce.y * 96.0f;
            int iyA, ixA; float r0A, r1A, arA;
            TAPCALC2(vxA, vyA, iyA, ixA, r0A, r1A, arA)
            (void)arA;
            const float* rowp = smem + ((iyA - ly0)*6 + (ixA - lx0)) * ROWP;
            #pragma unroll
            for (int kt = 0; kt < 2; ++kt) {
                const int kb = kt*32 + kg*8;
                const float4 f0a = *(const float4*)(rowp + kb);
                const float4 f0b = *(const float4*)(rowp + kb + 4);
                const float4 s1a = *(const float4*)(rowp + 64 + kb);
                const float4 s1b = *(const float4*)(rowp + 64 + kb + 4);
                const float4 t1a = *(const float4*)(rowp + 192 + kb);
                const float4 t1b = *(const float4*)(rowp + 192 + kb + 4);
                float f0[8]  = {f0a.x,f0a.y,f0a.z,f0a.w,f0b.x,f0b.y,f0b.z,f0b.w};
                float sc1[8] = {s1a.x,s1a.y,s1a.z,s1a.w,s1b.x,s1b.y,s1b.z,s1b.w};
                float sh1[8] = {t1a.x,t1a.y,t1a.z,t1a.w,t1b.x,t1b.y,t1b.z,t1b.w};
                float hv[8];
                #pragma unroll
                for (int j = 0; j < 8; ++j) {
                    float pre = f0[j];
                    pre = fmaf(r0A, wr64[kt][j], pre);
                    pre = fmaf(r1A, wr65[kt][j], pre);
                    pre = fmaf(rc0, wr66[kt][j], pre);
                    pre = fmaf(rc1, wr67[kt][j], pre);
                    hv[j] = fmaxf(fmaf(pre, sc1[j], sh1[j]), 0.f);
                }
                split8(hv, Ahi[kt], Alo[kt]);
            }
        }

        f32x4 acc[4];
        #pragma unroll
        for (int nt = 0; nt < 4; ++nt) {
            f32x4 a0 = {b1c[nt], b1c[nt], b1c[nt], b1c[nt]};
            acc[nt] = a0;
        }
        #pragma unroll
        for (int nt = 0; nt < 4; ++nt) {
            #pragma unroll
            for (int kt = 0; kt < 2; ++kt) {
                acc[nt] = __builtin_amdgcn_mfma_f32_16x16x32_bf16(Ahi[kt], Bh[nt][kt], acc[nt], 0, 0, 0);
                acc[nt] = __builtin_amdgcn_mfma_f32_16x16x32_bf16(Alo[kt], Bh[nt][kt], acc[nt], 0, 0, 0);
            }
        }

        const int qE = qy*384 + Xw + kg;
        const float2 cv = coordv[qE];
        const float cy = cv.x, cx = cv.y;
        int iy0,ix0,iy1,ix1,iy2,ix2,iy3,ix3;
        float r00,r10,r01,r11,r02,r12,r03,r13, a0,a1,a2,a3;
        TAPCALC2(-1.0f, -1.0f, iy0, ix0, r00, r10, a0)
        TAPCALC2(-1.0f,  1.0f, iy1, ix1, r01, r11, a1)
        TAPCALC2( 1.0f, -1.0f, iy2, ix2, r02, r12, a2)
        TAPCALC2( 1.0f,  1.0f, iy3, ix3, r03, r13, a3)
        const int lr0 = (iy0 - ly0)*6 + (ix0 - lx0);
        const int lr1 = (iy1 - ly0)*6 + (ix1 - lx0);
        const int lr2 = (iy2 - ly0)*6 + (ix2 - lx0);
        const int lr3 = (iy3 - ly0)*6 + (ix3 - lx0);
        const float invt = 1.0f / (a0 + a1 + a2 + a3);
        const float w0_ = a3 * invt, w1_ = a2 * invt, w2_ = a1 * invt, w3_ = a0 * invt;

        float p0 = 0.f, p1 = 0.f, p2 = 0.f;
        #pragma unroll
        for (int i = 0; i < 4; ++i) {
            const int   lri = (i == 0) ? lr0 : (i == 1) ? lr1 : (i == 2) ? lr2 : lr3;
            const float wi  = (i == 0) ? w0_ : (i == 1) ? w1_ : (i == 2) ? w2_ : w3_;
            const float* rp = smem + lri*ROWP;
            float s0 = 0.f, s1 = 0.f, s2 = 0.f;
            #pragma unroll
            for (int nt = 0; nt < 4; ++nt) {
                const float sc2 = rp[128 + nt*16 + c];
                const float sh2 = rp[256 + nt*16 + c];
                const float v = fmaxf(fmaf(acc[nt][i], sc2, sh2), 0.f);
                s0 = fmaf(v, w2r[nt][0], s0);
                s1 = fmaf(v, w2r[nt][1], s1);
                s2 = fmaf(v, w2r[nt][2], s2);
            }
            p0 = fmaf(s0, wi, p0);
            p1 = fmaf(s1, wi, p1);
            p2 = fmaf(s2, wi, p2);
        }
        #pragma unroll
        for (int d = 1; d < 16; d <<= 1) {
            p0 += __shfl_xor(p0, d);
            p1 += __shfl_xor(p1, d);
            p2 += __shfl_xor(p2, d);
        }
        if (c < 3) {
            const float ov = (c == 0) ? p0 + b2v0 : (c == 1) ? p1 + b2v1 : p2 + b2v2;
            out[(size_t)qE*3 + c] = ov;
        }
    }
}

extern "C" void kernel_launch(void* const* d_in, const int* in_sizes, int n_in,
                              void* d_out, int out_size, void* d_ws, size_t ws_size,
                              hipStream_t stream) {
    const float* feat  = (const float*)d_in[0];
    const float* coord = (const float*)d_in[1];
    const float* cell  = (const float*)d_in[2];
    const float* Wh1   = (const float*)d_in[3];
    const float* bh1   = (const float*)d_in[4];
    const float* Wh2   = (const float*)d_in[5];
    const float* bh2   = (const float*)d_in[6];
    const float* W0    = (const float*)d_in[7];
    const float* b0    = (const float*)d_in[8];
    const float* W1    = (const float*)d_in[9];
    const float* b1    = (const float*)d_in[10];
    const float* W2    = (const float*)d_in[11];
    const float* b2    = (const float*)d_in[12];
    float* out = (float*)d_out;

    float* mod_ws = (float*)d_ws;                         // 9216*256 f32
    float* f0_ws  = (float*)d_ws + 9216*256;              // 9216*64  f32
    short* wsw    = (short*)((char*)d_ws + 11796480);     // 424 frags * 2048 B

    swizzle_kernel<<<dim3(106), dim3(256), 0, stream>>>(Wh1, Wh2, W0, wsw);
    hyper_mfma<<<dim3(576), dim3(256), 0, stream>>>(
        feat, cell, Wh1, bh1, bh2, b0, wsw, mod_ws, f0_ws);
    query_kernel_v3<<<dim3(576), dim3(256), 0, stream>>>(
        coord, cell, W0, W1, b1, W2, b2, mod_ws, f0_ws, out);
}

// Round 6
// 105.038 us; speedup vs baseline: 5.3608x; 1.3509x over previous
//
#include <hip/hip_runtime.h>

// LM-LIIF fused pipeline. R5: occupancy + dedup round.
//  - hyper_mfma: 512 threads (8 waves, each owns 32 output cols). im2col tile
//    stored PRE-SPLIT as bf16 hi/lo short-planes [k/8][px][k%8] -> A-frag is
//    one ds_read_b128 per plane, split8 done once at staging (not per wave).
//    h1 same. LDS 52 KB -> 3 blocks/CU. F0 A-frags read from global feat.
//  - query_kernel_v3: 8x8 query tile / block -> LDS 20.7 KB, 2304 blocks.
//  - swizzle_kernel unchanged.

#define HW 96
#define NPIX (96*96)
#define CFEAT 64

typedef __attribute__((ext_vector_type(8))) short short8;
typedef __attribute__((ext_vector_type(4))) float f32x4;

__device__ __forceinline__ unsigned pack_bf2(float a, float b) {
    unsigned ua = __builtin_bit_cast(unsigned, a);
    unsigned ub = __builtin_bit_cast(unsigned, b);
    return (ua >> 16) | (ub & 0xffff0000u);
}
__device__ __forceinline__ float bf_hi(float a) {
    return __builtin_bit_cast(float, __builtin_bit_cast(unsigned, a) & 0xffff0000u);
}
__device__ __forceinline__ void split8(const float (&v)[8], short8& hi, short8& lo) {
    union { short8 s; unsigned u[4]; } H, L;
    #pragma unroll
    for (int p = 0; p < 4; ++p) {
        float a = v[2*p], b = v[2*p+1];
        H.u[p] = pack_bf2(a, b);
        L.u[p] = pack_bf2(a - bf_hi(a), b - bf_hi(b));
    }
    hi = H.s; lo = L.s;
}
__device__ __forceinline__ unsigned rne16(float x) {
    unsigned u = __builtin_bit_cast(unsigned, x);
    return (u + 0x7fffu + ((u >> 16) & 1u)) >> 16;
}
__device__ __forceinline__ unsigned pack_bf2_rne(float a, float b) {
    return rne16(a) | (rne16(b) << 16);
}
__device__ __forceinline__ short top16(float a) {
    return (short)(__builtin_bit_cast(unsigned, a) >> 16);
}

#define TAPCALC2(VX, VY, IY, IX, R0, R1, AR)                           \
{                                                                      \
    float ey = cy + (VX)*(1.0f/96.0f) + 1e-6f;                         \
    float ex = cx + (VY)*(1.0f/96.0f) + 1e-6f;                         \
    ey = fminf(fmaxf(ey, -1.0f + 1e-6f), 1.0f - 1e-6f);                \
    ex = fminf(fmaxf(ex, -1.0f + 1e-6f), 1.0f - 1e-6f);                \
    IY = (int)rintf((ey + 1.0f) * 48.0f - 0.5f);                       \
    IX = (int)rintf((ex + 1.0f) * 48.0f - 0.5f);                       \
    IY = min(max(IY, 0), 95);                                          \
    IX = min(max(IX, 0), 95);                                          \
    const float qy_ = ((IY + 0.5f) / 96.0f) * 2.0f - 1.0f;             \
    const float qx_ = ((IX + 0.5f) / 96.0f) * 2.0f - 1.0f;             \
    R0 = (cy - qy_) * 96.0f;                                           \
    R1 = (cx - qx_) * 96.0f;                                           \
    AR = fabsf(R0 * R1) + 1e-9f;                                       \
}

// ---------------- weight pre-swizzle (unchanged) ----------------
__global__ __launch_bounds__(256) void swizzle_kernel(
    const float* __restrict__ Wh1, const float* __restrict__ Wh2,
    const float* __restrict__ W0, short* __restrict__ wsw)
{
    const int gid = blockIdx.x*256 + threadIdx.x;
    if (gid >= 424*64) return;
    const int f    = gid >> 6;
    const int lane = gid & 63;
    const int c    = lane & 15;
    const int kg   = lane >> 4;
    const float* W; int kt, nt, N;
    if (f < 288)      { W = Wh1; kt = f >> 4;        nt = f & 15;        N = 256; }
    else if (f < 416) { W = Wh2; kt = (f-288) >> 4;  nt = (f-288) & 15;  N = 256; }
    else              { W = W0;  kt = (f-416) >> 2;  nt = (f-416) & 3;   N = 64;  }
    float v[8];
    #pragma unroll
    for (int j = 0; j < 8; ++j)
        v[j] = W[(kt*32 + kg*8 + j)*N + nt*16 + c];
    short8 hi, lo;
    split8(v, hi, lo);
    *(short8*)(wsw + (size_t)f*1024 + lane*8)       = hi;
    *(short8*)(wsw + (size_t)f*1024 + 512 + lane*8) = lo;
}

// ---------------- hyper net (MFMA, 8 waves, pre-split LDS) ----------------
__global__ __launch_bounds__(512) void hyper_mfma(
    const float* __restrict__ feat,
    const float* __restrict__ cell,
    const float* __restrict__ Wh1,    // rows 576,577 read raw
    const float* __restrict__ bh1,
    const float* __restrict__ bh2,
    const float* __restrict__ b0,
    const short* __restrict__ wsw,
    float* __restrict__ mod_ws,       // (9216,256)
    float* __restrict__ f0_ws)        // (9216,64)
{
    __shared__ short AHI[72*128];     // [k/8][px][k%8]  18 KB
    __shared__ short ALO[72*128];     // 18 KB
    __shared__ short HHI[32*128];     // [n/8][px][n%8]   8 KB
    __shared__ short HLO[32*128];     //  8 KB   (total 52 KB -> 3 blocks/CU)

    const int tid = threadIdx.x;
    const int blk = blockIdx.x;
    const int y   = blk / 6;
    const int x0  = (blk % 6) * 16;
    const int qbase = y*HW + x0;

    // ---- im2col stage, pre-split ----
    for (int idx = tid; idx < 9216; idx += 512) {
        const int px = idx & 15;
        const int k  = idx >> 4;
        const int ch = k / 9;
        const int j  = k - 9*ch;
        const int dy = j / 3;
        const int dx = j - 3*dy;
        const int gy = y + dy - 1;
        const int gx = x0 + px + dx - 1;
        float v = 0.0f;
        if (gy >= 0 && gy < HW && gx >= 0 && gx < HW)
            v = feat[ch*NPIX + gy*HW + gx];
        const int dst = (k >> 3)*128 + px*8 + (k & 7);
        AHI[dst] = top16(v);
        ALO[dst] = top16(v - bf_hi(v));
    }
    __syncthreads();

    const int lane = tid & 63;
    const int wid  = tid >> 6;     // 0..7
    const int c    = lane & 15;    // px / C-col
    const int kg   = lane >> 4;

    const short* wh1f = wsw;
    const short* wh2f = wsw + (size_t)288*1024;
    const short* w0f  = wsw + (size_t)416*1024;

    // ================= F0 (waves 0..3): feat @ W0[0:64] + b0 =================
    if (wid < 4) {
        f32x4 acc0;
        const float bb = b0[wid*16 + c];
        acc0[0] = bb; acc0[1] = bb; acc0[2] = bb; acc0[3] = bb;
        #pragma unroll
        for (int kt = 0; kt < 2; ++kt) {
            float v[8];
            #pragma unroll
            for (int j = 0; j < 8; ++j)
                v[j] = feat[(kt*32 + kg*8 + j)*NPIX + y*HW + x0 + c];  // center tap
            short8 Ahi, Alo;
            split8(v, Ahi, Alo);
            const short* bp = w0f + (size_t)(kt*4 + wid)*1024 + lane*8;
            const short8 Bhi = *(const short8*)bp;
            const short8 Blo = *(const short8*)(bp + 512);
            acc0 = __builtin_amdgcn_mfma_f32_16x16x32_bf16(Ahi, Bhi, acc0, 0, 0, 0);
            acc0 = __builtin_amdgcn_mfma_f32_16x16x32_bf16(Alo, Bhi, acc0, 0, 0, 0);
            acc0 = __builtin_amdgcn_mfma_f32_16x16x32_bf16(Ahi, Blo, acc0, 0, 0, 0);
        }
        #pragma unroll
        for (int i = 0; i < 4; ++i)
            f0_ws[(size_t)(qbase + kg*4 + i)*64 + wid*16 + c] = acc0[i];
    }

    // ================= layer1: (16x576) @ Wh1 ; wave owns cols wid*32..+31 ====
    f32x4 acc[2];
    #pragma unroll
    for (int nt = 0; nt < 2; ++nt) {
        const float bb = bh1[wid*32 + nt*16 + c];
        acc[nt][0] = bb; acc[nt][1] = bb; acc[nt][2] = bb; acc[nt][3] = bb;
    }
    #pragma unroll
    for (int kt = 0; kt < 18; ++kt) {
        const int aoff = (kt*4 + kg)*128 + c*8;
        const short8 Ahi = *(const short8*)&AHI[aoff];
        const short8 Alo = *(const short8*)&ALO[aoff];
        #pragma unroll
        for (int nt = 0; nt < 2; ++nt) {
            const short* bp = wh1f + (size_t)(kt*16 + wid*2 + nt)*1024 + lane*8;
            const short8 Bhi = *(const short8*)bp;
            const short8 Blo = *(const short8*)(bp + 512);
            acc[nt] = __builtin_amdgcn_mfma_f32_16x16x32_bf16(Ahi, Bhi, acc[nt], 0, 0, 0);
            acc[nt] = __builtin_amdgcn_mfma_f32_16x16x32_bf16(Alo, Bhi, acc[nt], 0, 0, 0);
            acc[nt] = __builtin_amdgcn_mfma_f32_16x16x32_bf16(Ahi, Blo, acc[nt], 0, 0, 0);
        }
    }
    // epilogue: + rel_cell rank-1, relu, pre-split into H planes
    {
        float rc0v[4], rc1v[4];
        #pragma unroll
        for (int i = 0; i < 4; ++i) {
            const int q = qbase + kg*4 + i;
            const float2 ce = ((const float2*)cell)[q];
            rc0v[i] = ce.x * 96.0f;
            rc1v[i] = ce.y * 96.0f;
        }
        #pragma unroll
        for (int nt = 0; nt < 2; ++nt) {
            const int n = wid*32 + nt*16 + c;
            const float w5 = Wh1[576*256 + n];
            const float w6 = Wh1[577*256 + n];
            #pragma unroll
            for (int i = 0; i < 4; ++i) {
                float hv = acc[nt][i] + rc0v[i]*w5 + rc1v[i]*w6;
                hv = fmaxf(hv, 0.0f);
                const int dst = (n >> 3)*128 + (kg*4 + i)*8 + (n & 7);
                HHI[dst] = top16(hv);
                HLO[dst] = top16(hv - bf_hi(hv));
            }
        }
    }
    __syncthreads();

    // ================= layer2: (16x256) @ Wh2 =================
    f32x4 acc2[2];
    #pragma unroll
    for (int nt = 0; nt < 2; ++nt) {
        const float bb = bh2[wid*32 + nt*16 + c];
        acc2[nt][0] = bb; acc2[nt][1] = bb; acc2[nt][2] = bb; acc2[nt][3] = bb;
    }
    #pragma unroll
    for (int kt = 0; kt < 8; ++kt) {
        const int aoff = (kt*4 + kg)*128 + c*8;
        const short8 Ahi = *(const short8*)&HHI[aoff];
        const short8 Alo = *(const short8*)&HLO[aoff];
        #pragma unroll
        for (int nt = 0; nt < 2; ++nt) {
            const short* bp = wh2f + (size_t)(kt*16 + wid*2 + nt)*1024 + lane*8;
            const short8 Bhi = *(const short8*)bp;
            const short8 Blo = *(const short8*)(bp + 512);
            acc2[nt] = __builtin_amdgcn_mfma_f32_16x16x32_bf16(Ahi, Bhi, acc2[nt], 0, 0, 0);
            acc2[nt] = __builtin_amdgcn_mfma_f32_16x16x32_bf16(Alo, Bhi, acc2[nt], 0, 0, 0);
            acc2[nt] = __builtin_amdgcn_mfma_f32_16x16x32_bf16(Ahi, Blo, acc2[nt], 0, 0, 0);
        }
    }
    #pragma unroll
    for (int nt = 0; nt < 2; ++nt) {
        #pragma unroll
        for (int i = 0; i < 4; ++i)
            mod_ws[(size_t)(qbase + kg*4 + i)*256 + wid*32 + nt*16 + c] = acc2[nt][i];
    }
}

// ---------------- query kernel: 8x8 tile / block ----------------
#define ROWP 324

__global__ __launch_bounds__(256) void query_kernel_v3(
    const float* __restrict__ coord,
    const float* __restrict__ cell,
    const float* __restrict__ W0,      // rows 64..67 used
    const float* __restrict__ W1,      // (64,64)
    const float* __restrict__ b1,
    const float* __restrict__ W2,      // (64,3)
    const float* __restrict__ b2,
    const float* __restrict__ mod_ws,
    const float* __restrict__ f0_ws,
    float* __restrict__ out)
{
    __shared__ float smem[16*ROWP];    // 20.7 KB

    const int tid = threadIdx.x;
    const int bX  = blockIdx.x % 48;
    const int bY  = blockIdx.x / 48;
    const int X0  = bX * 8;
    const int Y0  = bY * 8;
    const int lx0 = bX*2 - 1;
    const int ly0 = bY*2 - 1;

    // stage 4x4 latent patch: 16 rows x 80 float4
    for (int idx = tid; idx < 1280; idx += 256) {
        const int r  = idx / 80;
        const int o  = idx - r*80;
        const int ry = r >> 2;
        const int rx = r & 3;
        const int gy = min(max(ly0 + ry, 0), 95);
        const int gx = min(max(lx0 + rx, 0), 95);
        const int src = gy*96 + gx;
        float4 v;
        int dst;
        if (o < 16) {
            v = ((const float4*)(f0_ws + (size_t)src*64))[o];
            dst = r*ROWP + o*4;
        } else {
            v = ((const float4*)(mod_ws + (size_t)src*256))[o - 16];
            dst = r*ROWP + 64 + (o - 16)*4;
        }
        *(float4*)(smem + dst) = v;
    }

    const int lane = tid & 63;
    const int wid  = tid >> 6;
    const int c    = lane & 15;
    const int kg   = lane >> 4;

    short8 Bh[4][2];
    #pragma unroll
    for (int nt = 0; nt < 4; ++nt) {
        #pragma unroll
        for (int kt = 0; kt < 2; ++kt) {
            union { short8 s; unsigned u[4]; } H;
            #pragma unroll
            for (int p = 0; p < 4; ++p) {
                float a = W1[(kt*32 + kg*8 + 2*p    )*64 + nt*16 + c];
                float b = W1[(kt*32 + kg*8 + 2*p + 1)*64 + nt*16 + c];
                H.u[p] = pack_bf2_rne(a, b);
            }
            Bh[nt][kt] = H.s;
        }
    }
    float wr64[2][8], wr65[2][8], wr66[2][8], wr67[2][8];
    #pragma unroll
    for (int kt = 0; kt < 2; ++kt) {
        const int kb = kt*32 + kg*8;
        #pragma unroll
        for (int j = 0; j < 8; ++j) {
            wr64[kt][j] = W0[64*64 + kb + j];
            wr65[kt][j] = W0[65*64 + kb + j];
            wr66[kt][j] = W0[66*64 + kb + j];
            wr67[kt][j] = W0[67*64 + kb + j];
        }
    }
    float b1c[4];
    float w2r[4][3];
    #pragma unroll
    for (int nt = 0; nt < 4; ++nt) {
        b1c[nt] = b1[nt*16 + c];
        w2r[nt][0] = W2[(nt*16 + c)*3 + 0];
        w2r[nt][1] = W2[(nt*16 + c)*3 + 1];
        w2r[nt][2] = W2[(nt*16 + c)*3 + 2];
    }
    const float b2v0 = b2[0], b2v1 = b2[1], b2v2 = b2[2];

    __syncthreads();

    const int Xw   = X0 + (wid & 1)*4;
    const int Yw   = Y0 + (wid >> 1)*4;
    const int qxA  = c >> 2;
    const int tapA = c & 3;
    const float vxA = (tapA < 2) ? -1.0f : 1.0f;
    const float vyA = (tapA & 1) ? 1.0f : -1.0f;
    const float2* coordv = (const float2*)coord;
    const float2* cellv  = (const float2*)cell;

    for (int m = 0; m < 4; ++m) {
        const int qy = Yw + m;

        short8 Ahi[2], Alo[2];
        {
            const int qA = qy*384 + Xw + qxA;
            const float2 cv = coordv[qA];
            const float2 ce = cellv[qA];
            const float cy = cv.x, cx = cv.y;
            const float rc0 = ce.x * 96.0f;
            const float rc1 = ce.y * 96.0f;
            int iyA, ixA; float r0A, r1A, arA;
            TAPCALC2(vxA, vyA, iyA, ixA, r0A, r1A, arA)
            (void)arA;
            const float* rowp = smem + ((iyA - ly0)*4 + (ixA - lx0)) * ROWP;
            #pragma unroll
            for (int kt = 0; kt < 2; ++kt) {
                const int kb = kt*32 + kg*8;
                const float4 f0a = *(const float4*)(rowp + kb);
                const float4 f0b = *(const float4*)(rowp + kb + 4);
                const float4 s1a = *(const float4*)(rowp + 64 + kb);
                const float4 s1b = *(const float4*)(rowp + 64 + kb + 4);
                const float4 t1a = *(const float4*)(rowp + 192 + kb);
                const float4 t1b = *(const float4*)(rowp + 192 + kb + 4);
                float f0[8]  = {f0a.x,f0a.y,f0a.z,f0a.w,f0b.x,f0b.y,f0b.z,f0b.w};
                float sc1[8] = {s1a.x,s1a.y,s1a.z,s1a.w,s1b.x,s1b.y,s1b.z,s1b.w};
                float sh1[8] = {t1a.x,t1a.y,t1a.z,t1a.w,t1b.x,t1b.y,t1b.z,t1b.w};
                float hv[8];
                #pragma unroll
                for (int j = 0; j < 8; ++j) {
                    float pre = f0[j];
                    pre = fmaf(r0A, wr64[kt][j], pre);
                    pre = fmaf(r1A, wr65[kt][j], pre);
                    pre = fmaf(rc0, wr66[kt][j], pre);
                    pre = fmaf(rc1, wr67[kt][j], pre);
                    hv[j] = fmaxf(fmaf(pre, sc1[j], sh1[j]), 0.f);
                }
                split8(hv, Ahi[kt], Alo[kt]);
            }
        }

        f32x4 acc[4];
        #pragma unroll
        for (int nt = 0; nt < 4; ++nt) {
            f32x4 a0 = {b1c[nt], b1c[nt], b1c[nt], b1c[nt]};
            acc[nt] = a0;
        }
        #pragma unroll
        for (int nt = 0; nt < 4; ++nt) {
            #pragma unroll
            for (int kt = 0; kt < 2; ++kt) {
                acc[nt] = __builtin_amdgcn_mfma_f32_16x16x32_bf16(Ahi[kt], Bh[nt][kt], acc[nt], 0, 0, 0);
                acc[nt] = __builtin_amdgcn_mfma_f32_16x16x32_bf16(Alo[kt], Bh[nt][kt], acc[nt], 0, 0, 0);
            }
        }

        const int qE = qy*384 + Xw + kg;
        const float2 cv = coordv[qE];
        const float cy = cv.x, cx = cv.y;
        int iy0,ix0,iy1,ix1,iy2,ix2,iy3,ix3;
        float r00,r10,r01,r11,r02,r12,r03,r13, a0,a1,a2,a3;
        TAPCALC2(-1.0f, -1.0f, iy0, ix0, r00, r10, a0)
        TAPCALC2(-1.0f,  1.0f, iy1, ix1, r01, r11, a1)
        TAPCALC2( 1.0f, -1.0f, iy2, ix2, r02, r12, a2)
        TAPCALC2( 1.0f,  1.0f, iy3, ix3, r03, r13, a3)
        const int lr0 = (iy0 - ly0)*4 + (ix0 - lx0);
        const int lr1 = (iy1 - ly0)*4 + (ix1 - lx0);
        const int lr2 = (iy2 - ly0)*4 + (ix2 - lx0);
        const int lr3 = (iy3 - ly0)*4 + (ix3 - lx0);
        const float invt = 1.0f / (a0 + a1 + a2 + a3);
        const float w0_ = a3 * invt, w1_ = a2 * invt, w2_ = a1 * invt, w3_ = a0 * invt;

        float p0 = 0.f, p1 = 0.f, p2 = 0.f;
        #pragma unroll
        for (int i = 0; i < 4; ++i) {
            const int   lri = (i == 0) ? lr0 : (i == 1) ? lr1 : (i == 2) ? lr2 : lr3;
            const float wi  = (i == 0) ? w0_ : (i == 1) ? w1_ : (i == 2) ? w2_ : w3_;
            const float* rp = smem + lri*ROWP;
            float s0 = 0.f, s1 = 0.f, s2 = 0.f;
            #pragma unroll
            for (int nt = 0; nt < 4; ++nt) {
                const float sc2 = rp[128 + nt*16 + c];
                const float sh2 = rp[256 + nt*16 + c];
                const float v = fmaxf(fmaf(acc[nt][i], sc2, sh2), 0.f);
                s0 = fmaf(v, w2r[nt][0], s0);
                s1 = fmaf(v, w2r[nt][1], s1);
                s2 = fmaf(v, w2r[nt][2], s2);
            }
            p0 = fmaf(s0, wi, p0);
            p1 = fmaf(s1, wi, p1);
            p2 = fmaf(s2, wi, p2);
        }
        #pragma unroll
        for (int d = 1; d < 16; d <<= 1) {
            p0 += __shfl_xor(p0, d);
            p1 += __shfl_xor(p1, d);
            p2 += __shfl_xor(p2, d);
        }
        if (c < 3) {
            const float ov = (c == 0) ? p0 + b2v0 : (c == 1) ? p1 + b2v1 : p2 + b2v2;
            out[(size_t)qE*3 + c] = ov;
        }
    }
}

extern "C" void kernel_launch(void* const* d_in, const int* in_sizes, int n_in,
                              void* d_out, int out_size, void* d_ws, size_t ws_size,
                              hipStream_t stream) {
    const float* feat  = (const float*)d_in[0];
    const float* coord = (const float*)d_in[1];
    const float* cell  = (const float*)d_in[2];
    const float* Wh1   = (const float*)d_in[3];
    const float* bh1   = (const float*)d_in[4];
    const float* Wh2   = (const float*)d_in[5];
    const float* bh2   = (const float*)d_in[6];
    const float* W0    = (const float*)d_in[7];
    const float* b0    = (const float*)d_in[8];
    const float* W1    = (const float*)d_in[9];
    const float* b1    = (const float*)d_in[10];
    const float* W2    = (const float*)d_in[11];
    const float* b2    = (const float*)d_in[12];
    float* out = (float*)d_out;

    float* mod_ws = (float*)d_ws;                         // 9216*256 f32
    float* f0_ws  = (float*)d_ws + 9216*256;              // 9216*64  f32
    short* wsw    = (short*)((char*)d_ws + 11796480);     // 424 frags * 2048 B

    swizzle_kernel<<<dim3(106), dim3(256), 0, stream>>>(Wh1, Wh2, W0, wsw);
    hyper_mfma<<<dim3(576), dim3(512), 0, stream>>>(
        feat, cell, Wh1, bh1, bh2, b0, wsw, mod_ws, f0_ws);
    query_kernel_v3<<<dim3(2304), dim3(256), 0, stream>>>(
        coord, cell, W0, W1, b1, W2, b2, mod_ws, f0_ws, out);
}

// Round 7
// 101.590 us; speedup vs baseline: 5.5428x; 1.0339x over previous
//
#include <hip/hip_runtime.h>

// LM-LIIF fused pipeline. R6: query kernel v4.
//  - LDS row per latent px: [g(64) | u0..u3(256) | sc2(64) | sh2(64)] pad 452
//    where g = sc1*f0 + sh1, u_t = sc1*W0row(64+t)  (modulate folded at stage
//    time; algebraically identical). Kills per-tap modulate + the 64 VGPRs
//    that held W0 rows -> more waves/SIMD.
//  - epilogue tap math factored (2 y-calcs + 2 x-calcs, shared across 4 taps);
//    all /96 divisions replaced with fma forms.
//  - #pragma unroll 2 on m-loop.
//  - hyper_mfma / swizzle_kernel unchanged from R5.

#define HW 96
#define NPIX (96*96)
#define CFEAT 64

typedef __attribute__((ext_vector_type(8))) short short8;
typedef __attribute__((ext_vector_type(4))) float f32x4;

__device__ __forceinline__ unsigned pack_bf2(float a, float b) {
    unsigned ua = __builtin_bit_cast(unsigned, a);
    unsigned ub = __builtin_bit_cast(unsigned, b);
    return (ua >> 16) | (ub & 0xffff0000u);
}
__device__ __forceinline__ float bf_hi(float a) {
    return __builtin_bit_cast(float, __builtin_bit_cast(unsigned, a) & 0xffff0000u);
}
__device__ __forceinline__ void split8(const float (&v)[8], short8& hi, short8& lo) {
    union { short8 s; unsigned u[4]; } H, L;
    #pragma unroll
    for (int p = 0; p < 4; ++p) {
        float a = v[2*p], b = v[2*p+1];
        H.u[p] = pack_bf2(a, b);
        L.u[p] = pack_bf2(a - bf_hi(a), b - bf_hi(b));
    }
    hi = H.s; lo = L.s;
}
__device__ __forceinline__ unsigned rne16(float x) {
    unsigned u = __builtin_bit_cast(unsigned, x);
    return (u + 0x7fffu + ((u >> 16) & 1u)) >> 16;
}
__device__ __forceinline__ unsigned pack_bf2_rne(float a, float b) {
    return rne16(a) | (rne16(b) << 16);
}
__device__ __forceinline__ short top16(float a) {
    return (short)(__builtin_bit_cast(unsigned, a) >> 16);
}

// factored tap math: given center coordinate CV and sign SGN, produce latent
// index II and rel coord RR (x96).  qcoord = II*(2/96) + (1/96 - 1).
#define AXCALC(CV, SGN, II, RR)                                        \
{                                                                      \
    float e = CV + (SGN)*(1.0f/96.0f) + 1e-6f;                         \
    e = fminf(fmaxf(e, -1.0f + 1e-6f), 1.0f - 1e-6f);                  \
    II = (int)rintf((e + 1.0f) * 48.0f - 0.5f);                        \
    II = min(max(II, 0), 95);                                          \
    RR = (CV - fmaf((float)II, 0.0208333333f, -0.9895833333f)) * 96.0f;\
}

// ---------------- weight pre-swizzle (unchanged) ----------------
__global__ __launch_bounds__(256) void swizzle_kernel(
    const float* __restrict__ Wh1, const float* __restrict__ Wh2,
    const float* __restrict__ W0, short* __restrict__ wsw)
{
    const int gid = blockIdx.x*256 + threadIdx.x;
    if (gid >= 424*64) return;
    const int f    = gid >> 6;
    const int lane = gid & 63;
    const int c    = lane & 15;
    const int kg   = lane >> 4;
    const float* W; int kt, nt, N;
    if (f < 288)      { W = Wh1; kt = f >> 4;        nt = f & 15;        N = 256; }
    else if (f < 416) { W = Wh2; kt = (f-288) >> 4;  nt = (f-288) & 15;  N = 256; }
    else              { W = W0;  kt = (f-416) >> 2;  nt = (f-416) & 3;   N = 64;  }
    float v[8];
    #pragma unroll
    for (int j = 0; j < 8; ++j)
        v[j] = W[(kt*32 + kg*8 + j)*N + nt*16 + c];
    short8 hi, lo;
    split8(v, hi, lo);
    *(short8*)(wsw + (size_t)f*1024 + lane*8)       = hi;
    *(short8*)(wsw + (size_t)f*1024 + 512 + lane*8) = lo;
}

// ---------------- hyper net (unchanged from R5) ----------------
__global__ __launch_bounds__(512) void hyper_mfma(
    const float* __restrict__ feat,
    const float* __restrict__ cell,
    const float* __restrict__ Wh1,
    const float* __restrict__ bh1,
    const float* __restrict__ bh2,
    const float* __restrict__ b0,
    const short* __restrict__ wsw,
    float* __restrict__ mod_ws,
    float* __restrict__ f0_ws)
{
    __shared__ short AHI[72*128];
    __shared__ short ALO[72*128];
    __shared__ short HHI[32*128];
    __shared__ short HLO[32*128];

    const int tid = threadIdx.x;
    const int blk = blockIdx.x;
    const int y   = blk / 6;
    const int x0  = (blk % 6) * 16;
    const int qbase = y*HW + x0;

    for (int idx = tid; idx < 9216; idx += 512) {
        const int px = idx & 15;
        const int k  = idx >> 4;
        const int ch = k / 9;
        const int j  = k - 9*ch;
        const int dy = j / 3;
        const int dx = j - 3*dy;
        const int gy = y + dy - 1;
        const int gx = x0 + px + dx - 1;
        float v = 0.0f;
        if (gy >= 0 && gy < HW && gx >= 0 && gx < HW)
            v = feat[ch*NPIX + gy*HW + gx];
        const int dst = (k >> 3)*128 + px*8 + (k & 7);
        AHI[dst] = top16(v);
        ALO[dst] = top16(v - bf_hi(v));
    }
    __syncthreads();

    const int lane = tid & 63;
    const int wid  = tid >> 6;
    const int c    = lane & 15;
    const int kg   = lane >> 4;

    const short* wh1f = wsw;
    const short* wh2f = wsw + (size_t)288*1024;
    const short* w0f  = wsw + (size_t)416*1024;

    if (wid < 4) {
        f32x4 acc0;
        const float bb = b0[wid*16 + c];
        acc0[0] = bb; acc0[1] = bb; acc0[2] = bb; acc0[3] = bb;
        #pragma unroll
        for (int kt = 0; kt < 2; ++kt) {
            float v[8];
            #pragma unroll
            for (int j = 0; j < 8; ++j)
                v[j] = feat[(kt*32 + kg*8 + j)*NPIX + y*HW + x0 + c];
            short8 Ahi, Alo;
            split8(v, Ahi, Alo);
            const short* bp = w0f + (size_t)(kt*4 + wid)*1024 + lane*8;
            const short8 Bhi = *(const short8*)bp;
            const short8 Blo = *(const short8*)(bp + 512);
            acc0 = __builtin_amdgcn_mfma_f32_16x16x32_bf16(Ahi, Bhi, acc0, 0, 0, 0);
            acc0 = __builtin_amdgcn_mfma_f32_16x16x32_bf16(Alo, Bhi, acc0, 0, 0, 0);
            acc0 = __builtin_amdgcn_mfma_f32_16x16x32_bf16(Ahi, Blo, acc0, 0, 0, 0);
        }
        #pragma unroll
        for (int i = 0; i < 4; ++i)
            f0_ws[(size_t)(qbase + kg*4 + i)*64 + wid*16 + c] = acc0[i];
    }

    f32x4 acc[2];
    #pragma unroll
    for (int nt = 0; nt < 2; ++nt) {
        const float bb = bh1[wid*32 + nt*16 + c];
        acc[nt][0] = bb; acc[nt][1] = bb; acc[nt][2] = bb; acc[nt][3] = bb;
    }
    #pragma unroll
    for (int kt = 0; kt < 18; ++kt) {
        const int aoff = (kt*4 + kg)*128 + c*8;
        const short8 Ahi = *(const short8*)&AHI[aoff];
        const short8 Alo = *(const short8*)&ALO[aoff];
        #pragma unroll
        for (int nt = 0; nt < 2; ++nt) {
            const short* bp = wh1f + (size_t)(kt*16 + wid*2 + nt)*1024 + lane*8;
            const short8 Bhi = *(const short8*)bp;
            const short8 Blo = *(const short8*)(bp + 512);
            acc[nt] = __builtin_amdgcn_mfma_f32_16x16x32_bf16(Ahi, Bhi, acc[nt], 0, 0, 0);
            acc[nt] = __builtin_amdgcn_mfma_f32_16x16x32_bf16(Alo, Bhi, acc[nt], 0, 0, 0);
            acc[nt] = __builtin_amdgcn_mfma_f32_16x16x32_bf16(Ahi, Blo, acc[nt], 0, 0, 0);
        }
    }
    {
        float rc0v[4], rc1v[4];
        #pragma unroll
        for (int i = 0; i < 4; ++i) {
            const int q = qbase + kg*4 + i;
            const float2 ce = ((const float2*)cell)[q];
            rc0v[i] = ce.x * 96.0f;
            rc1v[i] = ce.y * 96.0f;
        }
        #pragma unroll
        for (int nt = 0; nt < 2; ++nt) {
            const int n = wid*32 + nt*16 + c;
            const float w5 = Wh1[576*256 + n];
            const float w6 = Wh1[577*256 + n];
            #pragma unroll
            for (int i = 0; i < 4; ++i) {
                float hv = acc[nt][i] + rc0v[i]*w5 + rc1v[i]*w6;
                hv = fmaxf(hv, 0.0f);
                const int dst = (n >> 3)*128 + (kg*4 + i)*8 + (n & 7);
                HHI[dst] = top16(hv);
                HLO[dst] = top16(hv - bf_hi(hv));
            }
        }
    }
    __syncthreads();

    f32x4 acc2[2];
    #pragma unroll
    for (int nt = 0; nt < 2; ++nt) {
        const float bb = bh2[wid*32 + nt*16 + c];
        acc2[nt][0] = bb; acc2[nt][1] = bb; acc2[nt][2] = bb; acc2[nt][3] = bb;
    }
    #pragma unroll
    for (int kt = 0; kt < 8; ++kt) {
        const int aoff = (kt*4 + kg)*128 + c*8;
        const short8 Ahi = *(const short8*)&HHI[aoff];
        const short8 Alo = *(const short8*)&HLO[aoff];
        #pragma unroll
        for (int nt = 0; nt < 2; ++nt) {
            const short* bp = wh2f + (size_t)(kt*16 + wid*2 + nt)*1024 + lane*8;
            const short8 Bhi = *(const short8*)bp;
            const short8 Blo = *(const short8*)(bp + 512);
            acc2[nt] = __builtin_amdgcn_mfma_f32_16x16x32_bf16(Ahi, Bhi, acc2[nt], 0, 0, 0);
            acc2[nt] = __builtin_amdgcn_mfma_f32_16x16x32_bf16(Alo, Bhi, acc2[nt], 0, 0, 0);
            acc2[nt] = __builtin_amdgcn_mfma_f32_16x16x32_bf16(Ahi, Blo, acc2[nt], 0, 0, 0);
        }
    }
    #pragma unroll
    for (int nt = 0; nt < 2; ++nt) {
        #pragma unroll
        for (int i = 0; i < 4; ++i)
            mod_ws[(size_t)(qbase + kg*4 + i)*256 + wid*32 + nt*16 + c] = acc2[nt][i];
    }
}

// ---------------- query kernel v4 ----------------
// LDS row (per latent px), 452 floats:
//   [0..63]    g   = sc1*f0 + sh1
//   [64..319]  u_t = sc1*W0row(64+t), t=0..3
//   [320..383] sc2
//   [384..447] sh2
#define ROWP2 452

__global__ __launch_bounds__(256) void query_kernel_v4(
    const float* __restrict__ coord,
    const float* __restrict__ cell,
    const float* __restrict__ W0,
    const float* __restrict__ W1,
    const float* __restrict__ b1,
    const float* __restrict__ W2,
    const float* __restrict__ b2,
    const float* __restrict__ mod_ws,
    const float* __restrict__ f0_ws,
    float* __restrict__ out)
{
    __shared__ float smem[16*ROWP2];    // 28.3 KB

    const int tid = threadIdx.x;
    const int bX  = blockIdx.x % 48;
    const int bY  = blockIdx.x / 48;
    const int X0  = bX * 8;
    const int Y0  = bY * 8;
    const int lx0 = bX*2 - 1;
    const int ly0 = bY*2 - 1;

    // ---- stage 4x4 latent patch with modulate folded in: 16 rows x 112 f4 ----
    for (int idx = tid; idx < 1792; idx += 256) {
        const int r  = idx / 112;
        const int o  = idx - r*112;
        const int ry = r >> 2;
        const int rx = r & 3;
        const int gy = min(max(ly0 + ry, 0), 95);
        const int gx = min(max(lx0 + rx, 0), 95);
        const int src = gy*96 + gx;
        const float4* modv = (const float4*)(mod_ws + (size_t)src*256);
        float4 v;
        int dst;
        if (o < 16) {
            const float4 f0 = ((const float4*)(f0_ws + (size_t)src*64))[o];
            const float4 s1 = modv[o];
            const float4 t1 = modv[32 + o];
            v.x = fmaf(f0.x, s1.x, t1.x);
            v.y = fmaf(f0.y, s1.y, t1.y);
            v.z = fmaf(f0.z, s1.z, t1.z);
            v.w = fmaf(f0.w, s1.w, t1.w);
            dst = r*ROWP2 + o*4;
        } else if (o < 80) {
            const int t  = (o - 16) >> 4;
            const int oo = (o - 16) & 15;
            const float4 s1 = modv[oo];
            const float4 w  = *(const float4*)(W0 + (64 + t)*64 + oo*4);
            v.x = s1.x * w.x;
            v.y = s1.y * w.y;
            v.z = s1.z * w.z;
            v.w = s1.w * w.w;
            dst = r*ROWP2 + 64 + (o - 16)*4;
        } else {
            const int oo = o - 80;               // 0..31: sc2 then sh2
            v = (oo < 16) ? modv[16 + oo] : modv[32 + oo];
            dst = r*ROWP2 + 320 + oo*4;
        }
        *(float4*)(smem + dst) = v;
    }

    const int lane = tid & 63;
    const int wid  = tid >> 6;
    const int c    = lane & 15;
    const int kg   = lane >> 4;

    // per-wave constants
    short8 Bh[4][2];
    #pragma unroll
    for (int nt = 0; nt < 4; ++nt) {
        #pragma unroll
        for (int kt = 0; kt < 2; ++kt) {
            union { short8 s; unsigned u[4]; } H;
            #pragma unroll
            for (int p = 0; p < 4; ++p) {
                float a = W1[(kt*32 + kg*8 + 2*p    )*64 + nt*16 + c];
                float b = W1[(kt*32 + kg*8 + 2*p + 1)*64 + nt*16 + c];
                H.u[p] = pack_bf2_rne(a, b);
            }
            Bh[nt][kt] = H.s;
        }
    }
    float b1c[4];
    float w2r[4][3];
    #pragma unroll
    for (int nt = 0; nt < 4; ++nt) {
        b1c[nt] = b1[nt*16 + c];
        w2r[nt][0] = W2[(nt*16 + c)*3 + 0];
        w2r[nt][1] = W2[(nt*16 + c)*3 + 1];
        w2r[nt][2] = W2[(nt*16 + c)*3 + 2];
    }
    const float b2v0 = b2[0], b2v1 = b2[1], b2v2 = b2[2];

    __syncthreads();

    const int Xw   = X0 + (wid & 1)*4;
    const int Yw   = Y0 + (wid >> 1)*4;
    const int qxA  = c >> 2;
    const int tapA = c & 3;
    const float vxA = (tapA < 2) ? -1.0f : 1.0f;
    const float vyA = (tapA & 1) ? 1.0f : -1.0f;
    const float2* coordv = (const float2*)coord;
    const float2* cellv  = (const float2*)cell;

    #pragma unroll 2
    for (int m = 0; m < 4; ++m) {
        const int qy = Yw + m;

        // ================= A-build =================
        short8 Ahi[2], Alo[2];
        {
            const int qA = qy*384 + Xw + qxA;
            const float2 cv = coordv[qA];
            const float2 ce = cellv[qA];
            const float rc0 = ce.x * 96.0f;
            const float rc1 = ce.y * 96.0f;
            int iyA, ixA; float r0A, r1A;
            AXCALC(cv.x, vxA, iyA, r0A)
            AXCALC(cv.y, vyA, ixA, r1A)
            const float* rowp = smem + ((iyA - ly0)*4 + (ixA - lx0)) * ROWP2;
            #pragma unroll
            for (int kt = 0; kt < 2; ++kt) {
                const int kb = kt*32 + kg*8;
                const float4 ga  = *(const float4*)(rowp + kb);
                const float4 gb  = *(const float4*)(rowp + kb + 4);
                const float4 u0a = *(const float4*)(rowp + 64  + kb);
                const float4 u0b = *(const float4*)(rowp + 64  + kb + 4);
                const float4 u1a = *(const float4*)(rowp + 128 + kb);
                const float4 u1b = *(const float4*)(rowp + 128 + kb + 4);
                const float4 u2a = *(const float4*)(rowp + 192 + kb);
                const float4 u2b = *(const float4*)(rowp + 192 + kb + 4);
                const float4 u3a = *(const float4*)(rowp + 256 + kb);
                const float4 u3b = *(const float4*)(rowp + 256 + kb + 4);
                float g[8]  = {ga.x,ga.y,ga.z,ga.w,gb.x,gb.y,gb.z,gb.w};
                float u0[8] = {u0a.x,u0a.y,u0a.z,u0a.w,u0b.x,u0b.y,u0b.z,u0b.w};
                float u1[8] = {u1a.x,u1a.y,u1a.z,u1a.w,u1b.x,u1b.y,u1b.z,u1b.w};
                float u2[8] = {u2a.x,u2a.y,u2a.z,u2a.w,u2b.x,u2b.y,u2b.z,u2b.w};
                float u3[8] = {u3a.x,u3a.y,u3a.z,u3a.w,u3b.x,u3b.y,u3b.z,u3b.w};
                float hv[8];
                #pragma unroll
                for (int j = 0; j < 8; ++j) {
                    float pre = g[j];
                    pre = fmaf(r0A, u0[j], pre);
                    pre = fmaf(r1A, u1[j], pre);
                    pre = fmaf(rc0, u2[j], pre);
                    pre = fmaf(rc1, u3[j], pre);
                    hv[j] = fmaxf(pre, 0.f);
                }
                split8(hv, Ahi[kt], Alo[kt]);
            }
        }

        // ================= MFMA =================
        f32x4 acc[4];
        #pragma unroll
        for (int nt = 0; nt < 4; ++nt) {
            f32x4 a0 = {b1c[nt], b1c[nt], b1c[nt], b1c[nt]};
            acc[nt] = a0;
        }
        #pragma unroll
        for (int nt = 0; nt < 4; ++nt) {
            #pragma unroll
            for (int kt = 0; kt < 2; ++kt) {
                acc[nt] = __builtin_amdgcn_mfma_f32_16x16x32_bf16(Ahi[kt], Bh[nt][kt], acc[nt], 0, 0, 0);
                acc[nt] = __builtin_amdgcn_mfma_f32_16x16x32_bf16(Alo[kt], Bh[nt][kt], acc[nt], 0, 0, 0);
            }
        }

        // ================= epilogue (factored tap math) =================
        const int qE = qy*384 + Xw + kg;
        const float2 cv = coordv[qE];
        int iym, iyp, ixm, ixp;
        float r0m, r0p, r1m, r1p;
        AXCALC(cv.x, -1.0f, iym, r0m)
        AXCALC(cv.x,  1.0f, iyp, r0p)
        AXCALC(cv.y, -1.0f, ixm, r1m)
        AXCALC(cv.y,  1.0f, ixp, r1p)
        const float a0 = fabsf(r0m*r1m) + 1e-9f;
        const float a1 = fabsf(r0m*r1p) + 1e-9f;
        const float a2 = fabsf(r0p*r1m) + 1e-9f;
        const float a3 = fabsf(r0p*r1p) + 1e-9f;
        const int rym = (iym - ly0)*4 - lx0;
        const int ryp = (iyp - ly0)*4 - lx0;
        const int lr0 = rym + ixm, lr1 = rym + ixp;
        const int lr2 = ryp + ixm, lr3 = ryp + ixp;
        const float invt = 1.0f / (a0 + a1 + a2 + a3);
        const float w0_ = a3 * invt, w1_ = a2 * invt, w2_ = a1 * invt, w3_ = a0 * invt;

        float p0 = 0.f, p1 = 0.f, p2 = 0.f;
        #pragma unroll
        for (int i = 0; i < 4; ++i) {
            const int   lri = (i == 0) ? lr0 : (i == 1) ? lr1 : (i == 2) ? lr2 : lr3;
            const float wi  = (i == 0) ? w0_ : (i == 1) ? w1_ : (i == 2) ? w2_ : w3_;
            const float* rp = smem + lri*ROWP2;
            float s0 = 0.f, s1 = 0.f, s2 = 0.f;
            #pragma unroll
            for (int nt = 0; nt < 4; ++nt) {
                const float sc2 = rp[320 + nt*16 + c];
                const float sh2 = rp[384 + nt*16 + c];
                const float v = fmaxf(fmaf(acc[nt][i], sc2, sh2), 0.f);
                s0 = fmaf(v, w2r[nt][0], s0);
                s1 = fmaf(v, w2r[nt][1], s1);
                s2 = fmaf(v, w2r[nt][2], s2);
            }
            p0 = fmaf(s0, wi, p0);
            p1 = fmaf(s1, wi, p1);
            p2 = fmaf(s2, wi, p2);
        }
        #pragma unroll
        for (int d = 1; d < 16; d <<= 1) {
            p0 += __shfl_xor(p0, d);
            p1 += __shfl_xor(p1, d);
            p2 += __shfl_xor(p2, d);
        }
        if (c < 3) {
            const float ov = (c == 0) ? p0 + b2v0 : (c == 1) ? p1 + b2v1 : p2 + b2v2;
            out[(size_t)qE*3 + c] = ov;
        }
    }
}

extern "C" void kernel_launch(void* const* d_in, const int* in_sizes, int n_in,
                              void* d_out, int out_size, void* d_ws, size_t ws_size,
                              hipStream_t stream) {
    const float* feat  = (const float*)d_in[0];
    const float* coord = (const float*)d_in[1];
    const float* cell  = (const float*)d_in[2];
    const float* Wh1   = (const float*)d_in[3];
    const float* bh1   = (const float*)d_in[4];
    const float* Wh2   = (const float*)d_in[5];
    const float* bh2   = (const float*)d_in[6];
    const float* W0    = (const float*)d_in[7];
    const float* b0    = (const float*)d_in[8];
    const float* W1    = (const float*)d_in[9];
    const float* b1    = (const float*)d_in[10];
    const float* W2    = (const float*)d_in[11];
    const float* b2    = (const float*)d_in[12];
    float* out = (float*)d_out;

    float* mod_ws = (float*)d_ws;                         // 9216*256 f32
    float* f0_ws  = (float*)d_ws + 9216*256;              // 9216*64  f32
    short* wsw    = (short*)((char*)d_ws + 11796480);     // 424 frags * 2048 B

    swizzle_kernel<<<dim3(106), dim3(256), 0, stream>>>(Wh1, Wh2, W0, wsw);
    hyper_mfma<<<dim3(576), dim3(512), 0, stream>>>(
        feat, cell, Wh1, bh1, bh2, b0, wsw, mod_ws, f0_ws);
    query_kernel_v4<<<dim3(2304), dim3(256), 0, stream>>>(
        coord, cell, W0, W1, b1, W2, b2, mod_ws, f0_ws, out);
}

// Round 8
// 90.017 us; speedup vs baseline: 6.2554x; 1.1286x over previous
//
#include <hip/hip_runtime.h>

// LM-LIIF fused pipeline. R7: query kernel v5.
//  - rel_cell folded at stage time (cell is query-uniform; value READ from the
//    cell buffer): g' = s1*(f0 + rc0*w66 + rc1*w67) + t1. A-build = 2 rank-1.
//  - coords computed arithmetically (same formula as reference) -> no global
//    loads in the main loop at all.
//  - sc2/sh2 stored transposed [c][nt] -> epilogue reads 8 x b128 (was 32 b32),
//    issued before the MFMA.
//  - 16-lane reduce via DPP adds (quad_perm 0xB1/0x4E, half-mirror, mirror) --
//    pure VALU, replaces 12 ds_bpermute.
//  - hyper_mfma / swizzle_kernel unchanged from R5/R6.

#define HW 96
#define NPIX (96*96)
#define CFEAT 64
#define INV192 (1.0f/192.0f)

typedef __attribute__((ext_vector_type(8))) short short8;
typedef __attribute__((ext_vector_type(4))) float f32x4;

__device__ __forceinline__ unsigned pack_bf2(float a, float b) {
    unsigned ua = __builtin_bit_cast(unsigned, a);
    unsigned ub = __builtin_bit_cast(unsigned, b);
    return (ua >> 16) | (ub & 0xffff0000u);
}
__device__ __forceinline__ float bf_hi(float a) {
    return __builtin_bit_cast(float, __builtin_bit_cast(unsigned, a) & 0xffff0000u);
}
__device__ __forceinline__ void split8(const float (&v)[8], short8& hi, short8& lo) {
    union { short8 s; unsigned u[4]; } H, L;
    #pragma unroll
    for (int p = 0; p < 4; ++p) {
        float a = v[2*p], b = v[2*p+1];
        H.u[p] = pack_bf2(a, b);
        L.u[p] = pack_bf2(a - bf_hi(a), b - bf_hi(b));
    }
    hi = H.s; lo = L.s;
}
__device__ __forceinline__ unsigned rne16(float x) {
    unsigned u = __builtin_bit_cast(unsigned, x);
    return (u + 0x7fffu + ((u >> 16) & 1u)) >> 16;
}
__device__ __forceinline__ unsigned pack_bf2_rne(float a, float b) {
    return rne16(a) | (rne16(b) << 16);
}
__device__ __forceinline__ short top16(float a) {
    return (short)(__builtin_bit_cast(unsigned, a) >> 16);
}

// sum over the 16-lane group via DPP (all lanes end with the group sum)
__device__ __forceinline__ float dpp_red16(float v) {
    int x;
    x = __builtin_amdgcn_update_dpp(0, __builtin_bit_cast(int, v), 0xB1, 0xF, 0xF, true);
    v += __builtin_bit_cast(float, x);                       // xor 1 (quad_perm [1,0,3,2])
    x = __builtin_amdgcn_update_dpp(0, __builtin_bit_cast(int, v), 0x4E, 0xF, 0xF, true);
    v += __builtin_bit_cast(float, x);                       // xor 2 (quad_perm [2,3,0,1])
    x = __builtin_amdgcn_update_dpp(0, __builtin_bit_cast(int, v), 0x141, 0xF, 0xF, true);
    v += __builtin_bit_cast(float, x);                       // half-row mirror (quad swap)
    x = __builtin_amdgcn_update_dpp(0, __builtin_bit_cast(int, v), 0x140, 0xF, 0xF, true);
    v += __builtin_bit_cast(float, x);                       // row mirror (half swap)
    return v;
}

#define AXCALC(CV, SGN, II, RR)                                        \
{                                                                      \
    float e = CV + (SGN)*(1.0f/96.0f) + 1e-6f;                         \
    e = fminf(fmaxf(e, -1.0f + 1e-6f), 1.0f - 1e-6f);                  \
    II = (int)rintf((e + 1.0f) * 48.0f - 0.5f);                        \
    II = min(max(II, 0), 95);                                          \
    RR = (CV - fmaf((float)II, 0.0208333333f, -0.9895833333f)) * 96.0f;\
}

// ---------------- weight pre-swizzle (unchanged) ----------------
__global__ __launch_bounds__(256) void swizzle_kernel(
    const float* __restrict__ Wh1, const float* __restrict__ Wh2,
    const float* __restrict__ W0, short* __restrict__ wsw)
{
    const int gid = blockIdx.x*256 + threadIdx.x;
    if (gid >= 424*64) return;
    const int f    = gid >> 6;
    const int lane = gid & 63;
    const int c    = lane & 15;
    const int kg   = lane >> 4;
    const float* W; int kt, nt, N;
    if (f < 288)      { W = Wh1; kt = f >> 4;        nt = f & 15;        N = 256; }
    else if (f < 416) { W = Wh2; kt = (f-288) >> 4;  nt = (f-288) & 15;  N = 256; }
    else              { W = W0;  kt = (f-416) >> 2;  nt = (f-416) & 3;   N = 64;  }
    float v[8];
    #pragma unroll
    for (int j = 0; j < 8; ++j)
        v[j] = W[(kt*32 + kg*8 + j)*N + nt*16 + c];
    short8 hi, lo;
    split8(v, hi, lo);
    *(short8*)(wsw + (size_t)f*1024 + lane*8)       = hi;
    *(short8*)(wsw + (size_t)f*1024 + 512 + lane*8) = lo;
}

// ---------------- hyper net (unchanged) ----------------
__global__ __launch_bounds__(512) void hyper_mfma(
    const float* __restrict__ feat,
    const float* __restrict__ cell,
    const float* __restrict__ Wh1,
    const float* __restrict__ bh1,
    const float* __restrict__ bh2,
    const float* __restrict__ b0,
    const short* __restrict__ wsw,
    float* __restrict__ mod_ws,
    float* __restrict__ f0_ws)
{
    __shared__ short AHI[72*128];
    __shared__ short ALO[72*128];
    __shared__ short HHI[32*128];
    __shared__ short HLO[32*128];

    const int tid = threadIdx.x;
    const int blk = blockIdx.x;
    const int y   = blk / 6;
    const int x0  = (blk % 6) * 16;
    const int qbase = y*HW + x0;

    for (int idx = tid; idx < 9216; idx += 512) {
        const int px = idx & 15;
        const int k  = idx >> 4;
        const int ch = k / 9;
        const int j  = k - 9*ch;
        const int dy = j / 3;
        const int dx = j - 3*dy;
        const int gy = y + dy - 1;
        const int gx = x0 + px + dx - 1;
        float v = 0.0f;
        if (gy >= 0 && gy < HW && gx >= 0 && gx < HW)
            v = feat[ch*NPIX + gy*HW + gx];
        const int dst = (k >> 3)*128 + px*8 + (k & 7);
        AHI[dst] = top16(v);
        ALO[dst] = top16(v - bf_hi(v));
    }
    __syncthreads();

    const int lane = tid & 63;
    const int wid  = tid >> 6;
    const int c    = lane & 15;
    const int kg   = lane >> 4;

    const short* wh1f = wsw;
    const short* wh2f = wsw + (size_t)288*1024;
    const short* w0f  = wsw + (size_t)416*1024;

    if (wid < 4) {
        f32x4 acc0;
        const float bb = b0[wid*16 + c];
        acc0[0] = bb; acc0[1] = bb; acc0[2] = bb; acc0[3] = bb;
        #pragma unroll
        for (int kt = 0; kt < 2; ++kt) {
            float v[8];
            #pragma unroll
            for (int j = 0; j < 8; ++j)
                v[j] = feat[(kt*32 + kg*8 + j)*NPIX + y*HW + x0 + c];
            short8 Ahi, Alo;
            split8(v, Ahi, Alo);
            const short* bp = w0f + (size_t)(kt*4 + wid)*1024 + lane*8;
            const short8 Bhi = *(const short8*)bp;
            const short8 Blo = *(const short8*)(bp + 512);
            acc0 = __builtin_amdgcn_mfma_f32_16x16x32_bf16(Ahi, Bhi, acc0, 0, 0, 0);
            acc0 = __builtin_amdgcn_mfma_f32_16x16x32_bf16(Alo, Bhi, acc0, 0, 0, 0);
            acc0 = __builtin_amdgcn_mfma_f32_16x16x32_bf16(Ahi, Blo, acc0, 0, 0, 0);
        }
        #pragma unroll
        for (int i = 0; i < 4; ++i)
            f0_ws[(size_t)(qbase + kg*4 + i)*64 + wid*16 + c] = acc0[i];
    }

    f32x4 acc[2];
    #pragma unroll
    for (int nt = 0; nt < 2; ++nt) {
        const float bb = bh1[wid*32 + nt*16 + c];
        acc[nt][0] = bb; acc[nt][1] = bb; acc[nt][2] = bb; acc[nt][3] = bb;
    }
    #pragma unroll
    for (int kt = 0; kt < 18; ++kt) {
        const int aoff = (kt*4 + kg)*128 + c*8;
        const short8 Ahi = *(const short8*)&AHI[aoff];
        const short8 Alo = *(const short8*)&ALO[aoff];
        #pragma unroll
        for (int nt = 0; nt < 2; ++nt) {
            const short* bp = wh1f + (size_t)(kt*16 + wid*2 + nt)*1024 + lane*8;
            const short8 Bhi = *(const short8*)bp;
            const short8 Blo = *(const short8*)(bp + 512);
            acc[nt] = __builtin_amdgcn_mfma_f32_16x16x32_bf16(Ahi, Bhi, acc[nt], 0, 0, 0);
            acc[nt] = __builtin_amdgcn_mfma_f32_16x16x32_bf16(Alo, Bhi, acc[nt], 0, 0, 0);
            acc[nt] = __builtin_amdgcn_mfma_f32_16x16x32_bf16(Ahi, Blo, acc[nt], 0, 0, 0);
        }
    }
    {
        float rc0v[4], rc1v[4];
        #pragma unroll
        for (int i = 0; i < 4; ++i) {
            const int q = qbase + kg*4 + i;
            const float2 ce = ((const float2*)cell)[q];
            rc0v[i] = ce.x * 96.0f;
            rc1v[i] = ce.y * 96.0f;
        }
        #pragma unroll
        for (int nt = 0; nt < 2; ++nt) {
            const int n = wid*32 + nt*16 + c;
            const float w5 = Wh1[576*256 + n];
            const float w6 = Wh1[577*256 + n];
            #pragma unroll
            for (int i = 0; i < 4; ++i) {
                float hv = acc[nt][i] + rc0v[i]*w5 + rc1v[i]*w6;
                hv = fmaxf(hv, 0.0f);
                const int dst = (n >> 3)*128 + (kg*4 + i)*8 + (n & 7);
                HHI[dst] = top16(hv);
                HLO[dst] = top16(hv - bf_hi(hv));
            }
        }
    }
    __syncthreads();

    f32x4 acc2[2];
    #pragma unroll
    for (int nt = 0; nt < 2; ++nt) {
        const float bb = bh2[wid*32 + nt*16 + c];
        acc2[nt][0] = bb; acc2[nt][1] = bb; acc2[nt][2] = bb; acc2[nt][3] = bb;
    }
    #pragma unroll
    for (int kt = 0; kt < 8; ++kt) {
        const int aoff = (kt*4 + kg)*128 + c*8;
        const short8 Ahi = *(const short8*)&HHI[aoff];
        const short8 Alo = *(const short8*)&HLO[aoff];
        #pragma unroll
        for (int nt = 0; nt < 2; ++nt) {
            const short* bp = wh2f + (size_t)(kt*16 + wid*2 + nt)*1024 + lane*8;
            const short8 Bhi = *(const short8*)bp;
            const short8 Blo = *(const short8*)(bp + 512);
            acc2[nt] = __builtin_amdgcn_mfma_f32_16x16x32_bf16(Ahi, Bhi, acc2[nt], 0, 0, 0);
            acc2[nt] = __builtin_amdgcn_mfma_f32_16x16x32_bf16(Alo, Bhi, acc2[nt], 0, 0, 0);
            acc2[nt] = __builtin_amdgcn_mfma_f32_16x16x32_bf16(Ahi, Blo, acc2[nt], 0, 0, 0);
        }
    }
    #pragma unroll
    for (int nt = 0; nt < 2; ++nt) {
        #pragma unroll
        for (int i = 0; i < 4; ++i)
            mod_ws[(size_t)(qbase + kg*4 + i)*256 + wid*32 + nt*16 + c] = acc2[nt][i];
    }
}

// ---------------- query kernel v5 ----------------
// LDS row (per latent px), 324 floats:
//   [0..63]    g'  = s1*(f0 + rc0*w66 + rc1*w67) + t1
//   [64..127]  u0  = s1*W0row64
//   [128..191] u1  = s1*W0row65
//   [192..255] sc2T  ([c][nt]: sc2T[c*4+nt] = mod[64+nt*16+c])
//   [256..319] sh2T  ([c][nt]: sh2T[c*4+nt] = mod[192+nt*16+c])
#define ROWQ 324

__global__ __launch_bounds__(256) void query_kernel_v5(
    const float* __restrict__ cell,
    const float* __restrict__ W0,
    const float* __restrict__ W1,
    const float* __restrict__ b1,
    const float* __restrict__ W2,
    const float* __restrict__ b2,
    const float* __restrict__ mod_ws,
    const float* __restrict__ f0_ws,
    float* __restrict__ out)
{
    __shared__ float smem[16*ROWQ];    // 20.3 KB

    const int tid = threadIdx.x;
    const int bX  = blockIdx.x % 48;
    const int bY  = blockIdx.x / 48;
    const int X0  = bX * 8;
    const int Y0  = bY * 8;
    const int lx0 = bX*2 - 1;
    const int ly0 = bY*2 - 1;

    const float rc0 = cell[0] * 96.0f;   // query-uniform (read from buffer)
    const float rc1 = cell[1] * 96.0f;

    const float4* w64p = (const float4*)(W0 + 64*64);
    const float4* w65p = (const float4*)(W0 + 65*64);
    const float4* w66p = (const float4*)(W0 + 66*64);
    const float4* w67p = (const float4*)(W0 + 67*64);

    // ---- stage 4x4 latent patch: 16 rows x 64 items ----
    for (int idx = tid; idx < 1024; idx += 256) {
        const int r  = idx >> 6;
        const int o  = idx & 63;
        const int ry = r >> 2;
        const int rx = r & 3;
        const int gy = min(max(ly0 + ry, 0), 95);
        const int gx = min(max(lx0 + rx, 0), 95);
        const int src = gy*96 + gx;
        const float4* modv = (const float4*)(mod_ws + (size_t)src*256);
        if (o < 16) {
            const float4 f0 = ((const float4*)(f0_ws + (size_t)src*64))[o];
            const float4 s1 = modv[o];
            const float4 t1 = modv[32 + o];
            const float4 a  = w66p[o];
            const float4 b  = w67p[o];
            float4 v;
            v.x = fmaf(s1.x, fmaf(rc1, b.x, fmaf(rc0, a.x, f0.x)), t1.x);
            v.y = fmaf(s1.y, fmaf(rc1, b.y, fmaf(rc0, a.y, f0.y)), t1.y);
            v.z = fmaf(s1.z, fmaf(rc1, b.z, fmaf(rc0, a.z, f0.z)), t1.z);
            v.w = fmaf(s1.w, fmaf(rc1, b.w, fmaf(rc0, a.w, f0.w)), t1.w);
            *(float4*)(smem + r*ROWQ + o*4) = v;
        } else if (o < 32) {
            const int oo = o - 16;
            const float4 s1 = modv[oo];
            const float4 w  = w64p[oo];
            float4 v = {s1.x*w.x, s1.y*w.y, s1.z*w.z, s1.w*w.w};
            *(float4*)(smem + r*ROWQ + 64 + oo*4) = v;
        } else if (o < 48) {
            const int oo = o - 32;
            const float4 s1 = modv[oo];
            const float4 w  = w65p[oo];
            float4 v = {s1.x*w.x, s1.y*w.y, s1.z*w.z, s1.w*w.w};
            *(float4*)(smem + r*ROWQ + 128 + oo*4) = v;
        } else {
            const int oo = o - 48;
            const float4 s2 = modv[16 + oo];   // sc2 cols oo*4..+3
            const float4 h2 = modv[48 + oo];   // sh2 cols oo*4..+3
            #pragma unroll
            for (int j = 0; j < 4; ++j) {
                const int col = oo*4 + j;
                const int cc  = col & 15;
                const int nt  = col >> 4;
                const float sv = (j==0)?s2.x:(j==1)?s2.y:(j==2)?s2.z:s2.w;
                const float hv = (j==0)?h2.x:(j==1)?h2.y:(j==2)?h2.z:h2.w;
                smem[r*ROWQ + 192 + cc*4 + nt] = sv;
                smem[r*ROWQ + 256 + cc*4 + nt] = hv;
            }
        }
    }

    const int lane = tid & 63;
    const int wid  = tid >> 6;
    const int c    = lane & 15;
    const int kg   = lane >> 4;

    // per-wave constants
    short8 Bh[4][2];
    #pragma unroll
    for (int nt = 0; nt < 4; ++nt) {
        #pragma unroll
        for (int kt = 0; kt < 2; ++kt) {
            union { short8 s; unsigned u[4]; } H;
            #pragma unroll
            for (int p = 0; p < 4; ++p) {
                float a = W1[(kt*32 + kg*8 + 2*p    )*64 + nt*16 + c];
                float b = W1[(kt*32 + kg*8 + 2*p + 1)*64 + nt*16 + c];
                H.u[p] = pack_bf2_rne(a, b);
            }
            Bh[nt][kt] = H.s;
        }
    }
    float b1c[4];
    float w2r[4][3];
    #pragma unroll
    for (int nt = 0; nt < 4; ++nt) {
        b1c[nt] = b1[nt*16 + c];
        w2r[nt][0] = W2[(nt*16 + c)*3 + 0];
        w2r[nt][1] = W2[(nt*16 + c)*3 + 1];
        w2r[nt][2] = W2[(nt*16 + c)*3 + 2];
    }
    const float b2v0 = b2[0], b2v1 = b2[1], b2v2 = b2[2];

    __syncthreads();

    const int Xw   = X0 + (wid & 1)*4;
    const int Yw   = Y0 + (wid >> 1)*4;
    const int qxA  = c >> 2;
    const int tapA = c & 3;
    const float vxA = (tapA < 2) ? -1.0f : 1.0f;
    const float vyA = (tapA & 1) ? 1.0f : -1.0f;

    const float cxA = ((float)(Xw + qxA) + 0.5f) * INV192 - 1.0f;
    const float cxE = ((float)(Xw + kg)  + 0.5f) * INV192 - 1.0f;
    int ixm, ixp; float r1m, r1p;
    AXCALC(cxE, -1.0f, ixm, r1m)      // x-axis tap math is m-invariant
    AXCALC(cxE,  1.0f, ixp, r1p)

    #pragma unroll 2
    for (int m = 0; m < 4; ++m) {
        const int qy = Yw + m;
        const float cy = ((float)qy + 0.5f) * INV192 - 1.0f;

        // ================= A-build =================
        short8 Ahi[2], Alo[2];
        {
            int iyA, ixA; float r0A, r1A;
            AXCALC(cy,  vxA, iyA, r0A)
            AXCALC(cxA, vyA, ixA, r1A)
            const float* rowp = smem + ((iyA - ly0)*4 + (ixA - lx0)) * ROWQ;
            #pragma unroll
            for (int kt = 0; kt < 2; ++kt) {
                const int kb = kt*32 + kg*8;
                const float4 ga  = *(const float4*)(rowp + kb);
                const float4 gb  = *(const float4*)(rowp + kb + 4);
                const float4 u0a = *(const float4*)(rowp + 64  + kb);
                const float4 u0b = *(const float4*)(rowp + 64  + kb + 4);
                const float4 u1a = *(const float4*)(rowp + 128 + kb);
                const float4 u1b = *(const float4*)(rowp + 128 + kb + 4);
                float g[8]  = {ga.x,ga.y,ga.z,ga.w,gb.x,gb.y,gb.z,gb.w};
                float u0[8] = {u0a.x,u0a.y,u0a.z,u0a.w,u0b.x,u0b.y,u0b.z,u0b.w};
                float u1[8] = {u1a.x,u1a.y,u1a.z,u1a.w,u1b.x,u1b.y,u1b.z,u1b.w};
                float hv[8];
                #pragma unroll
                for (int j = 0; j < 8; ++j) {
                    float pre = fmaf(r0A, u0[j], g[j]);
                    pre = fmaf(r1A, u1[j], pre);
                    hv[j] = fmaxf(pre, 0.f);
                }
                split8(hv, Ahi[kt], Alo[kt]);
            }
        }

        // ================= epilogue indices + early LDS loads =================
        int iym, iyp; float r0m, r0p;
        AXCALC(cy, -1.0f, iym, r0m)
        AXCALC(cy,  1.0f, iyp, r0p)
        const int rym = (iym - ly0)*4 - lx0;
        const int ryp = (iyp - ly0)*4 - lx0;
        const int lr0 = rym + ixm, lr1 = rym + ixp;
        const int lr2 = ryp + ixm, lr3 = ryp + ixp;
        float4 sc2v[4], sh2v[4];
        #pragma unroll
        for (int i = 0; i < 4; ++i) {
            const int lri = (i == 0) ? lr0 : (i == 1) ? lr1 : (i == 2) ? lr2 : lr3;
            sc2v[i] = *(const float4*)(smem + lri*ROWQ + 192 + c*4);
            sh2v[i] = *(const float4*)(smem + lri*ROWQ + 256 + c*4);
        }
        const float a0 = fabsf(r0m*r1m) + 1e-9f;
        const float a1 = fabsf(r0m*r1p) + 1e-9f;
        const float a2 = fabsf(r0p*r1m) + 1e-9f;
        const float a3 = fabsf(r0p*r1p) + 1e-9f;
        const float invt = 1.0f / (a0 + a1 + a2 + a3);
        const float w0_ = a3 * invt, w1_ = a2 * invt, w2_ = a1 * invt, w3_ = a0 * invt;

        // ================= MFMA =================
        f32x4 acc[4];
        #pragma unroll
        for (int nt = 0; nt < 4; ++nt) {
            f32x4 z = {b1c[nt], b1c[nt], b1c[nt], b1c[nt]};
            acc[nt] = z;
        }
        #pragma unroll
        for (int nt = 0; nt < 4; ++nt) {
            #pragma unroll
            for (int kt = 0; kt < 2; ++kt) {
                acc[nt] = __builtin_amdgcn_mfma_f32_16x16x32_bf16(Ahi[kt], Bh[nt][kt], acc[nt], 0, 0, 0);
                acc[nt] = __builtin_amdgcn_mfma_f32_16x16x32_bf16(Alo[kt], Bh[nt][kt], acc[nt], 0, 0, 0);
            }
        }

        // ================= modulate2 + layer2 + blend =================
        float p0 = 0.f, p1 = 0.f, p2 = 0.f;
        #pragma unroll
        for (int i = 0; i < 4; ++i) {
            const float wi = (i == 0) ? w0_ : (i == 1) ? w1_ : (i == 2) ? w2_ : w3_;
            float s0 = 0.f, s1 = 0.f, s2 = 0.f;
            #pragma unroll
            for (int nt = 0; nt < 4; ++nt) {
                const float sc2 = (nt==0)?sc2v[i].x:(nt==1)?sc2v[i].y:(nt==2)?sc2v[i].z:sc2v[i].w;
                const float sh2 = (nt==0)?sh2v[i].x:(nt==1)?sh2v[i].y:(nt==2)?sh2v[i].z:sh2v[i].w;
                const float v = fmaxf(fmaf(acc[nt][i], sc2, sh2), 0.f);
                s0 = fmaf(v, w2r[nt][0], s0);
                s1 = fmaf(v, w2r[nt][1], s1);
                s2 = fmaf(v, w2r[nt][2], s2);
            }
            p0 = fmaf(s0, wi, p0);
            p1 = fmaf(s1, wi, p1);
            p2 = fmaf(s2, wi, p2);
        }
        p0 = dpp_red16(p0);
        p1 = dpp_red16(p1);
        p2 = dpp_red16(p2);
        if (c < 3) {
            const int qE = qy*384 + Xw + kg;
            const float ov = (c == 0) ? p0 + b2v0 : (c == 1) ? p1 + b2v1 : p2 + b2v2;
            out[(size_t)qE*3 + c] = ov;
        }
    }
}

extern "C" void kernel_launch(void* const* d_in, const int* in_sizes, int n_in,
                              void* d_out, int out_size, void* d_ws, size_t ws_size,
                              hipStream_t stream) {
    const float* feat  = (const float*)d_in[0];
    const float* cell  = (const float*)d_in[2];
    const float* Wh1   = (const float*)d_in[3];
    const float* bh1   = (const float*)d_in[4];
    const float* Wh2   = (const float*)d_in[5];
    const float* bh2   = (const float*)d_in[6];
    const float* W0    = (const float*)d_in[7];
    const float* b0    = (const float*)d_in[8];
    const float* W1    = (const float*)d_in[9];
    const float* b1    = (const float*)d_in[10];
    const float* W2    = (const float*)d_in[11];
    const float* b2    = (const float*)d_in[12];
    float* out = (float*)d_out;

    float* mod_ws = (float*)d_ws;                         // 9216*256 f32
    float* f0_ws  = (float*)d_ws + 9216*256;              // 9216*64  f32
    short* wsw    = (short*)((char*)d_ws + 11796480);     // 424 frags * 2048 B

    swizzle_kernel<<<dim3(106), dim3(256), 0, stream>>>(Wh1, Wh2, W0, wsw);
    hyper_mfma<<<dim3(576), dim3(512), 0, stream>>>(
        feat, cell, Wh1, bh1, bh2, b0, wsw, mod_ws, f0_ws);
    query_kernel_v5<<<dim3(2304), dim3(256), 0, stream>>>(
        cell, W0, W1, b1, W2, b2, mod_ws, f0_ws, out);
}

// Round 9
// 87.284 us; speedup vs baseline: 6.4512x; 1.0313x over previous
//
#include <hip/hip_runtime.h>

// LM-LIIF fused pipeline. R8:
//  - hyper: B = RNE-bf16 only (no B_lo plane) -> halves weight L2 traffic and
//    removes 1/3 of MFMAs. A-side split (Ahi+Alo) kept exact. Same scheme the
//    query kernel has used for W1 since R3 (absmax unchanged there).
//  - query v6: 512-thr block / 16x8 query tile (1152 blocks, 24-row patch);
//    sc2T/sh2T interleaved per column -> epilogue = 4 ds_read_b128 (was 8);
//    m-invariant x-axis tap calc hoisted out of the m-loop.

#define HW 96
#define NPIX (96*96)
#define CFEAT 64
#define INV192 (1.0f/192.0f)

typedef __attribute__((ext_vector_type(8))) short short8;
typedef __attribute__((ext_vector_type(4))) float f32x4;

__device__ __forceinline__ unsigned pack_bf2(float a, float b) {
    unsigned ua = __builtin_bit_cast(unsigned, a);
    unsigned ub = __builtin_bit_cast(unsigned, b);
    return (ua >> 16) | (ub & 0xffff0000u);
}
__device__ __forceinline__ float bf_hi(float a) {
    return __builtin_bit_cast(float, __builtin_bit_cast(unsigned, a) & 0xffff0000u);
}
__device__ __forceinline__ void split8(const float (&v)[8], short8& hi, short8& lo) {
    union { short8 s; unsigned u[4]; } H, L;
    #pragma unroll
    for (int p = 0; p < 4; ++p) {
        float a = v[2*p], b = v[2*p+1];
        H.u[p] = pack_bf2(a, b);
        L.u[p] = pack_bf2(a - bf_hi(a), b - bf_hi(b));
    }
    hi = H.s; lo = L.s;
}
__device__ __forceinline__ unsigned rne16(float x) {
    unsigned u = __builtin_bit_cast(unsigned, x);
    return (u + 0x7fffu + ((u >> 16) & 1u)) >> 16;
}
__device__ __forceinline__ unsigned pack_bf2_rne(float a, float b) {
    return rne16(a) | (rne16(b) << 16);
}
__device__ __forceinline__ short top16(float a) {
    return (short)(__builtin_bit_cast(unsigned, a) >> 16);
}

// sum over the 16-lane group via DPP (all lanes end with the group sum)
__device__ __forceinline__ float dpp_red16(float v) {
    int x;
    x = __builtin_amdgcn_update_dpp(0, __builtin_bit_cast(int, v), 0xB1, 0xF, 0xF, true);
    v += __builtin_bit_cast(float, x);
    x = __builtin_amdgcn_update_dpp(0, __builtin_bit_cast(int, v), 0x4E, 0xF, 0xF, true);
    v += __builtin_bit_cast(float, x);
    x = __builtin_amdgcn_update_dpp(0, __builtin_bit_cast(int, v), 0x141, 0xF, 0xF, true);
    v += __builtin_bit_cast(float, x);
    x = __builtin_amdgcn_update_dpp(0, __builtin_bit_cast(int, v), 0x140, 0xF, 0xF, true);
    v += __builtin_bit_cast(float, x);
    return v;
}

#define AXCALC(CV, SGN, II, RR)                                        \
{                                                                      \
    float e = CV + (SGN)*(1.0f/96.0f) + 1e-6f;                         \
    e = fminf(fmaxf(e, -1.0f + 1e-6f), 1.0f - 1e-6f);                  \
    II = (int)rintf((e + 1.0f) * 48.0f - 0.5f);                        \
    II = min(max(II, 0), 95);                                          \
    RR = (CV - fmaf((float)II, 0.0208333333f, -0.9895833333f)) * 96.0f;\
}

// ---------------- weight pre-swizzle: RNE-bf16 hi plane only ----------------
// frag = 512 shorts (1 KB): B[k][n] for kt,nt; lane*8 layout.
__global__ __launch_bounds__(256) void swizzle_kernel(
    const float* __restrict__ Wh1, const float* __restrict__ Wh2,
    const float* __restrict__ W0, short* __restrict__ wsw)
{
    const int gid = blockIdx.x*256 + threadIdx.x;
    if (gid >= 424*64) return;
    const int f    = gid >> 6;
    const int lane = gid & 63;
    const int c    = lane & 15;
    const int kg   = lane >> 4;
    const float* W; int kt, nt, N;
    if (f < 288)      { W = Wh1; kt = f >> 4;        nt = f & 15;        N = 256; }
    else if (f < 416) { W = Wh2; kt = (f-288) >> 4;  nt = (f-288) & 15;  N = 256; }
    else              { W = W0;  kt = (f-416) >> 2;  nt = (f-416) & 3;   N = 64;  }
    union { short8 s; unsigned u[4]; } H;
    #pragma unroll
    for (int p = 0; p < 4; ++p) {
        float a = W[(kt*32 + kg*8 + 2*p    )*N + nt*16 + c];
        float b = W[(kt*32 + kg*8 + 2*p + 1)*N + nt*16 + c];
        H.u[p] = pack_bf2_rne(a, b);
    }
    *(short8*)(wsw + (size_t)f*512 + lane*8) = H.s;
}

// ---------------- hyper net (MFMA, 2-term: Ahi*B + Alo*B) ----------------
__global__ __launch_bounds__(512) void hyper_mfma(
    const float* __restrict__ feat,
    const float* __restrict__ cell,
    const float* __restrict__ Wh1,
    const float* __restrict__ bh1,
    const float* __restrict__ bh2,
    const float* __restrict__ b0,
    const short* __restrict__ wsw,
    float* __restrict__ mod_ws,
    float* __restrict__ f0_ws)
{
    __shared__ short AHI[72*128];
    __shared__ short ALO[72*128];
    __shared__ short HHI[32*128];
    __shared__ short HLO[32*128];

    const int tid = threadIdx.x;
    const int blk = blockIdx.x;
    const int y   = blk / 6;
    const int x0  = (blk % 6) * 16;
    const int qbase = y*HW + x0;

    for (int idx = tid; idx < 9216; idx += 512) {
        const int px = idx & 15;
        const int k  = idx >> 4;
        const int ch = k / 9;
        const int j  = k - 9*ch;
        const int dy = j / 3;
        const int dx = j - 3*dy;
        const int gy = y + dy - 1;
        const int gx = x0 + px + dx - 1;
        float v = 0.0f;
        if (gy >= 0 && gy < HW && gx >= 0 && gx < HW)
            v = feat[ch*NPIX + gy*HW + gx];
        const int dst = (k >> 3)*128 + px*8 + (k & 7);
        AHI[dst] = top16(v);
        ALO[dst] = top16(v - bf_hi(v));
    }
    __syncthreads();

    const int lane = tid & 63;
    const int wid  = tid >> 6;
    const int c    = lane & 15;
    const int kg   = lane >> 4;

    const short* wh1f = wsw;
    const short* wh2f = wsw + (size_t)288*512;
    const short* w0f  = wsw + (size_t)416*512;

    if (wid < 4) {
        f32x4 acc0;
        const float bb = b0[wid*16 + c];
        acc0[0] = bb; acc0[1] = bb; acc0[2] = bb; acc0[3] = bb;
        #pragma unroll
        for (int kt = 0; kt < 2; ++kt) {
            float v[8];
            #pragma unroll
            for (int j = 0; j < 8; ++j)
                v[j] = feat[(kt*32 + kg*8 + j)*NPIX + y*HW + x0 + c];
            short8 Ahi, Alo;
            split8(v, Ahi, Alo);
            const short8 B = *(const short8*)(w0f + (size_t)(kt*4 + wid)*512 + lane*8);
            acc0 = __builtin_amdgcn_mfma_f32_16x16x32_bf16(Ahi, B, acc0, 0, 0, 0);
            acc0 = __builtin_amdgcn_mfma_f32_16x16x32_bf16(Alo, B, acc0, 0, 0, 0);
        }
        #pragma unroll
        for (int i = 0; i < 4; ++i)
            f0_ws[(size_t)(qbase + kg*4 + i)*64 + wid*16 + c] = acc0[i];
    }

    f32x4 acc[2];
    #pragma unroll
    for (int nt = 0; nt < 2; ++nt) {
        const float bb = bh1[wid*32 + nt*16 + c];
        acc[nt][0] = bb; acc[nt][1] = bb; acc[nt][2] = bb; acc[nt][3] = bb;
    }
    #pragma unroll
    for (int kt = 0; kt < 18; ++kt) {
        const int aoff = (kt*4 + kg)*128 + c*8;
        const short8 Ahi = *(const short8*)&AHI[aoff];
        const short8 Alo = *(const short8*)&ALO[aoff];
        #pragma unroll
        for (int nt = 0; nt < 2; ++nt) {
            const short8 B = *(const short8*)(wh1f + (size_t)(kt*16 + wid*2 + nt)*512 + lane*8);
            acc[nt] = __builtin_amdgcn_mfma_f32_16x16x32_bf16(Ahi, B, acc[nt], 0, 0, 0);
            acc[nt] = __builtin_amdgcn_mfma_f32_16x16x32_bf16(Alo, B, acc[nt], 0, 0, 0);
        }
    }
    {
        float rc0v[4], rc1v[4];
        #pragma unroll
        for (int i = 0; i < 4; ++i) {
            const int q = qbase + kg*4 + i;
            const float2 ce = ((const float2*)cell)[q];
            rc0v[i] = ce.x * 96.0f;
            rc1v[i] = ce.y * 96.0f;
        }
        #pragma unroll
        for (int nt = 0; nt < 2; ++nt) {
            const int n = wid*32 + nt*16 + c;
            const float w5 = Wh1[576*256 + n];
            const float w6 = Wh1[577*256 + n];
            #pragma unroll
            for (int i = 0; i < 4; ++i) {
                float hv = acc[nt][i] + rc0v[i]*w5 + rc1v[i]*w6;
                hv = fmaxf(hv, 0.0f);
                const int dst = (n >> 3)*128 + (kg*4 + i)*8 + (n & 7);
                HHI[dst] = top16(hv);
                HLO[dst] = top16(hv - bf_hi(hv));
            }
        }
    }
    __syncthreads();

    f32x4 acc2[2];
    #pragma unroll
    for (int nt = 0; nt < 2; ++nt) {
        const float bb = bh2[wid*32 + nt*16 + c];
        acc2[nt][0] = bb; acc2[nt][1] = bb; acc2[nt][2] = bb; acc2[nt][3] = bb;
    }
    #pragma unroll
    for (int kt = 0; kt < 8; ++kt) {
        const int aoff = (kt*4 + kg)*128 + c*8;
        const short8 Ahi = *(const short8*)&HHI[aoff];
        const short8 Alo = *(const short8*)&HLO[aoff];
        #pragma unroll
        for (int nt = 0; nt < 2; ++nt) {
            const short8 B = *(const short8*)(wh2f + (size_t)(kt*16 + wid*2 + nt)*512 + lane*8);
            acc2[nt] = __builtin_amdgcn_mfma_f32_16x16x32_bf16(Ahi, B, acc2[nt], 0, 0, 0);
            acc2[nt] = __builtin_amdgcn_mfma_f32_16x16x32_bf16(Alo, B, acc2[nt], 0, 0, 0);
        }
    }
    #pragma unroll
    for (int nt = 0; nt < 2; ++nt) {
        #pragma unroll
        for (int i = 0; i < 4; ++i)
            mod_ws[(size_t)(qbase + kg*4 + i)*256 + wid*32 + nt*16 + c] = acc2[nt][i];
    }
}

// ---------------- query kernel v6 ----------------
// LDS row (per latent px), 324 floats:
//   [0..63]    g'  = s1*(f0 + rc0*w66 + rc1*w67) + t1
//   [64..127]  u0  = s1*W0row64
//   [128..191] u1  = s1*W0row65
//   [192..319] interleaved: for col c=0..15: [192+c*8 .. +3]=sc2T[c][nt],
//              [192+c*8+4 .. +7]=sh2T[c][nt]
#define ROWQ 324

__global__ __launch_bounds__(512) void query_kernel_v6(
    const float* __restrict__ cell,
    const float* __restrict__ W0,
    const float* __restrict__ W1,
    const float* __restrict__ b1,
    const float* __restrict__ W2,
    const float* __restrict__ b2,
    const float* __restrict__ mod_ws,
    const float* __restrict__ f0_ws,
    float* __restrict__ out)
{
    __shared__ float smem[24*ROWQ];    // 31.1 KB

    const int tid = threadIdx.x;
    const int bX  = blockIdx.x % 24;   // 384/16
    const int bY  = blockIdx.x / 24;   // 384/8
    const int X0  = bX * 16;
    const int Y0  = bY * 8;
    const int lx0 = bX*4 - 1;          // 6 latent cols
    const int ly0 = bY*2 - 1;          // 4 latent rows

    const float rc0 = cell[0] * 96.0f;
    const float rc1 = cell[1] * 96.0f;

    const float4* w64p = (const float4*)(W0 + 64*64);
    const float4* w65p = (const float4*)(W0 + 65*64);
    const float4* w66p = (const float4*)(W0 + 66*64);
    const float4* w67p = (const float4*)(W0 + 67*64);

    // ---- stage 4x6 latent patch: 24 rows x 64 items ----
    for (int idx = tid; idx < 1536; idx += 512) {
        const int r  = idx >> 6;
        const int o  = idx & 63;
        const int ry = r / 6;
        const int rx = r - ry*6;
        const int gy = min(max(ly0 + ry, 0), 95);
        const int gx = min(max(lx0 + rx, 0), 95);
        const int src = gy*96 + gx;
        const float4* modv = (const float4*)(mod_ws + (size_t)src*256);
        if (o < 16) {
            const float4 f0 = ((const float4*)(f0_ws + (size_t)src*64))[o];
            const float4 s1 = modv[o];
            const float4 t1 = modv[32 + o];
            const float4 a  = w66p[o];
            const float4 b  = w67p[o];
            float4 v;
            v.x = fmaf(s1.x, fmaf(rc1, b.x, fmaf(rc0, a.x, f0.x)), t1.x);
            v.y = fmaf(s1.y, fmaf(rc1, b.y, fmaf(rc0, a.y, f0.y)), t1.y);
            v.z = fmaf(s1.z, fmaf(rc1, b.z, fmaf(rc0, a.z, f0.z)), t1.z);
            v.w = fmaf(s1.w, fmaf(rc1, b.w, fmaf(rc0, a.w, f0.w)), t1.w);
            *(float4*)(smem + r*ROWQ + o*4) = v;
        } else if (o < 32) {
            const int oo = o - 16;
            const float4 s1 = modv[oo];
            const float4 w  = w64p[oo];
            float4 v = {s1.x*w.x, s1.y*w.y, s1.z*w.z, s1.w*w.w};
            *(float4*)(smem + r*ROWQ + 64 + oo*4) = v;
        } else if (o < 48) {
            const int oo = o - 32;
            const float4 s1 = modv[oo];
            const float4 w  = w65p[oo];
            float4 v = {s1.x*w.x, s1.y*w.y, s1.z*w.z, s1.w*w.w};
            *(float4*)(smem + r*ROWQ + 128 + oo*4) = v;
        } else {
            const int oo = o - 48;             // 0..15
            const float4 s2 = modv[16 + oo];   // sc2 cols oo*4..+3
            const float4 h2 = modv[48 + oo];   // sh2 cols oo*4..+3
            #pragma unroll
            for (int j = 0; j < 4; ++j) {
                const int col = oo*4 + j;
                const int cc  = col & 15;
                const int nt  = col >> 4;
                const float sv = (j==0)?s2.x:(j==1)?s2.y:(j==2)?s2.z:s2.w;
                const float hv = (j==0)?h2.x:(j==1)?h2.y:(j==2)?h2.z:h2.w;
                smem[r*ROWQ + 192 + cc*8 + nt]     = sv;
                smem[r*ROWQ + 192 + cc*8 + 4 + nt] = hv;
            }
        }
    }

    const int lane = tid & 63;
    const int wid  = tid >> 6;     // 0..7
    const int c    = lane & 15;
    const int kg   = lane >> 4;

    // per-wave constants
    short8 Bh[4][2];
    #pragma unroll
    for (int nt = 0; nt < 4; ++nt) {
        #pragma unroll
        for (int kt = 0; kt < 2; ++kt) {
            union { short8 s; unsigned u[4]; } H;
            #pragma unroll
            for (int p = 0; p < 4; ++p) {
                float a = W1[(kt*32 + kg*8 + 2*p    )*64 + nt*16 + c];
                float b = W1[(kt*32 + kg*8 + 2*p + 1)*64 + nt*16 + c];
                H.u[p] = pack_bf2_rne(a, b);
            }
            Bh[nt][kt] = H.s;
        }
    }
    float b1c[4];
    float w2r[4][3];
    #pragma unroll
    for (int nt = 0; nt < 4; ++nt) {
        b1c[nt] = b1[nt*16 + c];
        w2r[nt][0] = W2[(nt*16 + c)*3 + 0];
        w2r[nt][1] = W2[(nt*16 + c)*3 + 1];
        w2r[nt][2] = W2[(nt*16 + c)*3 + 2];
    }
    const float b2v0 = b2[0], b2v1 = b2[1], b2v2 = b2[2];

    __syncthreads();

    const int Xw   = X0 + (wid & 3)*4;
    const int Yw   = Y0 + (wid >> 2)*4;
    const int qxA  = c >> 2;
    const int tapA = c & 3;
    const float vxA = (tapA < 2) ? -1.0f : 1.0f;
    const float vyA = (tapA & 1) ? 1.0f : -1.0f;

    // m-invariant x-axis tap math (A-side and epilogue-side)
    const float cxA = ((float)(Xw + qxA) + 0.5f) * INV192 - 1.0f;
    const float cxE = ((float)(Xw + kg)  + 0.5f) * INV192 - 1.0f;
    int ixA; float r1A;
    AXCALC(cxA, vyA, ixA, r1A)
    const int ixAc = ixA - lx0;
    int ixm, ixp; float r1m, r1p;
    AXCALC(cxE, -1.0f, ixm, r1m)
    AXCALC(cxE,  1.0f, ixp, r1p)

    #pragma unroll 2
    for (int m = 0; m < 4; ++m) {
        const int qy = Yw + m;
        const float cy = ((float)qy + 0.5f) * INV192 - 1.0f;

        // ================= A-build =================
        short8 Ahi[2], Alo[2];
        {
            int iyA; float r0A;
            AXCALC(cy, vxA, iyA, r0A)
            const float* rowp = smem + ((iyA - ly0)*6 + ixAc) * ROWQ;
            #pragma unroll
            for (int kt = 0; kt < 2; ++kt) {
                const int kb = kt*32 + kg*8;
                const float4 ga  = *(const float4*)(rowp + kb);
                const float4 gb  = *(const float4*)(rowp + kb + 4);
                const float4 u0a = *(const float4*)(rowp + 64  + kb);
                const float4 u0b = *(const float4*)(rowp + 64  + kb + 4);
                const float4 u1a = *(const float4*)(rowp + 128 + kb);
                const float4 u1b = *(const float4*)(rowp + 128 + kb + 4);
                float g[8]  = {ga.x,ga.y,ga.z,ga.w,gb.x,gb.y,gb.z,gb.w};
                float u0[8] = {u0a.x,u0a.y,u0a.z,u0a.w,u0b.x,u0b.y,u0b.z,u0b.w};
                float u1[8] = {u1a.x,u1a.y,u1a.z,u1a.w,u1b.x,u1b.y,u1b.z,u1b.w};
                float hv[8];
                #pragma unroll
                for (int j = 0; j < 8; ++j) {
                    float pre = fmaf(r0A, u0[j], g[j]);
                    pre = fmaf(r1A, u1[j], pre);
                    hv[j] = fmaxf(pre, 0.f);
                }
                split8(hv, Ahi[kt], Alo[kt]);
            }
        }

        // ================= epilogue indices + early LDS loads =================
        int iym, iyp; float r0m, r0p;
        AXCALC(cy, -1.0f, iym, r0m)
        AXCALC(cy,  1.0f, iyp, r0p)
        const int rym = (iym - ly0)*6 - lx0;
        const int ryp = (iyp - ly0)*6 - lx0;
        const int lr0 = rym + ixm, lr1 = rym + ixp;
        const int lr2 = ryp + ixm, lr3 = ryp + ixp;
        float4 sc2v[4], sh2v[4];
        #pragma unroll
        for (int i = 0; i < 4; ++i) {
            const int lri = (i == 0) ? lr0 : (i == 1) ? lr1 : (i == 2) ? lr2 : lr3;
            const float* p8 = smem + lri*ROWQ + 192 + c*8;
            sc2v[i] = *(const float4*)p8;
            sh2v[i] = *(const float4*)(p8 + 4);
        }
        const float a0 = fabsf(r0m*r1m) + 1e-9f;
        const float a1 = fabsf(r0m*r1p) + 1e-9f;
        const float a2 = fabsf(r0p*r1m) + 1e-9f;
        const float a3 = fabsf(r0p*r1p) + 1e-9f;
        const float invt = 1.0f / (a0 + a1 + a2 + a3);
        const float w0_ = a3 * invt, w1_ = a2 * invt, w2_ = a1 * invt, w3_ = a0 * invt;

        // ================= MFMA =================
        f32x4 acc[4];
        #pragma unroll
        for (int nt = 0; nt < 4; ++nt) {
            f32x4 z = {b1c[nt], b1c[nt], b1c[nt], b1c[nt]};
            acc[nt] = z;
        }
        #pragma unroll
        for (int nt = 0; nt < 4; ++nt) {
            #pragma unroll
            for (int kt = 0; kt < 2; ++kt) {
                acc[nt] = __builtin_amdgcn_mfma_f32_16x16x32_bf16(Ahi[kt], Bh[nt][kt], acc[nt], 0, 0, 0);
                acc[nt] = __builtin_amdgcn_mfma_f32_16x16x32_bf16(Alo[kt], Bh[nt][kt], acc[nt], 0, 0, 0);
            }
        }

        // ================= modulate2 + layer2 + blend =================
        float p0 = 0.f, p1 = 0.f, p2 = 0.f;
        #pragma unroll
        for (int i = 0; i < 4; ++i) {
            const float wi = (i == 0) ? w0_ : (i == 1) ? w1_ : (i == 2) ? w2_ : w3_;
            float s0 = 0.f, s1 = 0.f, s2 = 0.f;
            #pragma unroll
            for (int nt = 0; nt < 4; ++nt) {
                const float sc2 = (nt==0)?sc2v[i].x:(nt==1)?sc2v[i].y:(nt==2)?sc2v[i].z:sc2v[i].w;
                const float sh2 = (nt==0)?sh2v[i].x:(nt==1)?sh2v[i].y:(nt==2)?sh2v[i].z:sh2v[i].w;
                const float v = fmaxf(fmaf(acc[nt][i], sc2, sh2), 0.f);
                s0 = fmaf(v, w2r[nt][0], s0);
                s1 = fmaf(v, w2r[nt][1], s1);
                s2 = fmaf(v, w2r[nt][2], s2);
            }
            p0 = fmaf(s0, wi, p0);
            p1 = fmaf(s1, wi, p1);
            p2 = fmaf(s2, wi, p2);
        }
        p0 = dpp_red16(p0);
        p1 = dpp_red16(p1);
        p2 = dpp_red16(p2);
        if (c < 3) {
            const int qE = qy*384 + Xw + kg;
            const float ov = (c == 0) ? p0 + b2v0 : (c == 1) ? p1 + b2v1 : p2 + b2v2;
            out[(size_t)qE*3 + c] = ov;
        }
    }
}

extern "C" void kernel_launch(void* const* d_in, const int* in_sizes, int n_in,
                              void* d_out, int out_size, void* d_ws, size_t ws_size,
                              hipStream_t stream) {
    const float* feat  = (const float*)d_in[0];
    const float* cell  = (const float*)d_in[2];
    const float* Wh1   = (const float*)d_in[3];
    const float* bh1   = (const float*)d_in[4];
    const float* Wh2   = (const float*)d_in[5];
    const float* bh2   = (const float*)d_in[6];
    const float* W0    = (const float*)d_in[7];
    const float* b0    = (const float*)d_in[8];
    const float* W1    = (const float*)d_in[9];
    const float* b1    = (const float*)d_in[10];
    const float* W2    = (const float*)d_in[11];
    const float* b2    = (const float*)d_in[12];
    float* out = (float*)d_out;

    float* mod_ws = (float*)d_ws;                         // 9216*256 f32
    float* f0_ws  = (float*)d_ws + 9216*256;              // 9216*64  f32
    short* wsw    = (short*)((char*)d_ws + 11796480);     // 424 frags * 1024 B

    swizzle_kernel<<<dim3(106), dim3(256), 0, stream>>>(Wh1, Wh2, W0, wsw);
    hyper_mfma<<<dim3(576), dim3(512), 0, stream>>>(
        feat, cell, Wh1, bh1, bh2, b0, wsw, mod_ws, f0_ws);
    query_kernel_v6<<<dim3(1152), dim3(512), 0, stream>>>(
        cell, W0, W1, b1, W2, b2, mod_ws, f0_ws, out);
}

// Round 10
// 79.329 us; speedup vs baseline: 7.0982x; 1.1003x over previous
//
#include <hip/hip_runtime.h>

// LM-LIIF fused pipeline. R9:
//  - query v7: revert v6's regressions (v5 layout: separate sc2T/sh2T at
//    stride-4 => 2-way banks; 256-thr blocks), keep v6's hoisted x-tap math,
//    and stretch the tile to 8x16 queries (m-loop=8) so the block prologue
//    (staging + W1 frag build) amortizes 2x. 1152 blocks, 31 KB LDS.
//  - hyper / swizzle unchanged from R8 (B = RNE-bf16, A split exact).

#define HW 96
#define NPIX (96*96)
#define CFEAT 64
#define INV192 (1.0f/192.0f)

typedef __attribute__((ext_vector_type(8))) short short8;
typedef __attribute__((ext_vector_type(4))) float f32x4;

__device__ __forceinline__ unsigned pack_bf2(float a, float b) {
    unsigned ua = __builtin_bit_cast(unsigned, a);
    unsigned ub = __builtin_bit_cast(unsigned, b);
    return (ua >> 16) | (ub & 0xffff0000u);
}
__device__ __forceinline__ float bf_hi(float a) {
    return __builtin_bit_cast(float, __builtin_bit_cast(unsigned, a) & 0xffff0000u);
}
__device__ __forceinline__ void split8(const float (&v)[8], short8& hi, short8& lo) {
    union { short8 s; unsigned u[4]; } H, L;
    #pragma unroll
    for (int p = 0; p < 4; ++p) {
        float a = v[2*p], b = v[2*p+1];
        H.u[p] = pack_bf2(a, b);
        L.u[p] = pack_bf2(a - bf_hi(a), b - bf_hi(b));
    }
    hi = H.s; lo = L.s;
}
__device__ __forceinline__ unsigned rne16(float x) {
    unsigned u = __builtin_bit_cast(unsigned, x);
    return (u + 0x7fffu + ((u >> 16) & 1u)) >> 16;
}
__device__ __forceinline__ unsigned pack_bf2_rne(float a, float b) {
    return rne16(a) | (rne16(b) << 16);
}
__device__ __forceinline__ short top16(float a) {
    return (short)(__builtin_bit_cast(unsigned, a) >> 16);
}

__device__ __forceinline__ float dpp_red16(float v) {
    int x;
    x = __builtin_amdgcn_update_dpp(0, __builtin_bit_cast(int, v), 0xB1, 0xF, 0xF, true);
    v += __builtin_bit_cast(float, x);
    x = __builtin_amdgcn_update_dpp(0, __builtin_bit_cast(int, v), 0x4E, 0xF, 0xF, true);
    v += __builtin_bit_cast(float, x);
    x = __builtin_amdgcn_update_dpp(0, __builtin_bit_cast(int, v), 0x141, 0xF, 0xF, true);
    v += __builtin_bit_cast(float, x);
    x = __builtin_amdgcn_update_dpp(0, __builtin_bit_cast(int, v), 0x140, 0xF, 0xF, true);
    v += __builtin_bit_cast(float, x);
    return v;
}

#define AXCALC(CV, SGN, II, RR)                                        \
{                                                                      \
    float e = CV + (SGN)*(1.0f/96.0f) + 1e-6f;                         \
    e = fminf(fmaxf(e, -1.0f + 1e-6f), 1.0f - 1e-6f);                  \
    II = (int)rintf((e + 1.0f) * 48.0f - 0.5f);                        \
    II = min(max(II, 0), 95);                                          \
    RR = (CV - fmaf((float)II, 0.0208333333f, -0.9895833333f)) * 96.0f;\
}

// ---------------- weight pre-swizzle (RNE-bf16 hi plane only) ----------------
__global__ __launch_bounds__(256) void swizzle_kernel(
    const float* __restrict__ Wh1, const float* __restrict__ Wh2,
    const float* __restrict__ W0, short* __restrict__ wsw)
{
    const int gid = blockIdx.x*256 + threadIdx.x;
    if (gid >= 424*64) return;
    const int f    = gid >> 6;
    const int lane = gid & 63;
    const int c    = lane & 15;
    const int kg   = lane >> 4;
    const float* W; int kt, nt, N;
    if (f < 288)      { W = Wh1; kt = f >> 4;        nt = f & 15;        N = 256; }
    else if (f < 416) { W = Wh2; kt = (f-288) >> 4;  nt = (f-288) & 15;  N = 256; }
    else              { W = W0;  kt = (f-416) >> 2;  nt = (f-416) & 3;   N = 64;  }
    union { short8 s; unsigned u[4]; } H;
    #pragma unroll
    for (int p = 0; p < 4; ++p) {
        float a = W[(kt*32 + kg*8 + 2*p    )*N + nt*16 + c];
        float b = W[(kt*32 + kg*8 + 2*p + 1)*N + nt*16 + c];
        H.u[p] = pack_bf2_rne(a, b);
    }
    *(short8*)(wsw + (size_t)f*512 + lane*8) = H.s;
}

// ---------------- hyper net (unchanged from R8) ----------------
__global__ __launch_bounds__(512) void hyper_mfma(
    const float* __restrict__ feat,
    const float* __restrict__ cell,
    const float* __restrict__ Wh1,
    const float* __restrict__ bh1,
    const float* __restrict__ bh2,
    const float* __restrict__ b0,
    const short* __restrict__ wsw,
    float* __restrict__ mod_ws,
    float* __restrict__ f0_ws)
{
    __shared__ short AHI[72*128];
    __shared__ short ALO[72*128];
    __shared__ short HHI[32*128];
    __shared__ short HLO[32*128];

    const int tid = threadIdx.x;
    const int blk = blockIdx.x;
    const int y   = blk / 6;
    const int x0  = (blk % 6) * 16;
    const int qbase = y*HW + x0;

    for (int idx = tid; idx < 9216; idx += 512) {
        const int px = idx & 15;
        const int k  = idx >> 4;
        const int ch = k / 9;
        const int j  = k - 9*ch;
        const int dy = j / 3;
        const int dx = j - 3*dy;
        const int gy = y + dy - 1;
        const int gx = x0 + px + dx - 1;
        float v = 0.0f;
        if (gy >= 0 && gy < HW && gx >= 0 && gx < HW)
            v = feat[ch*NPIX + gy*HW + gx];
        const int dst = (k >> 3)*128 + px*8 + (k & 7);
        AHI[dst] = top16(v);
        ALO[dst] = top16(v - bf_hi(v));
    }
    __syncthreads();

    const int lane = tid & 63;
    const int wid  = tid >> 6;
    const int c    = lane & 15;
    const int kg   = lane >> 4;

    const short* wh1f = wsw;
    const short* wh2f = wsw + (size_t)288*512;
    const short* w0f  = wsw + (size_t)416*512;

    if (wid < 4) {
        f32x4 acc0;
        const float bb = b0[wid*16 + c];
        acc0[0] = bb; acc0[1] = bb; acc0[2] = bb; acc0[3] = bb;
        #pragma unroll
        for (int kt = 0; kt < 2; ++kt) {
            float v[8];
            #pragma unroll
            for (int j = 0; j < 8; ++j)
                v[j] = feat[(kt*32 + kg*8 + j)*NPIX + y*HW + x0 + c];
            short8 Ahi, Alo;
            split8(v, Ahi, Alo);
            const short8 B = *(const short8*)(w0f + (size_t)(kt*4 + wid)*512 + lane*8);
            acc0 = __builtin_amdgcn_mfma_f32_16x16x32_bf16(Ahi, B, acc0, 0, 0, 0);
            acc0 = __builtin_amdgcn_mfma_f32_16x16x32_bf16(Alo, B, acc0, 0, 0, 0);
        }
        #pragma unroll
        for (int i = 0; i < 4; ++i)
            f0_ws[(size_t)(qbase + kg*4 + i)*64 + wid*16 + c] = acc0[i];
    }

    f32x4 acc[2];
    #pragma unroll
    for (int nt = 0; nt < 2; ++nt) {
        const float bb = bh1[wid*32 + nt*16 + c];
        acc[nt][0] = bb; acc[nt][1] = bb; acc[nt][2] = bb; acc[nt][3] = bb;
    }
    #pragma unroll
    for (int kt = 0; kt < 18; ++kt) {
        const int aoff = (kt*4 + kg)*128 + c*8;
        const short8 Ahi = *(const short8*)&AHI[aoff];
        const short8 Alo = *(const short8*)&ALO[aoff];
        #pragma unroll
        for (int nt = 0; nt < 2; ++nt) {
            const short8 B = *(const short8*)(wh1f + (size_t)(kt*16 + wid*2 + nt)*512 + lane*8);
            acc[nt] = __builtin_amdgcn_mfma_f32_16x16x32_bf16(Ahi, B, acc[nt], 0, 0, 0);
            acc[nt] = __builtin_amdgcn_mfma_f32_16x16x32_bf16(Alo, B, acc[nt], 0, 0, 0);
        }
    }
    {
        float rc0v[4], rc1v[4];
        #pragma unroll
        for (int i = 0; i < 4; ++i) {
            const int q = qbase + kg*4 + i;
            const float2 ce = ((const float2*)cell)[q];
            rc0v[i] = ce.x * 96.0f;
            rc1v[i] = ce.y * 96.0f;
        }
        #pragma unroll
        for (int nt = 0; nt < 2; ++nt) {
            const int n = wid*32 + nt*16 + c;
            const float w5 = Wh1[576*256 + n];
            const float w6 = Wh1[577*256 + n];
            #pragma unroll
            for (int i = 0; i < 4; ++i) {
                float hv = acc[nt][i] + rc0v[i]*w5 + rc1v[i]*w6;
                hv = fmaxf(hv, 0.0f);
                const int dst = (n >> 3)*128 + (kg*4 + i)*8 + (n & 7);
                HHI[dst] = top16(hv);
                HLO[dst] = top16(hv - bf_hi(hv));
            }
        }
    }
    __syncthreads();

    f32x4 acc2[2];
    #pragma unroll
    for (int nt = 0; nt < 2; ++nt) {
        const float bb = bh2[wid*32 + nt*16 + c];
        acc2[nt][0] = bb; acc2[nt][1] = bb; acc2[nt][2] = bb; acc2[nt][3] = bb;
    }
    #pragma unroll
    for (int kt = 0; kt < 8; ++kt) {
        const int aoff = (kt*4 + kg)*128 + c*8;
        const short8 Ahi = *(const short8*)&HHI[aoff];
        const short8 Alo = *(const short8*)&HLO[aoff];
        #pragma unroll
        for (int nt = 0; nt < 2; ++nt) {
            const short8 B = *(const short8*)(wh2f + (size_t)(kt*16 + wid*2 + nt)*512 + lane*8);
            acc2[nt] = __builtin_amdgcn_mfma_f32_16x16x32_bf16(Ahi, B, acc2[nt], 0, 0, 0);
            acc2[nt] = __builtin_amdgcn_mfma_f32_16x16x32_bf16(Alo, B, acc2[nt], 0, 0, 0);
        }
    }
    #pragma unroll
    for (int nt = 0; nt < 2; ++nt) {
        #pragma unroll
        for (int i = 0; i < 4; ++i)
            mod_ws[(size_t)(qbase + kg*4 + i)*256 + wid*32 + nt*16 + c] = acc2[nt][i];
    }
}

// ---------------- query kernel v7 ----------------
// LDS row (per latent px), 324 floats (v5 layout):
//   [0..63]    g'  = s1*(f0 + rc0*w66 + rc1*w67) + t1
//   [64..127]  u0  = s1*W0row64
//   [128..191] u1  = s1*W0row65
//   [192..255] sc2T (c*4+nt)     [256..319] sh2T (c*4+nt)
// Block = 8x16 queries, 256 thr (4 waves: 2x2, each 4 cols x 8 rows m-loop).
// Patch = 6 latent rows x 4 cols = 24 rows, 31.1 KB.
#define ROWQ 324

__global__ __launch_bounds__(256) void query_kernel_v7(
    const float* __restrict__ cell,
    const float* __restrict__ W0,
    const float* __restrict__ W1,
    const float* __restrict__ b1,
    const float* __restrict__ W2,
    const float* __restrict__ b2,
    const float* __restrict__ mod_ws,
    const float* __restrict__ f0_ws,
    float* __restrict__ out)
{
    __shared__ float smem[24*ROWQ];    // 31.1 KB

    const int tid = threadIdx.x;
    const int bX  = blockIdx.x % 48;   // x tiles of 8
    const int bY  = blockIdx.x / 48;   // y tiles of 16
    const int X0  = bX * 8;
    const int Y0  = bY * 16;
    const int lx0 = bX*2 - 1;          // 4 latent cols
    const int ly0 = bY*4 - 1;          // 6 latent rows

    const float rc0 = cell[0] * 96.0f;
    const float rc1 = cell[1] * 96.0f;

    const float4* w64p = (const float4*)(W0 + 64*64);
    const float4* w65p = (const float4*)(W0 + 65*64);
    const float4* w66p = (const float4*)(W0 + 66*64);
    const float4* w67p = (const float4*)(W0 + 67*64);

    // ---- stage 6x4 latent patch: 24 rows x 64 items ----
    for (int idx = tid; idx < 1536; idx += 256) {
        const int r  = idx >> 6;
        const int o  = idx & 63;
        const int ry = r >> 2;
        const int rx = r & 3;
        const int gy = min(max(ly0 + ry, 0), 95);
        const int gx = min(max(lx0 + rx, 0), 95);
        const int src = gy*96 + gx;
        const float4* modv = (const float4*)(mod_ws + (size_t)src*256);
        if (o < 16) {
            const float4 f0 = ((const float4*)(f0_ws + (size_t)src*64))[o];
            const float4 s1 = modv[o];
            const float4 t1 = modv[32 + o];
            const float4 a  = w66p[o];
            const float4 b  = w67p[o];
            float4 v;
            v.x = fmaf(s1.x, fmaf(rc1, b.x, fmaf(rc0, a.x, f0.x)), t1.x);
            v.y = fmaf(s1.y, fmaf(rc1, b.y, fmaf(rc0, a.y, f0.y)), t1.y);
            v.z = fmaf(s1.z, fmaf(rc1, b.z, fmaf(rc0, a.z, f0.z)), t1.z);
            v.w = fmaf(s1.w, fmaf(rc1, b.w, fmaf(rc0, a.w, f0.w)), t1.w);
            *(float4*)(smem + r*ROWQ + o*4) = v;
        } else if (o < 32) {
            const int oo = o - 16;
            const float4 s1 = modv[oo];
            const float4 w  = w64p[oo];
            float4 v = {s1.x*w.x, s1.y*w.y, s1.z*w.z, s1.w*w.w};
            *(float4*)(smem + r*ROWQ + 64 + oo*4) = v;
        } else if (o < 48) {
            const int oo = o - 32;
            const float4 s1 = modv[oo];
            const float4 w  = w65p[oo];
            float4 v = {s1.x*w.x, s1.y*w.y, s1.z*w.z, s1.w*w.w};
            *(float4*)(smem + r*ROWQ + 128 + oo*4) = v;
        } else {
            const int oo = o - 48;             // 0..15
            const float4 s2 = modv[16 + oo];   // sc2 cols oo*4..+3
            const float4 h2 = modv[48 + oo];   // sh2 cols oo*4..+3
            #pragma unroll
            for (int j = 0; j < 4; ++j) {
                const int col = oo*4 + j;
                const int cc  = col & 15;
                const int nt  = col >> 4;
                const float sv = (j==0)?s2.x:(j==1)?s2.y:(j==2)?s2.z:s2.w;
                const float hv = (j==0)?h2.x:(j==1)?h2.y:(j==2)?h2.z:h2.w;
                smem[r*ROWQ + 192 + cc*4 + nt] = sv;
                smem[r*ROWQ + 256 + cc*4 + nt] = hv;
            }
        }
    }

    const int lane = tid & 63;
    const int wid  = tid >> 6;
    const int c    = lane & 15;
    const int kg   = lane >> 4;

    // per-wave constants
    short8 Bh[4][2];
    #pragma unroll
    for (int nt = 0; nt < 4; ++nt) {
        #pragma unroll
        for (int kt = 0; kt < 2; ++kt) {
            union { short8 s; unsigned u[4]; } H;
            #pragma unroll
            for (int p = 0; p < 4; ++p) {
                float a = W1[(kt*32 + kg*8 + 2*p    )*64 + nt*16 + c];
                float b = W1[(kt*32 + kg*8 + 2*p + 1)*64 + nt*16 + c];
                H.u[p] = pack_bf2_rne(a, b);
            }
            Bh[nt][kt] = H.s;
        }
    }
    float b1c[4];
    float w2r[4][3];
    #pragma unroll
    for (int nt = 0; nt < 4; ++nt) {
        b1c[nt] = b1[nt*16 + c];
        w2r[nt][0] = W2[(nt*16 + c)*3 + 0];
        w2r[nt][1] = W2[(nt*16 + c)*3 + 1];
        w2r[nt][2] = W2[(nt*16 + c)*3 + 2];
    }
    const float b2v0 = b2[0], b2v1 = b2[1], b2v2 = b2[2];

    __syncthreads();

    const int Xw   = X0 + (wid & 1)*4;
    const int Yw   = Y0 + (wid >> 1)*8;
    const int qxA  = c >> 2;
    const int tapA = c & 3;
    const float vxA = (tapA < 2) ? -1.0f : 1.0f;
    const float vyA = (tapA & 1) ? 1.0f : -1.0f;

    // m-invariant x-axis tap math
    const float cxA = ((float)(Xw + qxA) + 0.5f) * INV192 - 1.0f;
    const float cxE = ((float)(Xw + kg)  + 0.5f) * INV192 - 1.0f;
    int ixA; float r1A;
    AXCALC(cxA, vyA, ixA, r1A)
    const int ixAc = ixA - lx0;
    int ixm, ixp; float r1m, r1p;
    AXCALC(cxE, -1.0f, ixm, r1m)
    AXCALC(cxE,  1.0f, ixp, r1p)

    #pragma unroll 2
    for (int m = 0; m < 8; ++m) {
        const int qy = Yw + m;
        const float cy = ((float)qy + 0.5f) * INV192 - 1.0f;

        // ================= A-build =================
        short8 Ahi[2], Alo[2];
        {
            int iyA; float r0A;
            AXCALC(cy, vxA, iyA, r0A)
            const float* rowp = smem + ((iyA - ly0)*4 + ixAc) * ROWQ;
            #pragma unroll
            for (int kt = 0; kt < 2; ++kt) {
                const int kb = kt*32 + kg*8;
                const float4 ga  = *(const float4*)(rowp + kb);
                const float4 gb  = *(const float4*)(rowp + kb + 4);
                const float4 u0a = *(const float4*)(rowp + 64  + kb);
                const float4 u0b = *(const float4*)(rowp + 64  + kb + 4);
                const float4 u1a = *(const float4*)(rowp + 128 + kb);
                const float4 u1b = *(const float4*)(rowp + 128 + kb + 4);
                float g[8]  = {ga.x,ga.y,ga.z,ga.w,gb.x,gb.y,gb.z,gb.w};
                float u0[8] = {u0a.x,u0a.y,u0a.z,u0a.w,u0b.x,u0b.y,u0b.z,u0b.w};
                float u1[8] = {u1a.x,u1a.y,u1a.z,u1a.w,u1b.x,u1b.y,u1b.z,u1b.w};
                float hv[8];
                #pragma unroll
                for (int j = 0; j < 8; ++j) {
                    float pre = fmaf(r0A, u0[j], g[j]);
                    pre = fmaf(r1A, u1[j], pre);
                    hv[j] = fmaxf(pre, 0.f);
                }
                split8(hv, Ahi[kt], Alo[kt]);
            }
        }

        // ================= epilogue indices + early LDS loads =================
        int iym, iyp; float r0m, r0p;
        AXCALC(cy, -1.0f, iym, r0m)
        AXCALC(cy,  1.0f, iyp, r0p)
        const int rym = (iym - ly0)*4 - lx0;
        const int ryp = (iyp - ly0)*4 - lx0;
        const int lr0 = rym + ixm, lr1 = rym + ixp;
        const int lr2 = ryp + ixm, lr3 = ryp + ixp;
        float4 sc2v[4], sh2v[4];
        #pragma unroll
        for (int i = 0; i < 4; ++i) {
            const int lri = (i == 0) ? lr0 : (i == 1) ? lr1 : (i == 2) ? lr2 : lr3;
            sc2v[i] = *(const float4*)(smem + lri*ROWQ + 192 + c*4);
            sh2v[i] = *(const float4*)(smem + lri*ROWQ + 256 + c*4);
        }
        const float a0 = fabsf(r0m*r1m) + 1e-9f;
        const float a1 = fabsf(r0m*r1p) + 1e-9f;
        const float a2 = fabsf(r0p*r1m) + 1e-9f;
        const float a3 = fabsf(r0p*r1p) + 1e-9f;
        const float invt = 1.0f / (a0 + a1 + a2 + a3);
        const float w0_ = a3 * invt, w1_ = a2 * invt, w2_ = a1 * invt, w3_ = a0 * invt;

        // ================= MFMA =================
        f32x4 acc[4];
        #pragma unroll
        for (int nt = 0; nt < 4; ++nt) {
            f32x4 z = {b1c[nt], b1c[nt], b1c[nt], b1c[nt]};
            acc[nt] = z;
        }
        #pragma unroll
        for (int nt = 0; nt < 4; ++nt) {
            #pragma unroll
            for (int kt = 0; kt < 2; ++kt) {
                acc[nt] = __builtin_amdgcn_mfma_f32_16x16x32_bf16(Ahi[kt], Bh[nt][kt], acc[nt], 0, 0, 0);
                acc[nt] = __builtin_amdgcn_mfma_f32_16x16x32_bf16(Alo[kt], Bh[nt][kt], acc[nt], 0, 0, 0);
            }
        }

        // ================= modulate2 + layer2 + blend =================
        float p0 = 0.f, p1 = 0.f, p2 = 0.f;
        #pragma unroll
        for (int i = 0; i < 4; ++i) {
            const float wi = (i == 0) ? w0_ : (i == 1) ? w1_ : (i == 2) ? w2_ : w3_;
            float s0 = 0.f, s1 = 0.f, s2 = 0.f;
            #pragma unroll
            for (int nt = 0; nt < 4; ++nt) {
                const float sc2 = (nt==0)?sc2v[i].x:(nt==1)?sc2v[i].y:(nt==2)?sc2v[i].z:sc2v[i].w;
                const float sh2 = (nt==0)?sh2v[i].x:(nt==1)?sh2v[i].y:(nt==2)?sh2v[i].z:sh2v[i].w;
                const float v = fmaxf(fmaf(acc[nt][i], sc2, sh2), 0.f);
                s0 = fmaf(v, w2r[nt][0], s0);
                s1 = fmaf(v, w2r[nt][1], s1);
                s2 = fmaf(v, w2r[nt][2], s2);
            }
            p0 = fmaf(s0, wi, p0);
            p1 = fmaf(s1, wi, p1);
            p2 = fmaf(s2, wi, p2);
        }
        p0 = dpp_red16(p0);
        p1 = dpp_red16(p1);
        p2 = dpp_red16(p2);
        if (c < 3) {
            const int qE = qy*384 + Xw + kg;
            const float ov = (c == 0) ? p0 + b2v0 : (c == 1) ? p1 + b2v1 : p2 + b2v2;
            out[(size_t)qE*3 + c] = ov;
        }
    }
}

extern "C" void kernel_launch(void* const* d_in, const int* in_sizes, int n_in,
                              void* d_out, int out_size, void* d_ws, size_t ws_size,
                              hipStream_t stream) {
    const float* feat  = (const float*)d_in[0];
    const float* cell  = (const float*)d_in[2];
    const float* Wh1   = (const float*)d_in[3];
    const float* bh1   = (const float*)d_in[4];
    const float* Wh2   = (const float*)d_in[5];
    const float* bh2   = (const float*)d_in[6];
    const float* W0    = (const float*)d_in[7];
    const float* b0    = (const float*)d_in[8];
    const float* W1    = (const float*)d_in[9];
    const float* b1    = (const float*)d_in[10];
    const float* W2    = (const float*)d_in[11];
    const float* b2    = (const float*)d_in[12];
    float* out = (float*)d_out;

    float* mod_ws = (float*)d_ws;                         // 9216*256 f32
    float* f0_ws  = (float*)d_ws + 9216*256;              // 9216*64  f32
    short* wsw    = (short*)((char*)d_ws + 11796480);     // 424 frags * 1024 B

    swizzle_kernel<<<dim3(106), dim3(256), 0, stream>>>(Wh1, Wh2, W0, wsw);
    hyper_mfma<<<dim3(576), dim3(512), 0, stream>>>(
        feat, cell, Wh1, bh1, bh2, b0, wsw, mod_ws, f0_ws);
    query_kernel_v7<<<dim3(1152), dim3(256), 0, stream>>>(
        cell, W0, W1, b1, W2, b2, mod_ws, f0_ws, out);
}

// Round 11
// 76.732 us; speedup vs baseline: 7.3384x; 1.0338x over previous
//
#include <hip/hip_runtime.h>

// LM-LIIF fused pipeline. R10:
//  - query v8: A-side lo plane dropped (A = RNE-bf16; spends accuracy budget,
//    predicted absmax ~4e-4 vs 8.06e-4 threshold) -> 4 MFMAs/m-iter, no split8;
//    W1 fragments pre-swizzled into wsw (prologue 64 scalar loads -> 8 b128);
//    m-loop unroll 4; epilogue LDS loads hoisted before A-build.
//  - hyper unchanged from R8/R9 (A split exact, B RNE).

#define HW 96
#define NPIX (96*96)
#define CFEAT 64
#define INV192 (1.0f/192.0f)

typedef __attribute__((ext_vector_type(8))) short short8;
typedef __attribute__((ext_vector_type(4))) float f32x4;

__device__ __forceinline__ unsigned pack_bf2(float a, float b) {
    unsigned ua = __builtin_bit_cast(unsigned, a);
    unsigned ub = __builtin_bit_cast(unsigned, b);
    return (ua >> 16) | (ub & 0xffff0000u);
}
__device__ __forceinline__ float bf_hi(float a) {
    return __builtin_bit_cast(float, __builtin_bit_cast(unsigned, a) & 0xffff0000u);
}
__device__ __forceinline__ void split8(const float (&v)[8], short8& hi, short8& lo) {
    union { short8 s; unsigned u[4]; } H, L;
    #pragma unroll
    for (int p = 0; p < 4; ++p) {
        float a = v[2*p], b = v[2*p+1];
        H.u[p] = pack_bf2(a, b);
        L.u[p] = pack_bf2(a - bf_hi(a), b - bf_hi(b));
    }
    hi = H.s; lo = L.s;
}
__device__ __forceinline__ unsigned rne16(float x) {
    unsigned u = __builtin_bit_cast(unsigned, x);
    return (u + 0x7fffu + ((u >> 16) & 1u)) >> 16;
}
__device__ __forceinline__ unsigned pack_bf2_rne(float a, float b) {
    return rne16(a) | (rne16(b) << 16);
}
__device__ __forceinline__ short top16(float a) {
    return (short)(__builtin_bit_cast(unsigned, a) >> 16);
}

__device__ __forceinline__ float dpp_red16(float v) {
    int x;
    x = __builtin_amdgcn_update_dpp(0, __builtin_bit_cast(int, v), 0xB1, 0xF, 0xF, true);
    v += __builtin_bit_cast(float, x);
    x = __builtin_amdgcn_update_dpp(0, __builtin_bit_cast(int, v), 0x4E, 0xF, 0xF, true);
    v += __builtin_bit_cast(float, x);
    x = __builtin_amdgcn_update_dpp(0, __builtin_bit_cast(int, v), 0x141, 0xF, 0xF, true);
    v += __builtin_bit_cast(float, x);
    x = __builtin_amdgcn_update_dpp(0, __builtin_bit_cast(int, v), 0x140, 0xF, 0xF, true);
    v += __builtin_bit_cast(float, x);
    return v;
}

#define AXCALC(CV, SGN, II, RR)                                        \
{                                                                      \
    float e = CV + (SGN)*(1.0f/96.0f) + 1e-6f;                         \
    e = fminf(fmaxf(e, -1.0f + 1e-6f), 1.0f - 1e-6f);                  \
    II = (int)rintf((e + 1.0f) * 48.0f - 0.5f);                        \
    II = min(max(II, 0), 95);                                          \
    RR = (CV - fmaf((float)II, 0.0208333333f, -0.9895833333f)) * 96.0f;\
}

// ---------------- weight pre-swizzle (RNE-bf16 hi plane only) ----------------
// frags: 0..287 Wh1, 288..415 Wh2, 416..423 W0 (N=64), 424..431 W1 (N=64).
__global__ __launch_bounds__(256) void swizzle_kernel(
    const float* __restrict__ Wh1, const float* __restrict__ Wh2,
    const float* __restrict__ W0, const float* __restrict__ W1,
    short* __restrict__ wsw)
{
    const int gid = blockIdx.x*256 + threadIdx.x;
    if (gid >= 432*64) return;
    const int f    = gid >> 6;
    const int lane = gid & 63;
    const int c    = lane & 15;
    const int kg   = lane >> 4;
    const float* W; int kt, nt, N;
    if (f < 288)      { W = Wh1; kt = f >> 4;        nt = f & 15;        N = 256; }
    else if (f < 416) { W = Wh2; kt = (f-288) >> 4;  nt = (f-288) & 15;  N = 256; }
    else if (f < 424) { W = W0;  kt = (f-416) >> 2;  nt = (f-416) & 3;   N = 64;  }
    else              { W = W1;  kt = (f-424) >> 2;  nt = (f-424) & 3;   N = 64;  }
    union { short8 s; unsigned u[4]; } H;
    #pragma unroll
    for (int p = 0; p < 4; ++p) {
        float a = W[(kt*32 + kg*8 + 2*p    )*N + nt*16 + c];
        float b = W[(kt*32 + kg*8 + 2*p + 1)*N + nt*16 + c];
        H.u[p] = pack_bf2_rne(a, b);
    }
    *(short8*)(wsw + (size_t)f*512 + lane*8) = H.s;
}

// ---------------- hyper net (unchanged from R8) ----------------
__global__ __launch_bounds__(512) void hyper_mfma(
    const float* __restrict__ feat,
    const float* __restrict__ cell,
    const float* __restrict__ Wh1,
    const float* __restrict__ bh1,
    const float* __restrict__ bh2,
    const float* __restrict__ b0,
    const short* __restrict__ wsw,
    float* __restrict__ mod_ws,
    float* __restrict__ f0_ws)
{
    __shared__ short AHI[72*128];
    __shared__ short ALO[72*128];
    __shared__ short HHI[32*128];
    __shared__ short HLO[32*128];

    const int tid = threadIdx.x;
    const int blk = blockIdx.x;
    const int y   = blk / 6;
    const int x0  = (blk % 6) * 16;
    const int qbase = y*HW + x0;

    for (int idx = tid; idx < 9216; idx += 512) {
        const int px = idx & 15;
        const int k  = idx >> 4;
        const int ch = k / 9;
        const int j  = k - 9*ch;
        const int dy = j / 3;
        const int dx = j - 3*dy;
        const int gy = y + dy - 1;
        const int gx = x0 + px + dx - 1;
        float v = 0.0f;
        if (gy >= 0 && gy < HW && gx >= 0 && gx < HW)
            v = feat[ch*NPIX + gy*HW + gx];
        const int dst = (k >> 3)*128 + px*8 + (k & 7);
        AHI[dst] = top16(v);
        ALO[dst] = top16(v - bf_hi(v));
    }
    __syncthreads();

    const int lane = tid & 63;
    const int wid  = tid >> 6;
    const int c    = lane & 15;
    const int kg   = lane >> 4;

    const short* wh1f = wsw;
    const short* wh2f = wsw + (size_t)288*512;
    const short* w0f  = wsw + (size_t)416*512;

    if (wid < 4) {
        f32x4 acc0;
        const float bb = b0[wid*16 + c];
        acc0[0] = bb; acc0[1] = bb; acc0[2] = bb; acc0[3] = bb;
        #pragma unroll
        for (int kt = 0; kt < 2; ++kt) {
            float v[8];
            #pragma unroll
            for (int j = 0; j < 8; ++j)
                v[j] = feat[(kt*32 + kg*8 + j)*NPIX + y*HW + x0 + c];
            short8 Ahi, Alo;
            split8(v, Ahi, Alo);
            const short8 B = *(const short8*)(w0f + (size_t)(kt*4 + wid)*512 + lane*8);
            acc0 = __builtin_amdgcn_mfma_f32_16x16x32_bf16(Ahi, B, acc0, 0, 0, 0);
            acc0 = __builtin_amdgcn_mfma_f32_16x16x32_bf16(Alo, B, acc0, 0, 0, 0);
        }
        #pragma unroll
        for (int i = 0; i < 4; ++i)
            f0_ws[(size_t)(qbase + kg*4 + i)*64 + wid*16 + c] = acc0[i];
    }

    f32x4 acc[2];
    #pragma unroll
    for (int nt = 0; nt < 2; ++nt) {
        const float bb = bh1[wid*32 + nt*16 + c];
        acc[nt][0] = bb; acc[nt][1] = bb; acc[nt][2] = bb; acc[nt][3] = bb;
    }
    #pragma unroll
    for (int kt = 0; kt < 18; ++kt) {
        const int aoff = (kt*4 + kg)*128 + c*8;
        const short8 Ahi = *(const short8*)&AHI[aoff];
        const short8 Alo = *(const short8*)&ALO[aoff];
        #pragma unroll
        for (int nt = 0; nt < 2; ++nt) {
            const short8 B = *(const short8*)(wh1f + (size_t)(kt*16 + wid*2 + nt)*512 + lane*8);
            acc[nt] = __builtin_amdgcn_mfma_f32_16x16x32_bf16(Ahi, B, acc[nt], 0, 0, 0);
            acc[nt] = __builtin_amdgcn_mfma_f32_16x16x32_bf16(Alo, B, acc[nt], 0, 0, 0);
        }
    }
    {
        float rc0v[4], rc1v[4];
        #pragma unroll
        for (int i = 0; i < 4; ++i) {
            const int q = qbase + kg*4 + i;
            const float2 ce = ((const float2*)cell)[q];
            rc0v[i] = ce.x * 96.0f;
            rc1v[i] = ce.y * 96.0f;
        }
        #pragma unroll
        for (int nt = 0; nt < 2; ++nt) {
            const int n = wid*32 + nt*16 + c;
            const float w5 = Wh1[576*256 + n];
            const float w6 = Wh1[577*256 + n];
            #pragma unroll
            for (int i = 0; i < 4; ++i) {
                float hv = acc[nt][i] + rc0v[i]*w5 + rc1v[i]*w6;
                hv = fmaxf(hv, 0.0f);
                const int dst = (n >> 3)*128 + (kg*4 + i)*8 + (n & 7);
                HHI[dst] = top16(hv);
                HLO[dst] = top16(hv - bf_hi(hv));
            }
        }
    }
    __syncthreads();

    f32x4 acc2[2];
    #pragma unroll
    for (int nt = 0; nt < 2; ++nt) {
        const float bb = bh2[wid*32 + nt*16 + c];
        acc2[nt][0] = bb; acc2[nt][1] = bb; acc2[nt][2] = bb; acc2[nt][3] = bb;
    }
    #pragma unroll
    for (int kt = 0; kt < 8; ++kt) {
        const int aoff = (kt*4 + kg)*128 + c*8;
        const short8 Ahi = *(const short8*)&HHI[aoff];
        const short8 Alo = *(const short8*)&HLO[aoff];
        #pragma unroll
        for (int nt = 0; nt < 2; ++nt) {
            const short8 B = *(const short8*)(wh2f + (size_t)(kt*16 + wid*2 + nt)*512 + lane*8);
            acc2[nt] = __builtin_amdgcn_mfma_f32_16x16x32_bf16(Ahi, B, acc2[nt], 0, 0, 0);
            acc2[nt] = __builtin_amdgcn_mfma_f32_16x16x32_bf16(Alo, B, acc2[nt], 0, 0, 0);
        }
    }
    #pragma unroll
    for (int nt = 0; nt < 2; ++nt) {
        #pragma unroll
        for (int i = 0; i < 4; ++i)
            mod_ws[(size_t)(qbase + kg*4 + i)*256 + wid*32 + nt*16 + c] = acc2[nt][i];
    }
}

// ---------------- query kernel v8 ----------------
// v7 geometry/layout; A = RNE-bf16 (no lo plane); W1 frags from wsw.
#define ROWQ 324

__global__ __launch_bounds__(256) void query_kernel_v8(
    const float* __restrict__ cell,
    const float* __restrict__ W0,
    const short* __restrict__ wsw,
    const float* __restrict__ b1,
    const float* __restrict__ W2,
    const float* __restrict__ b2,
    const float* __restrict__ mod_ws,
    const float* __restrict__ f0_ws,
    float* __restrict__ out)
{
    __shared__ float smem[24*ROWQ];    // 31.1 KB

    const int tid = threadIdx.x;
    const int bX  = blockIdx.x % 48;
    const int bY  = blockIdx.x / 48;
    const int X0  = bX * 8;
    const int Y0  = bY * 16;
    const int lx0 = bX*2 - 1;          // 4 latent cols
    const int ly0 = bY*4 - 1;          // 6 latent rows

    const float rc0 = cell[0] * 96.0f;
    const float rc1 = cell[1] * 96.0f;

    const float4* w64p = (const float4*)(W0 + 64*64);
    const float4* w65p = (const float4*)(W0 + 65*64);
    const float4* w66p = (const float4*)(W0 + 66*64);
    const float4* w67p = (const float4*)(W0 + 67*64);

    // ---- stage 6x4 latent patch: 24 rows x 64 items ----
    for (int idx = tid; idx < 1536; idx += 256) {
        const int r  = idx >> 6;
        const int o  = idx & 63;
        const int ry = r >> 2;
        const int rx = r & 3;
        const int gy = min(max(ly0 + ry, 0), 95);
        const int gx = min(max(lx0 + rx, 0), 95);
        const int src = gy*96 + gx;
        const float4* modv = (const float4*)(mod_ws + (size_t)src*256);
        if (o < 16) {
            const float4 f0 = ((const float4*)(f0_ws + (size_t)src*64))[o];
            const float4 s1 = modv[o];
            const float4 t1 = modv[32 + o];
            const float4 a  = w66p[o];
            const float4 b  = w67p[o];
            float4 v;
            v.x = fmaf(s1.x, fmaf(rc1, b.x, fmaf(rc0, a.x, f0.x)), t1.x);
            v.y = fmaf(s1.y, fmaf(rc1, b.y, fmaf(rc0, a.y, f0.y)), t1.y);
            v.z = fmaf(s1.z, fmaf(rc1, b.z, fmaf(rc0, a.z, f0.z)), t1.z);
            v.w = fmaf(s1.w, fmaf(rc1, b.w, fmaf(rc0, a.w, f0.w)), t1.w);
            *(float4*)(smem + r*ROWQ + o*4) = v;
        } else if (o < 32) {
            const int oo = o - 16;
            const float4 s1 = modv[oo];
            const float4 w  = w64p[oo];
            float4 v = {s1.x*w.x, s1.y*w.y, s1.z*w.z, s1.w*w.w};
            *(float4*)(smem + r*ROWQ + 64 + oo*4) = v;
        } else if (o < 48) {
            const int oo = o - 32;
            const float4 s1 = modv[oo];
            const float4 w  = w65p[oo];
            float4 v = {s1.x*w.x, s1.y*w.y, s1.z*w.z, s1.w*w.w};
            *(float4*)(smem + r*ROWQ + 128 + oo*4) = v;
        } else {
            const int oo = o - 48;             // 0..15
            const float4 s2 = modv[16 + oo];
            const float4 h2 = modv[48 + oo];
            #pragma unroll
            for (int j = 0; j < 4; ++j) {
                const int col = oo*4 + j;
                const int cc  = col & 15;
                const int nt  = col >> 4;
                const float sv = (j==0)?s2.x:(j==1)?s2.y:(j==2)?s2.z:s2.w;
                const float hv = (j==0)?h2.x:(j==1)?h2.y:(j==2)?h2.z:h2.w;
                smem[r*ROWQ + 192 + cc*4 + nt] = sv;
                smem[r*ROWQ + 256 + cc*4 + nt] = hv;
            }
        }
    }

    const int lane = tid & 63;
    const int wid  = tid >> 6;
    const int c    = lane & 15;
    const int kg   = lane >> 4;

    // per-wave constants: W1 frags from wsw (8 b128 loads)
    const short* w1f = wsw + (size_t)424*512;
    short8 Bh[4][2];
    #pragma unroll
    for (int kt = 0; kt < 2; ++kt)
        #pragma unroll
        for (int nt = 0; nt < 4; ++nt)
            Bh[nt][kt] = *(const short8*)(w1f + (size_t)(kt*4 + nt)*512 + lane*8);

    float b1c[4];
    float w2r[4][3];
    #pragma unroll
    for (int nt = 0; nt < 4; ++nt) {
        b1c[nt] = b1[nt*16 + c];
        w2r[nt][0] = W2[(nt*16 + c)*3 + 0];
        w2r[nt][1] = W2[(nt*16 + c)*3 + 1];
        w2r[nt][2] = W2[(nt*16 + c)*3 + 2];
    }
    const float b2v0 = b2[0], b2v1 = b2[1], b2v2 = b2[2];

    __syncthreads();

    const int Xw   = X0 + (wid & 1)*4;
    const int Yw   = Y0 + (wid >> 1)*8;
    const int qxA  = c >> 2;
    const int tapA = c & 3;
    const float vxA = (tapA < 2) ? -1.0f : 1.0f;
    const float vyA = (tapA & 1) ? 1.0f : -1.0f;

    // m-invariant x-axis tap math
    const float cxA = ((float)(Xw + qxA) + 0.5f) * INV192 - 1.0f;
    const float cxE = ((float)(Xw + kg)  + 0.5f) * INV192 - 1.0f;
    int ixA; float r1A;
    AXCALC(cxA, vyA, ixA, r1A)
    const int ixAc = ixA - lx0;
    int ixm, ixp; float r1m, r1p;
    AXCALC(cxE, -1.0f, ixm, r1m)
    AXCALC(cxE,  1.0f, ixp, r1p)

    #pragma unroll 4
    for (int m = 0; m < 8; ++m) {
        const int qy = Yw + m;
        const float cy = ((float)qy + 0.5f) * INV192 - 1.0f;

        // ====== epilogue indices + LDS loads issued FIRST (overlap A-build) ======
        int iym, iyp; float r0m, r0p;
        AXCALC(cy, -1.0f, iym, r0m)
        AXCALC(cy,  1.0f, iyp, r0p)
        const int rym = (iym - ly0)*4 - lx0;
        const int ryp = (iyp - ly0)*4 - lx0;
        const int lr0 = rym + ixm, lr1 = rym + ixp;
        const int lr2 = ryp + ixm, lr3 = ryp + ixp;
        float4 sc2v[4], sh2v[4];
        #pragma unroll
        for (int i = 0; i < 4; ++i) {
            const int lri = (i == 0) ? lr0 : (i == 1) ? lr1 : (i == 2) ? lr2 : lr3;
            sc2v[i] = *(const float4*)(smem + lri*ROWQ + 192 + c*4);
            sh2v[i] = *(const float4*)(smem + lri*ROWQ + 256 + c*4);
        }
        const float a0 = fabsf(r0m*r1m) + 1e-9f;
        const float a1 = fabsf(r0m*r1p) + 1e-9f;
        const float a2 = fabsf(r0p*r1m) + 1e-9f;
        const float a3 = fabsf(r0p*r1p) + 1e-9f;
        const float invt = 1.0f / (a0 + a1 + a2 + a3);
        const float w0_ = a3 * invt, w1_ = a2 * invt, w2_ = a1 * invt, w3_ = a0 * invt;

        // ================= A-build (RNE bf16, no lo plane) =================
        short8 A[2];
        {
            int iyA; float r0A;
            AXCALC(cy, vxA, iyA, r0A)
            const float* rowp = smem + ((iyA - ly0)*4 + ixAc) * ROWQ;
            #pragma unroll
            for (int kt = 0; kt < 2; ++kt) {
                const int kb = kt*32 + kg*8;
                const float4 ga  = *(const float4*)(rowp + kb);
                const float4 gb  = *(const float4*)(rowp + kb + 4);
                const float4 u0a = *(const float4*)(rowp + 64  + kb);
                const float4 u0b = *(const float4*)(rowp + 64  + kb + 4);
                const float4 u1a = *(const float4*)(rowp + 128 + kb);
                const float4 u1b = *(const float4*)(rowp + 128 + kb + 4);
                float g[8]  = {ga.x,ga.y,ga.z,ga.w,gb.x,gb.y,gb.z,gb.w};
                float u0[8] = {u0a.x,u0a.y,u0a.z,u0a.w,u0b.x,u0b.y,u0b.z,u0b.w};
                float u1[8] = {u1a.x,u1a.y,u1a.z,u1a.w,u1b.x,u1b.y,u1b.z,u1b.w};
                float hv[8];
                #pragma unroll
                for (int j = 0; j < 8; ++j) {
                    float pre = fmaf(r0A, u0[j], g[j]);
                    pre = fmaf(r1A, u1[j], pre);
                    hv[j] = fmaxf(pre, 0.f);
                }
                union { short8 s; unsigned u[4]; } P;
                #pragma unroll
                for (int p = 0; p < 4; ++p)
                    P.u[p] = pack_bf2_rne(hv[2*p], hv[2*p+1]);
                A[kt] = P.s;
            }
        }

        // ================= MFMA (4 per m-iter) =================
        f32x4 acc[4];
        #pragma unroll
        for (int nt = 0; nt < 4; ++nt) {
            f32x4 z = {b1c[nt], b1c[nt], b1c[nt], b1c[nt]};
            acc[nt] = z;
        }
        #pragma unroll
        for (int nt = 0; nt < 4; ++nt) {
            #pragma unroll
            for (int kt = 0; kt < 2; ++kt)
                acc[nt] = __builtin_amdgcn_mfma_f32_16x16x32_bf16(A[kt], Bh[nt][kt], acc[nt], 0, 0, 0);
        }

        // ================= modulate2 + layer2 + blend =================
        float p0 = 0.f, p1 = 0.f, p2 = 0.f;
        #pragma unroll
        for (int i = 0; i < 4; ++i) {
            const float wi = (i == 0) ? w0_ : (i == 1) ? w1_ : (i == 2) ? w2_ : w3_;
            float s0 = 0.f, s1 = 0.f, s2 = 0.f;
            #pragma unroll
            for (int nt = 0; nt < 4; ++nt) {
                const float sc2 = (nt==0)?sc2v[i].x:(nt==1)?sc2v[i].y:(nt==2)?sc2v[i].z:sc2v[i].w;
                const float sh2 = (nt==0)?sh2v[i].x:(nt==1)?sh2v[i].y:(nt==2)?sh2v[i].z:sh2v[i].w;
                const float v = fmaxf(fmaf(acc[nt][i], sc2, sh2), 0.f);
                s0 = fmaf(v, w2r[nt][0], s0);
                s1 = fmaf(v, w2r[nt][1], s1);
                s2 = fmaf(v, w2r[nt][2], s2);
            }
            p0 = fmaf(s0, wi, p0);
            p1 = fmaf(s1, wi, p1);
            p2 = fmaf(s2, wi, p2);
        }
        p0 = dpp_red16(p0);
        p1 = dpp_red16(p1);
        p2 = dpp_red16(p2);
        if (c < 3) {
            const int qE = qy*384 + Xw + kg;
            const float ov = (c == 0) ? p0 + b2v0 : (c == 1) ? p1 + b2v1 : p2 + b2v2;
            out[(size_t)qE*3 + c] = ov;
        }
    }
}

extern "C" void kernel_launch(void* const* d_in, const int* in_sizes, int n_in,
                              void* d_out, int out_size, void* d_ws, size_t ws_size,
                              hipStream_t stream) {
    const float* feat  = (const float*)d_in[0];
    const float* cell  = (const float*)d_in[2];
    const float* Wh1   = (const float*)d_in[3];
    const float* bh1   = (const float*)d_in[4];
    const float* Wh2   = (const float*)d_in[5];
    const float* bh2   = (const float*)d_in[6];
    const float* W0    = (const float*)d_in[7];
    const float* b0    = (const float*)d_in[8];
    const float* W1    = (const float*)d_in[9];
    const float* b1    = (const float*)d_in[10];
    const float* W2    = (const float*)d_in[11];
    const float* b2    = (const float*)d_in[12];
    float* out = (float*)d_out;

    float* mod_ws = (float*)d_ws;                         // 9216*256 f32
    float* f0_ws  = (float*)d_ws + 9216*256;              // 9216*64  f32
    short* wsw    = (short*)((char*)d_ws + 11796480);     // 432 frags * 1024 B

    swizzle_kernel<<<dim3(108), dim3(256), 0, stream>>>(Wh1, Wh2, W0, W1, wsw);
    hyper_mfma<<<dim3(576), dim3(512), 0, stream>>>(
        feat, cell, Wh1, bh1, bh2, b0, wsw, mod_ws, f0_ws);
    query_kernel_v8<<<dim3(1152), dim3(256), 0, stream>>>(
        cell, W0, wsw, b1, W2, b2, mod_ws, f0_ws, out);
}